// Round 1
// baseline (10005.347 us; speedup 1.0000x reference)
//
#include <hip/hip_runtime.h>
#include <math.h>

// ---------------- problem constants ----------------
#define BATCH 2
#define TSEQ 1024
#define DIMD 1024
#define MEMH 512
#define FFD 4096
#define CHUNKL 128
#define NPERS 16
#define NCH 8                       // TSEQ/CHUNKL
#define NTOK 2064                   // NPERS + TSEQ + TSEQ
#define ETA_C 0.9f
#define THETA_C 0.1f
#define ALPHA_C 0.02f

// ---------------- workspace layout (floats) ----------------
// union region A (16,908,288 floats) is time-multiplexed:
//   phase1: qkv | Qbuf | Kb | Vb   phase-scan tmps at A+0   phase2: aqkv   phase3: ffh
static const size_t OFF_QKV    = 0;          // 2048x3072
static const size_t OFF_QBUF   = 6291456;    // 2048x1024
static const size_t OFF_KB     = 8388608;    // [8][2][128][1024]
static const size_t OFF_VB     = 10485760;
static const size_t OFF_Z1     = 0;          // 256x512  (scan tmp, A dead region)
static const size_t OFF_H      = 131072;     // 256x512
static const size_t OFF_R      = 262144;     // 256x1024
static const size_t OFF_DH     = 524288;     // 256x512
static const size_t OFF_T1     = 0;          // 2048x512 (mem_tok hidden)
static const size_t OFF_MEMTOK = 1048576;    // 2048x1024
static const size_t OFF_AQKV   = 0;          // 4128x3072
static const size_t OFF_FFH    = 0;          // 4128x4096
static const size_t OFF_PAR    = 16908288;   // 1,050,112: W1|b1|W2|b2
static const size_t OFF_MOM    = 17958400;
static const size_t OFF_GRD    = 19008512;
static const size_t OFF_TOKENS = 20058624;   // 2x2064x1024
static const size_t OFF_OUTB   = 20058624;   // alias tokens (dead after aqkv)
static const size_t OFF_NEWQ   = 22155776;
static const size_t OFF_OBUF   = 24285696;   // 4128x1024
static const size_t OFF_Y2     = 24285696;   // alias obuf (dead after y1)
static const size_t OFF_Y1     = 28512768;   // 4128x1024
static const size_t OFF_HZ     = 28512768;   // alias y1 (dead after ffh), 2048x512
static const size_t OFF_MEMQ   = 29561344;   // 2048x1024
// total: 32,739,840 floats = 131 MB

static const size_t PW1 = 0, PB1 = 524288, PW2 = 524800, PB2 = 1049088, PSZ = 1050112;

// ---------------- generic fp32 tiled GEMM ----------------
// C[M,N] = act(alpha * op(A) @ op(B) + bias + add_scale*Add)
// TA==0: A is [M,K] row-major.  TA==1: A is [K,M] (we use A^T).
// TB==0: B is [N,K] row-major (we use B^T).  TB==1: B is [K,N].
// Requires K % 32 == 0 (all our K are).
#define GT 64
#define GK 32

template<int TA, int TB, int ACTF>
__global__ __launch_bounds__(256)
void gemm_k(const float* __restrict__ A, const float* __restrict__ B,
            float* __restrict__ C, int M, int N, int K,
            const float* __restrict__ bias, const float* __restrict__ add,
            float add_scale, float alpha)
{
    __shared__ float As[GK][GT + 1];
    __shared__ float Bs[GK][GT + 1];
    const int tid = threadIdx.x;
    const int tx = tid & 15, ty = tid >> 4;
    const int row0 = blockIdx.y * GT, col0 = blockIdx.x * GT;
    float acc[4][4] = {{0.f}};

    for (int k0 = 0; k0 < K; k0 += GK) {
        if (TA == 0) {
            const int k = tid & 31, mb = tid >> 5;
            #pragma unroll
            for (int p = 0; p < 8; ++p) {
                int m = mb + p * 8;
                int gr = row0 + m;
                As[k][m] = (gr < M) ? A[(size_t)gr * K + (k0 + k)] : 0.f;
            }
        } else {
            const int m = tid & 63, kb = tid >> 6;
            #pragma unroll
            for (int p = 0; p < 8; ++p) {
                int k = kb + p * 4;
                int gm = row0 + m;
                As[k][m] = (gm < M) ? A[(size_t)(k0 + k) * M + gm] : 0.f;
            }
        }
        if (TB == 0) {
            const int k = tid & 31, nb = tid >> 5;
            #pragma unroll
            for (int p = 0; p < 8; ++p) {
                int n = nb + p * 8;
                int gn = col0 + n;
                Bs[k][n] = (gn < N) ? B[(size_t)gn * K + (k0 + k)] : 0.f;
            }
        } else {
            const int n = tid & 63, kb = tid >> 6;
            #pragma unroll
            for (int p = 0; p < 8; ++p) {
                int k = kb + p * 4;
                int gn = col0 + n;
                Bs[k][n] = (gn < N) ? B[(size_t)(k0 + k) * N + gn] : 0.f;
            }
        }
        __syncthreads();
        #pragma unroll
        for (int kk = 0; kk < GK; ++kk) {
            float a[4], b[4];
            #pragma unroll
            for (int i = 0; i < 4; ++i) a[i] = As[kk][ty * 4 + i];
            #pragma unroll
            for (int j = 0; j < 4; ++j) b[j] = Bs[kk][tx * 4 + j];
            #pragma unroll
            for (int i = 0; i < 4; ++i)
                #pragma unroll
                for (int j = 0; j < 4; ++j)
                    acc[i][j] = fmaf(a[i], b[j], acc[i][j]);
        }
        __syncthreads();
    }

    #pragma unroll
    for (int i = 0; i < 4; ++i) {
        int r = row0 + ty * 4 + i;
        if (r >= M) continue;
        #pragma unroll
        for (int j = 0; j < 4; ++j) {
            int c = col0 + tx * 4 + j;
            if (c >= N) continue;
            float v = alpha * acc[i][j];
            if (bias) v += bias[c];
            if (add)  v += add_scale * add[(size_t)r * N + c];
            if (ACTF == 1) v = v / (1.f + __expf(-v));            // silu
            else if (ACTF == 2) {                                  // gelu (tanh approx, jax default)
                float u = 0.7978845608028654f * (v + 0.044715f * v * v * v);
                v = 0.5f * v * (1.f + tanhf(u));
            }
            C[(size_t)r * N + c] = v;
        }
    }
}

static void gemm(hipStream_t s, int ta, int tb, int act,
                 const float* A, const float* B, float* C,
                 int M, int N, int K, const float* bias = nullptr,
                 const float* add = nullptr, float add_scale = 0.f, float alpha = 1.f)
{
    dim3 g((N + GT - 1) / GT, (M + GT - 1) / GT), blk(256);
    if (ta == 0 && tb == 0 && act == 0)
        gemm_k<0,0,0><<<g, blk, 0, s>>>(A,B,C,M,N,K,bias,add,add_scale,alpha);
    else if (ta == 0 && tb == 0 && act == 1)
        gemm_k<0,0,1><<<g, blk, 0, s>>>(A,B,C,M,N,K,bias,add,add_scale,alpha);
    else if (ta == 0 && tb == 0 && act == 2)
        gemm_k<0,0,2><<<g, blk, 0, s>>>(A,B,C,M,N,K,bias,add,add_scale,alpha);
    else if (ta == 0 && tb == 1)
        gemm_k<0,1,0><<<g, blk, 0, s>>>(A,B,C,M,N,K,bias,add,add_scale,alpha);
    else
        gemm_k<1,1,0><<<g, blk, 0, s>>>(A,B,C,M,N,K,bias,add,add_scale,alpha);
}

// ---------------- elementwise / reshape kernels ----------------
__global__ void silu_elt_k(const float* __restrict__ z, float* __restrict__ h, int n) {
    int i = blockIdx.x * 256 + threadIdx.x;
    if (i < n) { float v = z[i]; h[i] = v / (1.f + __expf(-v)); }
}
__global__ void silubwd_k(const float* __restrict__ z, float* __restrict__ dh, int n) {
    int i = blockIdx.x * 256 + threadIdx.x;
    if (i < n) {
        float v = z[i];
        float sg = 1.f / (1.f + __expf(-v));
        dh[i] *= sg * (1.f + v * (1.f - sg));
    }
}
__global__ void colsum_k(const float* __restrict__ X, float* __restrict__ out,
                         int M, int N, float alpha) {
    int j = blockIdx.x * 256 + threadIdx.x;
    if (j >= N) return;
    float s = 0.f;
    for (int m = 0; m < M; ++m) s += X[(size_t)m * N + j];
    out[j] = alpha * s;
}
__global__ void update_k(float* __restrict__ p, float* __restrict__ mo,
                         const float* __restrict__ g, int n) {
    int i = blockIdx.x * 256 + threadIdx.x;
    if (i < n) {
        float m = ETA_C * mo[i] - THETA_C * g[i];
        mo[i] = m;
        p[i] = (1.f - ALPHA_C) * p[i] + m;
    }
}
// qkv [2048,3072] -> Qbuf [2048,1024], Kb/Vb [chunk][b][128][1024]
__global__ void extractqkv_k(const float* __restrict__ qkv, float* __restrict__ Q,
                             float* __restrict__ Kb, float* __restrict__ Vb) {
    size_t idx = (size_t)blockIdx.x * 256 + threadIdx.x;
    int m = (int)(idx / 3072), col = (int)(idx % 3072);
    int b = m >> 10, t = m & 1023;
    float v = qkv[idx];
    if (col < 1024) {
        Q[(size_t)m * 1024 + col] = v;
    } else {
        int d = col & 1023;
        int ch = t >> 7, r = t & 127;
        size_t o = ((size_t)((ch * 2 + b) * 128 + r)) * 1024 + d;
        if (col < 2048) Kb[o] = v; else Vb[o] = v;
    }
}
__global__ void tokens_k(const float* __restrict__ P, const float* __restrict__ memtok,
                         const float* __restrict__ x, float* __restrict__ tok) {
    size_t idx = (size_t)blockIdx.x * 256 + threadIdx.x;
    int d = (int)(idx & 1023);
    int n = (int)((idx >> 10) % NTOK);
    int b = (int)(idx / ((size_t)NTOK * 1024));
    float v;
    if (n < NPERS)            v = P[(size_t)n * 1024 + d];
    else if (n < NPERS + TSEQ) v = memtok[((size_t)b * TSEQ + (n - NPERS)) * 1024 + d];
    else                      v = x[((size_t)b * TSEQ + (n - NPERS - TSEQ)) * 1024 + d];
    tok[idx] = v;
}
__global__ void extract_out_k(const float* __restrict__ y2, float* __restrict__ outb) {
    size_t idx = (size_t)blockIdx.x * 256 + threadIdx.x;   // 2048*1024
    int d = (int)(idx & 1023);
    int m = (int)(idx >> 10);
    int b = m >> 10, t = m & 1023;
    outb[idx] = y2[((size_t)b * NTOK + (NPERS + TSEQ) + t) * 1024 + d];
}
__global__ void mul_k(const float* __restrict__ a, const float* __restrict__ b,
                      float* __restrict__ o, int n) {
    int i = blockIdx.x * 256 + threadIdx.x;
    if (i < n) o[i] = a[i] * b[i];
}

// ---------------- flash attention (fp32, causal, dh=64) ----------------
// grid (33, 16, 2), block 256.  aqkv [B*2064, 3072], o [B*2064, 1024]
__global__ __launch_bounds__(256)
void flash_k(const float* __restrict__ aqkv, float* __restrict__ o)
{
    __shared__ float Qs[64][65];
    __shared__ float Ks[64][65];
    __shared__ float Vs[64][65];
    __shared__ float Ps[64][65];
    const int qt = blockIdx.x, h = blockIdx.y, b = blockIdx.z;
    const int tid = threadIdx.x;
    const int tx = tid & 15, ty = tid >> 4;
    const int q0 = qt * 64;
    const size_t base = (size_t)b * NTOK * 3072 + (size_t)h * 64;

    {   // stage Q (pre-scaled by 1/sqrt(64))
        int d = tid & 63, rb = tid >> 6;
        #pragma unroll
        for (int p = 0; p < 16; ++p) {
            int r = rb * 16 + p;
            int n = q0 + r;
            Qs[r][d] = (n < NTOK) ? 0.125f * aqkv[base + (size_t)n * 3072 + d] : 0.f;
        }
    }
    float Oa[4][4] = {{0.f}};
    float mrow[4], lrow[4];
    #pragma unroll
    for (int i = 0; i < 4; ++i) { mrow[i] = -INFINITY; lrow[i] = 0.f; }
    __syncthreads();

    for (int jt = 0; jt <= qt; ++jt) {
        const int j0 = jt * 64;
        {   // stage K,V
            int d = tid & 63, rb = tid >> 6;
            #pragma unroll
            for (int p = 0; p < 16; ++p) {
                int r = rb * 16 + p;
                int n = j0 + r;
                if (n < NTOK) {
                    Ks[r][d] = aqkv[base + (size_t)n * 3072 + 1024 + d];
                    Vs[r][d] = aqkv[base + (size_t)n * 3072 + 2048 + d];
                } else { Ks[r][d] = 0.f; Vs[r][d] = 0.f; }
            }
        }
        __syncthreads();

        float s[4][4] = {{0.f}};
        #pragma unroll 8
        for (int d = 0; d < 64; ++d) {
            float a[4], bb[4];
            #pragma unroll
            for (int i = 0; i < 4; ++i) a[i] = Qs[ty * 4 + i][d];
            #pragma unroll
            for (int j = 0; j < 4; ++j) bb[j] = Ks[tx * 4 + j][d];
            #pragma unroll
            for (int i = 0; i < 4; ++i)
                #pragma unroll
                for (int j = 0; j < 4; ++j)
                    s[i][j] = fmaf(a[i], bb[j], s[i][j]);
        }
        // causal mask + online softmax (row groups of 16 lanes)
        #pragma unroll
        for (int i = 0; i < 4; ++i) {
            int qi = q0 + ty * 4 + i;
            float tmax = -INFINITY;
            #pragma unroll
            for (int j = 0; j < 4; ++j) {
                int kj = j0 + tx * 4 + j;
                if (kj > qi) s[i][j] = -INFINITY;
                tmax = fmaxf(tmax, s[i][j]);
            }
            #pragma unroll
            for (int off = 1; off < 16; off <<= 1)
                tmax = fmaxf(tmax, __shfl_xor(tmax, off));
            float mnew = fmaxf(mrow[i], tmax);
            float scale = __expf(mrow[i] - mnew);
            float p4[4], psum = 0.f;
            #pragma unroll
            for (int j = 0; j < 4; ++j) { p4[j] = __expf(s[i][j] - mnew); psum += p4[j]; }
            #pragma unroll
            for (int off = 1; off < 16; off <<= 1)
                psum += __shfl_xor(psum, off);
            lrow[i] = lrow[i] * scale + psum;
            mrow[i] = mnew;
            #pragma unroll
            for (int j = 0; j < 4; ++j) Oa[i][j] *= scale;
            #pragma unroll
            for (int j = 0; j < 4; ++j) Ps[ty * 4 + i][tx * 4 + j] = p4[j];
        }
        __syncthreads();
        #pragma unroll 8
        for (int kk = 0; kk < 64; ++kk) {
            float pv[4], vv[4];
            #pragma unroll
            for (int i = 0; i < 4; ++i) pv[i] = Ps[ty * 4 + i][kk];
            #pragma unroll
            for (int j = 0; j < 4; ++j) vv[j] = Vs[kk][tx * 4 + j];
            #pragma unroll
            for (int i = 0; i < 4; ++i)
                #pragma unroll
                for (int j = 0; j < 4; ++j)
                    Oa[i][j] = fmaf(pv[i], vv[j], Oa[i][j]);
        }
        __syncthreads();
    }

    #pragma unroll
    for (int i = 0; i < 4; ++i) {
        int n = q0 + ty * 4 + i;
        if (n >= NTOK) continue;
        float inv = 1.f / lrow[i];
        #pragma unroll
        for (int j = 0; j < 4; ++j)
            o[((size_t)b * NTOK + n) * 1024 + h * 64 + tx * 4 + j] = Oa[i][j] * inv;
    }
}

// ---------------- launch ----------------
extern "C" void kernel_launch(void* const* d_in, const int* in_sizes, int n_in,
                              void* d_out, int out_size, void* d_ws, size_t ws_size,
                              hipStream_t stream)
{
    const float* x     = (const float*)d_in[0];
    const float* Wqkv  = (const float*)d_in[1];
    const float* mW1   = (const float*)d_in[2];
    const float* mb1   = (const float*)d_in[3];
    const float* mW2   = (const float*)d_in[4];
    const float* mb2   = (const float*)d_in[5];
    const float* Pp    = (const float*)d_in[6];
    const float* Wqa   = (const float*)d_in[7];
    const float* Wo    = (const float*)d_in[8];
    const float* ffW1  = (const float*)d_in[9];
    const float* ffb1  = (const float*)d_in[10];
    const float* ffW2  = (const float*)d_in[11];
    const float* ffb2  = (const float*)d_in[12];
    float* ws = (float*)d_ws;

    float* qkv   = ws + OFF_QKV;
    float* Qbuf  = ws + OFF_QBUF;
    float* Kb    = ws + OFF_KB;
    float* Vb    = ws + OFF_VB;
    float* z1    = ws + OFF_Z1;
    float* hbuf  = ws + OFF_H;
    float* rbuf  = ws + OFF_R;
    float* dhb   = ws + OFF_DH;
    float* t1    = ws + OFF_T1;
    float* memtok= ws + OFF_MEMTOK;
    float* aqkv  = ws + OFF_AQKV;
    float* ffh   = ws + OFF_FFH;
    float* par   = ws + OFF_PAR;
    float* mom   = ws + OFF_MOM;
    float* grd   = ws + OFF_GRD;
    float* tokens= ws + OFF_TOKENS;
    float* outb  = ws + OFF_OUTB;
    float* newQ  = ws + OFF_NEWQ;
    float* obuf  = ws + OFF_OBUF;
    float* y2    = ws + OFF_Y2;
    float* y1    = ws + OFF_Y1;
    float* hz    = ws + OFF_HZ;
    float* memq  = ws + OFF_MEMQ;
    float* outp  = (float*)d_out;

    // init params = inputs, momentum = 0
    hipMemsetAsync(mom, 0, PSZ * sizeof(float), stream);
    hipMemcpyAsync(par + PW1, mW1, 524288 * sizeof(float), hipMemcpyDeviceToDevice, stream);
    hipMemcpyAsync(par + PB1, mb1, 512 * sizeof(float), hipMemcpyDeviceToDevice, stream);
    hipMemcpyAsync(par + PW2, mW2, 524288 * sizeof(float), hipMemcpyDeviceToDevice, stream);
    hipMemcpyAsync(par + PB2, mb2, 1024 * sizeof(float), hipMemcpyDeviceToDevice, stream);

    // qkv projection, split
    gemm(stream, 0, 0, 0, x, Wqkv, qkv, 2048, 3072, 1024);
    extractqkv_k<<<24576, 256, 0, stream>>>(qkv, Qbuf, Kb, Vb);

    // memory scan: 8 chunks of SGD-with-momentum on the 2-layer MLP
    const float cs = 2.f / (float)(BATCH * CHUNKL * DIMD);   // d(mean sq)/dz2 factor
    for (int c = 0; c < NCH; ++c) {
        const float* kc = Kb + (size_t)c * 262144;
        const float* vc = Vb + (size_t)c * 262144;
        gemm(stream, 0, 0, 0, kc, par + PW1, z1, 256, 512, 1024, par + PB1);
        silu_elt_k<<<512, 256, 0, stream>>>(z1, hbuf, 131072);
        gemm(stream, 0, 0, 0, hbuf, par + PW2, rbuf, 256, 1024, 512, par + PB2, vc, -1.f);
        gemm(stream, 1, 1, 0, rbuf, hbuf, grd + PW2, 1024, 512, 256, nullptr, nullptr, 0.f, cs);
        colsum_k<<<4, 256, 0, stream>>>(rbuf, grd + PB2, 256, 1024, cs);
        gemm(stream, 0, 1, 0, rbuf, par + PW2, dhb, 256, 512, 1024, nullptr, nullptr, 0.f, cs);
        silubwd_k<<<512, 256, 0, stream>>>(z1, dhb, 131072);
        gemm(stream, 1, 1, 0, dhb, kc, grd + PW1, 512, 1024, 256);
        colsum_k<<<2, 256, 0, stream>>>(dhb, grd + PB1, 256, 512, 1.f);
        update_k<<<4102, 256, 0, stream>>>(par, mom, grd, (int)PSZ);
    }

    // memory readout for Q tokens
    gemm(stream, 0, 0, 1, Qbuf, par + PW1, t1, 2048, 512, 1024, par + PB1);        // silu fused
    gemm(stream, 0, 0, 0, t1, par + PW2, memtok, 2048, 1024, 512, par + PB2);

    // tokens = [P, mem_tok, x]
    tokens_k<<<16512, 256, 0, stream>>>(Pp, memtok, x, tokens);

    // attention
    gemm(stream, 0, 0, 0, tokens, Wqa, aqkv, 4128, 3072, 1024);
    flash_k<<<dim3(33, 16, 2), 256, 0, stream>>>(aqkv, obuf);
    gemm(stream, 0, 0, 0, obuf, Wo, y1, 4128, 1024, 1024);

    // FFN
    gemm(stream, 0, 0, 2, y1, ffW1, ffh, 4128, 4096, 1024, ffb1);                  // gelu fused
    gemm(stream, 0, 0, 0, ffh, ffW2, y2, 4128, 1024, 4096, ffb2);

    // slice + gated output
    extract_out_k<<<8192, 256, 0, stream>>>(y2, outb);
    gemm(stream, 0, 0, 0, outb, Wqkv, newQ, 2048, 1024, 1024);                     // first 1024 rows = Q block
    gemm(stream, 0, 0, 1, newQ, par + PW1, hz, 2048, 512, 1024, par + PB1);        // silu fused
    gemm(stream, 0, 0, 0, hz, par + PW2, memq, 2048, 1024, 512, par + PB2);
    mul_k<<<8192, 256, 0, stream>>>(outb, memq, outp, 2097152);
}

// Round 3
// 5584.346 us; speedup vs baseline: 1.7917x; 1.7917x over previous
//
#include <hip/hip_runtime.h>
#include <math.h>

// ---------------- problem constants ----------------
#define BATCH 2
#define TSEQ 1024
#define DIMD 1024
#define NPERS 16
#define NCH 8
#define NTOK 2064
#define ETA_C 0.9f
#define THETA_C 0.1f
#define ALPHA_C 0.02f

typedef __attribute__((ext_vector_type(4))) float f32x4;
typedef __attribute__((ext_vector_type(8))) short s16x8;
typedef unsigned short u16;

// ---------------- bf16 helpers ----------------
__device__ __forceinline__ u16 f2bf(float f) {
    unsigned int u = __float_as_uint(f);
    return (u16)((u + 0x7fffu + ((u >> 16) & 1u)) >> 16);
}
__device__ __forceinline__ float bf2f(u16 h) { return __uint_as_float(((unsigned)h) << 16); }
__device__ __forceinline__ void split2(float v, u16& h, u16& l) {
    h = f2bf(v); l = f2bf(v - bf2f(h));
}

// ---------------- workspace layout (byte offsets) ----------------
static const size_t oRA = 0;                       // 50,724,864 multiplexed
static const size_t oRB = 50724864;                // 16,908,288
static const size_t oRC = 67633152;                // 12,582,912  (xh/xl -> mom -> Wqah/Wqal)
static const size_t oRD = 80216064;                // 16,777,216
static const size_t oRE = 96993280;                // 12,582,912 Wqkv h/l (persistent)
static const size_t oRF = 109576192;               //  4,194,304 parW h/l (persistent)
static const size_t oRG = 113770496;               //  4,200,448 par (persistent)
static const size_t oRH = 117970944;               //  8,388,608 outb f32
// total 126,359,552 bytes

static const size_t PW1 = 0, PB1 = 524288, PW2 = 524800, PB2 = 1049088, PSZ = 1050112;

// ---------------- fp32 tiled GEMM (scan only) ----------------
#define GT 64
#define GK 32
template<int TA, int TB>
__global__ __launch_bounds__(256)
void gemm_k(const float* __restrict__ A, const float* __restrict__ B,
            float* __restrict__ C, int M, int N, int K,
            const float* __restrict__ bias, const float* __restrict__ add,
            float add_scale, float alpha)
{
    __shared__ float As[GK][GT + 1];
    __shared__ float Bs[GK][GT + 1];
    const int tid = threadIdx.x;
    const int tx = tid & 15, ty = tid >> 4;
    const int row0 = blockIdx.y * GT, col0 = blockIdx.x * GT;
    float acc[4][4] = {{0.f}};
    for (int k0 = 0; k0 < K; k0 += GK) {
        if (TA == 0) {
            const int k = tid & 31, mb = tid >> 5;
            #pragma unroll
            for (int p = 0; p < 8; ++p) {
                int m = mb + p * 8; int gr = row0 + m;
                As[k][m] = (gr < M) ? A[(size_t)gr * K + (k0 + k)] : 0.f;
            }
        } else {
            const int m = tid & 63, kb = tid >> 6;
            #pragma unroll
            for (int p = 0; p < 8; ++p) {
                int k = kb + p * 4; int gm = row0 + m;
                As[k][m] = (gm < M) ? A[(size_t)(k0 + k) * M + gm] : 0.f;
            }
        }
        if (TB == 0) {
            const int k = tid & 31, nb = tid >> 5;
            #pragma unroll
            for (int p = 0; p < 8; ++p) {
                int n = nb + p * 8; int gn = col0 + n;
                Bs[k][n] = (gn < N) ? B[(size_t)gn * K + (k0 + k)] : 0.f;
            }
        } else {
            const int n = tid & 63, kb = tid >> 6;
            #pragma unroll
            for (int p = 0; p < 8; ++p) {
                int k = kb + p * 4; int gn = col0 + n;
                Bs[k][n] = (gn < N) ? B[(size_t)(k0 + k) * N + gn] : 0.f;
            }
        }
        __syncthreads();
        #pragma unroll
        for (int kk = 0; kk < GK; ++kk) {
            float a[4], b[4];
            #pragma unroll
            for (int i = 0; i < 4; ++i) a[i] = As[kk][ty * 4 + i];
            #pragma unroll
            for (int j = 0; j < 4; ++j) b[j] = Bs[kk][tx * 4 + j];
            #pragma unroll
            for (int i = 0; i < 4; ++i)
                #pragma unroll
                for (int j = 0; j < 4; ++j)
                    acc[i][j] = fmaf(a[i], b[j], acc[i][j]);
        }
        __syncthreads();
    }
    #pragma unroll
    for (int i = 0; i < 4; ++i) {
        int r = row0 + ty * 4 + i;
        if (r >= M) continue;
        #pragma unroll
        for (int j = 0; j < 4; ++j) {
            int c = col0 + tx * 4 + j;
            if (c >= N) continue;
            float v = alpha * acc[i][j];
            if (bias) v += bias[c];
            if (add)  v += add_scale * add[(size_t)r * N + c];
            C[(size_t)r * N + c] = v;
        }
    }
}

static void gemm(hipStream_t s, int ta, int tb,
                 const float* A, const float* B, float* C,
                 int M, int N, int K, const float* bias = nullptr,
                 const float* add = nullptr, float add_scale = 0.f, float alpha = 1.f)
{
    dim3 g((N + GT - 1) / GT, (M + GT - 1) / GT), blk(256);
    if (ta == 0 && tb == 0)      gemm_k<0,0><<<g, blk, 0, s>>>(A,B,C,M,N,K,bias,add,add_scale,alpha);
    else if (ta == 0 && tb == 1) gemm_k<0,1><<<g, blk, 0, s>>>(A,B,C,M,N,K,bias,add,add_scale,alpha);
    else                         gemm_k<1,1><<<g, blk, 0, s>>>(A,B,C,M,N,K,bias,add,add_scale,alpha);
}

// ---------------- split-bf16 MFMA GEMM:  C = act(A @ W^T + bias) ----------------
// A as (Ah,Al) bf16 [M,K]; W as (Wh,Wl) bf16 [N,K].  N % 128 == 0, K % 32 == 0.
// Tile 128x128, BK=32, 4 waves (2x2), 16x16x32 MFMA, 3-product split (hh + hl + lh).
__device__ __forceinline__ void gload_lds16(const u16* g, u16* l) {
    __builtin_amdgcn_global_load_lds(
        (const __attribute__((address_space(1))) unsigned int*)g,
        (__attribute__((address_space(3))) unsigned int*)l, 16, 0, 0);
}

template<int ACTF, int WF32, int WSPLIT>
__global__ __launch_bounds__(256)
void gemm_mfma_k(const u16* __restrict__ Ah, const u16* __restrict__ Al,
                 const u16* __restrict__ Wh, const u16* __restrict__ Wl,
                 float* __restrict__ C, u16* __restrict__ Chi, u16* __restrict__ Clo,
                 int M, int N, int K, const float* __restrict__ bias)
{
    __shared__ u16 lds[16384];                 // 4 tiles x [128][32] bf16 = 32 KB
    const int tid = threadIdx.x;
    const int lane = tid & 63, wid = tid >> 6;
    const int wm = wid >> 1, wn = wid & 1;
    const int row0 = blockIdx.y * 128, col0 = blockIdx.x * 128;

    // staging map: wave `wid` fills tile `wid` (0:Ah 1:Al 2:Wh 3:Wl)
    const u16* sp = (wid == 0) ? Ah : (wid == 1) ? Al : (wid == 2) ? Wh : Wl;
    const int rbase = (wid < 2) ? row0 : col0;
    const int lr = lane >> 2, lc = lane & 3;

    f32x4 acc[4][4] = {};

    const int frow = lane & 15, kblk = lane >> 4;

    for (int k0 = 0; k0 < K; k0 += 32) {
        #pragma unroll
        for (int i = 0; i < 8; ++i) {
            int r = i * 16 + lr;
            int gr = rbase + r;
            if (wid < 2 && gr >= M) gr = M - 1;           // clamp (N always %128)
            int g = lc ^ ((r >> 1) & 3);                   // pre-swizzled source chunk
            gload_lds16(sp + (size_t)gr * K + k0 + g * 8, &lds[wid * 4096 + i * 512]);
        }
        __syncthreads();                                   // drains vmcnt

        s16x8 bh[4], bl[4];
        #pragma unroll
        for (int ni = 0; ni < 4; ++ni) {
            int br = wn * 64 + ni * 16 + frow;
            int pc = kblk ^ ((br >> 1) & 3);
            bh[ni] = *(const s16x8*)&lds[2 * 4096 + br * 32 + pc * 8];
            bl[ni] = *(const s16x8*)&lds[3 * 4096 + br * 32 + pc * 8];
        }
        #pragma unroll
        for (int mi = 0; mi < 4; ++mi) {
            int ar = wm * 64 + mi * 16 + frow;
            int pc = kblk ^ ((ar >> 1) & 3);
            s16x8 ah = *(const s16x8*)&lds[0 * 4096 + ar * 32 + pc * 8];
            s16x8 al = *(const s16x8*)&lds[1 * 4096 + ar * 32 + pc * 8];
            #pragma unroll
            for (int ni = 0; ni < 4; ++ni) {
                acc[mi][ni] = __builtin_amdgcn_mfma_f32_16x16x32_bf16(ah, bh[ni], acc[mi][ni], 0, 0, 0);
                acc[mi][ni] = __builtin_amdgcn_mfma_f32_16x16x32_bf16(ah, bl[ni], acc[mi][ni], 0, 0, 0);
                acc[mi][ni] = __builtin_amdgcn_mfma_f32_16x16x32_bf16(al, bh[ni], acc[mi][ni], 0, 0, 0);
            }
        }
        __syncthreads();
    }

    const int erow = (lane >> 4) * 4, ecol = lane & 15;
    #pragma unroll
    for (int mi = 0; mi < 4; ++mi) {
        #pragma unroll
        for (int ni = 0; ni < 4; ++ni) {
            int c = col0 + wn * 64 + ni * 16 + ecol;
            float bv = bias ? bias[c] : 0.f;
            #pragma unroll
            for (int reg = 0; reg < 4; ++reg) {
                int r = row0 + wm * 64 + mi * 16 + erow + reg;
                if (r >= M) continue;
                float v = acc[mi][ni][reg] + bv;
                if (ACTF == 1) v = v / (1.f + __expf(-v));                 // silu
                else if (ACTF == 2) {                                      // gelu tanh
                    float u = 0.7978845608028654f * (v + 0.044715f * v * v * v);
                    v = 0.5f * v * (1.f + tanhf(u));
                }
                size_t o = (size_t)r * N + c;
                if (WF32) C[o] = v;
                if (WSPLIT) { u16 h, l; split2(v, h, l); Chi[o] = h; Clo[o] = l; }
            }
        }
    }
}

static void gemm_mfma(hipStream_t s, int act, int wf32, int wsplit,
                      const u16* Ah, const u16* Al, const u16* Wh, const u16* Wl,
                      float* C, u16* Ch, u16* Cl, int M, int N, int K, const float* bias)
{
    dim3 g(N / 128, (M + 127) / 128), b(256);
    if (act == 0 && wf32 == 1 && wsplit == 0)
        gemm_mfma_k<0,1,0><<<g,b,0,s>>>(Ah,Al,Wh,Wl,C,Ch,Cl,M,N,K,bias);
    else if (act == 0 && wf32 == 1 && wsplit == 1)
        gemm_mfma_k<0,1,1><<<g,b,0,s>>>(Ah,Al,Wh,Wl,C,Ch,Cl,M,N,K,bias);
    else if (act == 0 && wf32 == 0 && wsplit == 1)
        gemm_mfma_k<0,0,1><<<g,b,0,s>>>(Ah,Al,Wh,Wl,C,Ch,Cl,M,N,K,bias);
    else if (act == 1)
        gemm_mfma_k<1,0,1><<<g,b,0,s>>>(Ah,Al,Wh,Wl,C,Ch,Cl,M,N,K,bias);
    else
        gemm_mfma_k<2,0,1><<<g,b,0,s>>>(Ah,Al,Wh,Wl,C,Ch,Cl,M,N,K,bias);
}

// ---------------- small kernels ----------------
__global__ void cvt_split_k(const float* __restrict__ in, u16* __restrict__ hi,
                            u16* __restrict__ lo, int n4) {
    int i = blockIdx.x * 256 + threadIdx.x;
    if (i >= n4) return;
    float4 v = *(const float4*)&in[(size_t)i * 4];
    u16 h0,l0,h1,l1,h2,l2,h3,l3;
    split2(v.x,h0,l0); split2(v.y,h1,l1); split2(v.z,h2,l2); split2(v.w,h3,l3);
    ushort4 hv = {h0,h1,h2,h3}, lv = {l0,l1,l2,l3};
    *(ushort4*)&hi[(size_t)i * 4] = hv;
    *(ushort4*)&lo[(size_t)i * 4] = lv;
}
__global__ void silu_elt_k(const float* __restrict__ z, float* __restrict__ h, int n) {
    int i = blockIdx.x * 256 + threadIdx.x;
    if (i < n) { float v = z[i]; h[i] = v / (1.f + __expf(-v)); }
}
__global__ void silubwd_k(const float* __restrict__ z, float* __restrict__ dh, int n) {
    int i = blockIdx.x * 256 + threadIdx.x;
    if (i < n) {
        float v = z[i];
        float sg = 1.f / (1.f + __expf(-v));
        dh[i] *= sg * (1.f + v * (1.f - sg));
    }
}
__global__ void colsum_k(const float* __restrict__ X, float* __restrict__ out,
                         int M, int N, float alpha) {
    int j = blockIdx.x * 256 + threadIdx.x;
    if (j >= N) return;
    float s = 0.f;
    for (int m = 0; m < M; ++m) s += X[(size_t)m * N + j];
    out[j] = alpha * s;
}
__global__ void update_k(float* __restrict__ p, float* __restrict__ mo,
                         const float* __restrict__ g, int n) {
    int i = blockIdx.x * 256 + threadIdx.x;
    if (i < n) {
        float m = ETA_C * mo[i] - THETA_C * g[i];
        mo[i] = m;
        p[i] = (1.f - ALPHA_C) * p[i] + m;
    }
}
__global__ void extractqkv2_k(const float* __restrict__ qkv, u16* __restrict__ Qh,
                              u16* __restrict__ Ql, float* __restrict__ Kb,
                              float* __restrict__ Vb) {
    size_t idx = (size_t)blockIdx.x * 256 + threadIdx.x;   // 2048*3072
    int m = (int)(idx / 3072), col = (int)(idx % 3072);
    int b = m >> 10, t = m & 1023;
    float v = qkv[idx];
    if (col < 1024) {
        size_t o = (size_t)m * 1024 + col;
        u16 h, l; split2(v, h, l); Qh[o] = h; Ql[o] = l;
    } else {
        int d = col & 1023;
        int ch = t >> 7, r = t & 127;
        size_t o = ((size_t)((ch * 2 + b) * 128 + r)) * 1024 + d;
        if (col < 2048) Kb[o] = v; else Vb[o] = v;
    }
}
__global__ void tokens_split_k(const float* __restrict__ P, const float* __restrict__ memtok,
                               const float* __restrict__ x, u16* __restrict__ th,
                               u16* __restrict__ tl) {
    size_t idx = (size_t)blockIdx.x * 256 + threadIdx.x;   // 4128*1024
    int d = (int)(idx & 1023);
    int n = (int)((idx >> 10) % NTOK);
    int b = (int)(idx / ((size_t)NTOK * 1024));
    float v;
    if (n < NPERS)            v = P[(size_t)n * 1024 + d];
    else if (n < NPERS + TSEQ) v = memtok[((size_t)b * TSEQ + (n - NPERS)) * 1024 + d];
    else                      v = x[((size_t)b * TSEQ + (n - NPERS - TSEQ)) * 1024 + d];
    u16 h, l; split2(v, h, l); th[idx] = h; tl[idx] = l;
}
__global__ void mul_k(const float* __restrict__ a, const float* __restrict__ b,
                      float* __restrict__ o, int n) {
    int i = blockIdx.x * 256 + threadIdx.x;
    if (i < n) o[i] = a[i] * b[i];
}

// ---------------- flash attention (fp32, causal, dh=64, q-rows 1040..2063) ----------
// grid (16, 16, 2), block 256.  aqkv [B*2064, 3072]; out split bf16 compact [2048,1024]
__global__ __launch_bounds__(256)
void flash_k(const float* __restrict__ aqkv, u16* __restrict__ oh, u16* __restrict__ ol)
{
    __shared__ float Qs[64][65];
    __shared__ float Ks[64][65];
    __shared__ float Vs[64][65];
    __shared__ float Ps[64][65];
    const int qt = blockIdx.x, h = blockIdx.y, b = blockIdx.z;
    const int tid = threadIdx.x;
    const int tx = tid & 15, ty = tid >> 4;
    const int q0 = NPERS + TSEQ + qt * 64;       // 1040 + 64*qt
    const size_t base = (size_t)b * NTOK * 3072 + (size_t)h * 64;

    {
        int d = tid & 63, rb = tid >> 6;
        #pragma unroll
        for (int p = 0; p < 16; ++p) {
            int r = rb * 16 + p;
            Qs[r][d] = 0.125f * aqkv[base + (size_t)(q0 + r) * 3072 + d];
        }
    }
    float Oa[4][4] = {{0.f}};
    float mrow[4], lrow[4];
    #pragma unroll
    for (int i = 0; i < 4; ++i) { mrow[i] = -INFINITY; lrow[i] = 0.f; }
    __syncthreads();

    const int jtmax = (q0 + 63) >> 6;
    for (int jt = 0; jt <= jtmax; ++jt) {
        const int j0 = jt * 64;
        {
            int d = tid & 63, rb = tid >> 6;
            #pragma unroll
            for (int p = 0; p < 16; ++p) {
                int r = rb * 16 + p;
                int n = j0 + r;
                if (n < NTOK) {
                    Ks[r][d] = aqkv[base + (size_t)n * 3072 + 1024 + d];
                    Vs[r][d] = aqkv[base + (size_t)n * 3072 + 2048 + d];
                } else { Ks[r][d] = 0.f; Vs[r][d] = 0.f; }
            }
        }
        __syncthreads();

        float s[4][4] = {{0.f}};
        #pragma unroll 8
        for (int d = 0; d < 64; ++d) {
            float a[4], bb[4];
            #pragma unroll
            for (int i = 0; i < 4; ++i) a[i] = Qs[ty * 4 + i][d];
            #pragma unroll
            for (int j = 0; j < 4; ++j) bb[j] = Ks[tx * 4 + j][d];
            #pragma unroll
            for (int i = 0; i < 4; ++i)
                #pragma unroll
                for (int j = 0; j < 4; ++j)
                    s[i][j] = fmaf(a[i], bb[j], s[i][j]);
        }
        #pragma unroll
        for (int i = 0; i < 4; ++i) {
            int qi = q0 + ty * 4 + i;
            float tmax = -INFINITY;
            #pragma unroll
            for (int j = 0; j < 4; ++j) {
                int kj = j0 + tx * 4 + j;
                if (kj > qi) s[i][j] = -INFINITY;
                tmax = fmaxf(tmax, s[i][j]);
            }
            #pragma unroll
            for (int off = 1; off < 16; off <<= 1)
                tmax = fmaxf(tmax, __shfl_xor(tmax, off));
            float mnew = fmaxf(mrow[i], tmax);
            float scale = __expf(mrow[i] - mnew);
            float p4[4], psum = 0.f;
            #pragma unroll
            for (int j = 0; j < 4; ++j) { p4[j] = __expf(s[i][j] - mnew); psum += p4[j]; }
            #pragma unroll
            for (int off = 1; off < 16; off <<= 1)
                psum += __shfl_xor(psum, off);
            lrow[i] = lrow[i] * scale + psum;
            mrow[i] = mnew;
            #pragma unroll
            for (int j = 0; j < 4; ++j) Oa[i][j] *= scale;
            #pragma unroll
            for (int j = 0; j < 4; ++j) Ps[ty * 4 + i][tx * 4 + j] = p4[j];
        }
        __syncthreads();
        #pragma unroll 8
        for (int kk = 0; kk < 64; ++kk) {
            float pv[4], vv[4];
            #pragma unroll
            for (int i = 0; i < 4; ++i) pv[i] = Ps[ty * 4 + i][kk];
            #pragma unroll
            for (int j = 0; j < 4; ++j) vv[j] = Vs[kk][tx * 4 + j];
            #pragma unroll
            for (int i = 0; i < 4; ++i)
                #pragma unroll
                for (int j = 0; j < 4; ++j)
                    Oa[i][j] = fmaf(pv[i], vv[j], Oa[i][j]);
        }
        __syncthreads();
    }

    #pragma unroll
    for (int i = 0; i < 4; ++i) {
        float inv = 1.f / lrow[i];
        #pragma unroll
        for (int j = 0; j < 4; ++j) {
            float v = Oa[i][j] * inv;
            size_t o = ((size_t)(b * 1024 + qt * 64 + ty * 4 + i)) * 1024 + h * 64 + tx * 4 + j;
            u16 hh, ll; split2(v, hh, ll); oh[o] = hh; ol[o] = ll;
        }
    }
}

// ---------------- launch ----------------
extern "C" void kernel_launch(void* const* d_in, const int* in_sizes, int n_in,
                              void* d_out, int out_size, void* d_ws, size_t ws_size,
                              hipStream_t stream)
{
    const float* x     = (const float*)d_in[0];
    const float* Wqkv  = (const float*)d_in[1];
    const float* mW1   = (const float*)d_in[2];
    const float* mb1   = (const float*)d_in[3];
    const float* mW2   = (const float*)d_in[4];
    const float* mb2   = (const float*)d_in[5];
    const float* Pp    = (const float*)d_in[6];
    const float* Wqa   = (const float*)d_in[7];
    const float* Wo    = (const float*)d_in[8];
    const float* ffW1  = (const float*)d_in[9];
    const float* ffb1  = (const float*)d_in[10];
    const float* ffW2  = (const float*)d_in[11];
    const float* ffb2  = (const float*)d_in[12];
    char* wsb = (char*)d_ws;
    float* outp = (float*)d_out;

    // region A (multiplexed)
    float* qkv   = (float*)(wsb + oRA);
    float* z1    = (float*)(wsb + oRA);
    float* hbuf  = (float*)(wsb + oRA + 524288);
    float* rbuf  = (float*)(wsb + oRA + 1048576);
    float* dhb   = (float*)(wsb + oRA + 2097152);
    float* grd   = (float*)(wsb + oRA + 7346176);
    float* aqkv  = (float*)(wsb + oRA);
    u16* Woh     = (u16*)(wsb + oRA);
    u16* Wol     = (u16*)(wsb + oRA + 2097152);
    u16* ffhh    = (u16*)(wsb + oRA);
    u16* ffhl    = (u16*)(wsb + oRA + 16777216);
    u16* outbh   = (u16*)(wsb + oRA + 33554432);
    u16* outbl   = (u16*)(wsb + oRA + 37748736);
    u16* newQh   = (u16*)(wsb + oRA);
    u16* newQl   = (u16*)(wsb + oRA + 4194304);
    u16* hzh     = (u16*)(wsb + oRA + 8388608);
    u16* hzl     = (u16*)(wsb + oRA + 10485760);
    float* memq  = (float*)(wsb + oRA + 12582912);
    // region B
    float* Kb    = (float*)(wsb + oRB);
    float* Vb    = (float*)(wsb + oRB + 8388608);
    u16* tokh    = (u16*)(wsb + oRB);
    u16* tokl    = (u16*)(wsb + oRB + 8454144);
    u16* oh      = (u16*)(wsb + oRB);
    u16* ol      = (u16*)(wsb + oRB + 4194304);
    u16* y1h     = (u16*)(wsb + oRB + 8388608);
    u16* y1l     = (u16*)(wsb + oRB + 12582912);
    // region C (time-multiplexed: xh/xl -> mom -> Wqah/Wqal)
    u16* xh      = (u16*)(wsb + oRC);
    u16* xl      = (u16*)(wsb + oRC + 4194304);
    float* mom   = (float*)(wsb + oRC);            // alive only during the scan
    u16* Wqah    = (u16*)(wsb + oRC);
    u16* Wqal    = (u16*)(wsb + oRC + 6291456);
    // region D
    u16* Qh      = (u16*)(wsb + oRD);
    u16* Ql      = (u16*)(wsb + oRD + 4194304);
    u16* t1h     = (u16*)(wsb + oRD + 8388608);
    u16* t1l     = (u16*)(wsb + oRD + 10485760);
    float* memtok= (float*)(wsb + oRD);
    u16* ffW1h   = (u16*)(wsb + oRD);
    u16* ffW1l   = (u16*)(wsb + oRD + 8388608);
    u16* ffW2h   = (u16*)(wsb + oRD);
    u16* ffW2l   = (u16*)(wsb + oRD + 8388608);
    // persistent
    u16* Wqkvh   = (u16*)(wsb + oRE);
    u16* Wqkvl   = (u16*)(wsb + oRE + 6291456);
    u16* pW1h    = (u16*)(wsb + oRF);
    u16* pW1l    = (u16*)(wsb + oRF + 1048576);
    u16* pW2h    = (u16*)(wsb + oRF + 2097152);
    u16* pW2l    = (u16*)(wsb + oRF + 3145728);
    float* par   = (float*)(wsb + oRG);
    float* outb  = (float*)(wsb + oRH);

    // init memory-MLP params (par is a dedicated region; mom is zeroed later,
    // AFTER region C's xh/xl are dead -- placing the memset here would be clobbered)
    hipMemcpyAsync(par + PW1, mW1, 524288 * sizeof(float), hipMemcpyDeviceToDevice, stream);
    hipMemcpyAsync(par + PB1, mb1, 512 * sizeof(float), hipMemcpyDeviceToDevice, stream);
    hipMemcpyAsync(par + PW2, mW2, 524288 * sizeof(float), hipMemcpyDeviceToDevice, stream);
    hipMemcpyAsync(par + PB2, mb2, 1024 * sizeof(float), hipMemcpyDeviceToDevice, stream);

    // qkv = x @ Wqkv^T
    cvt_split_k<<<2048, 256, 0, stream>>>(x, xh, xl, 524288);
    cvt_split_k<<<3072, 256, 0, stream>>>(Wqkv, Wqkvh, Wqkvl, 786432);
    gemm_mfma(stream, 0, 1, 0, xh, xl, Wqkvh, Wqkvl, qkv, nullptr, nullptr, 2048, 3072, 1024, nullptr);
    extractqkv2_k<<<24576, 256, 0, stream>>>(qkv, Qh, Ql, Kb, Vb);

    // momentum = 0 (region C now free: xh/xl consumed by the qkv gemm above)
    hipMemsetAsync(mom, 0, PSZ * sizeof(float), stream);

    // memory scan (fp32)
    const float cs = 2.f / (float)(BATCH * 128 * DIMD);
    for (int c = 0; c < NCH; ++c) {
        const float* kc = Kb + (size_t)c * 262144;
        const float* vc = Vb + (size_t)c * 262144;
        gemm(stream, 0, 0, kc, par + PW1, z1, 256, 512, 1024, par + PB1);
        silu_elt_k<<<512, 256, 0, stream>>>(z1, hbuf, 131072);
        gemm(stream, 0, 0, hbuf, par + PW2, rbuf, 256, 1024, 512, par + PB2, vc, -1.f);
        gemm(stream, 1, 1, rbuf, hbuf, grd + PW2, 1024, 512, 256, nullptr, nullptr, 0.f, cs);
        colsum_k<<<4, 256, 0, stream>>>(rbuf, grd + PB2, 256, 1024, cs);
        gemm(stream, 0, 1, rbuf, par + PW2, dhb, 256, 512, 1024, nullptr, nullptr, 0.f, cs);
        silubwd_k<<<512, 256, 0, stream>>>(z1, dhb, 131072);
        gemm(stream, 1, 1, dhb, kc, grd + PW1, 512, 1024, 256);
        colsum_k<<<2, 256, 0, stream>>>(dhb, grd + PB1, 256, 512, 1.f);
        update_k<<<4102, 256, 0, stream>>>(par, mom, grd, (int)PSZ);
    }

    // memory readout (split-bf16 MFMA)
    cvt_split_k<<<512, 256, 0, stream>>>(par + PW1, pW1h, pW1l, 131072);
    cvt_split_k<<<512, 256, 0, stream>>>(par + PW2, pW2h, pW2l, 131072);
    gemm_mfma(stream, 1, 0, 1, Qh, Ql, pW1h, pW1l, nullptr, t1h, t1l, 2048, 512, 1024, par + PB1);
    gemm_mfma(stream, 0, 1, 0, t1h, t1l, pW2h, pW2l, memtok, nullptr, nullptr, 2048, 1024, 512, par + PB2);

    // tokens (split) + attention qkv
    tokens_split_k<<<16512, 256, 0, stream>>>(Pp, memtok, x, tokh, tokl);
    cvt_split_k<<<3072, 256, 0, stream>>>(Wqa, Wqah, Wqal, 786432);
    gemm_mfma(stream, 0, 1, 0, tokh, tokl, Wqah, Wqal, aqkv, nullptr, nullptr, 4128, 3072, 1024, nullptr);

    // flash attention, q-rows restricted to the x block
    flash_k<<<dim3(16, 16, 2), 256, 0, stream>>>(aqkv, oh, ol);

    // Wo projection + FFN (M = 2048 compact rows)
    cvt_split_k<<<1024, 256, 0, stream>>>(Wo, Woh, Wol, 262144);
    gemm_mfma(stream, 0, 0, 1, oh, ol, Woh, Wol, nullptr, y1h, y1l, 2048, 1024, 1024, nullptr);
    cvt_split_k<<<4096, 256, 0, stream>>>(ffW1, ffW1h, ffW1l, 1048576);
    gemm_mfma(stream, 2, 0, 1, y1h, y1l, ffW1h, ffW1l, nullptr, ffhh, ffhl, 2048, 4096, 1024, ffb1);
    cvt_split_k<<<4096, 256, 0, stream>>>(ffW2, ffW2h, ffW2l, 1048576);
    gemm_mfma(stream, 0, 1, 1, ffhh, ffhl, ffW2h, ffW2l, outb, outbh, outbl, 2048, 1024, 4096, ffb2);

    // gate: newQ = out @ Wqkv_Q^T ; memq = mem_read(newQ) ; out *= memq
    gemm_mfma(stream, 0, 0, 1, outbh, outbl, Wqkvh, Wqkvl, nullptr, newQh, newQl, 2048, 1024, 1024, nullptr);
    gemm_mfma(stream, 1, 0, 1, newQh, newQl, pW1h, pW1l, nullptr, hzh, hzl, 2048, 512, 1024, par + PB1);
    gemm_mfma(stream, 0, 1, 0, hzh, hzl, pW2h, pW2l, memq, nullptr, nullptr, 2048, 1024, 512, par + PB2);
    mul_k<<<8192, 256, 0, stream>>>(outb, memq, outp, 2097152);
}

// Round 4
// 3420.169 us; speedup vs baseline: 2.9254x; 1.6328x over previous
//
#include <hip/hip_runtime.h>
#include <math.h>

// ---------------- problem constants ----------------
#define BATCH 2
#define TSEQ 1024
#define DIMD 1024
#define NPERS 16
#define NCH 8
#define NTOK 2064
#define ETA_C 0.9f
#define THETA_C 0.1f
#define ALPHA_C 0.02f

typedef __attribute__((ext_vector_type(4))) float f32x4;
typedef __attribute__((ext_vector_type(8))) short s16x8;
typedef unsigned short u16;

// ---------------- bf16 helpers ----------------
__device__ __forceinline__ u16 f2bf(float f) {
    unsigned int u = __float_as_uint(f);
    return (u16)((u + 0x7fffu + ((u >> 16) & 1u)) >> 16);
}
__device__ __forceinline__ float bf2f(u16 h) { return __uint_as_float(((unsigned)h) << 16); }
__device__ __forceinline__ void split2(float v, u16& h, u16& l) {
    h = f2bf(v); l = f2bf(v - bf2f(h));
}

// ---------------- workspace layout (byte offsets) ----------------
static const size_t oRA = 0;                       // 50,724,864 multiplexed
static const size_t oRB = 50724864;                // 16,908,288
static const size_t oRC = 67633152;                // 12,582,912
static const size_t oRD = 80216064;                // 16,777,216
static const size_t oRE = 96993280;                // 12,582,912 Wqkv h/l (persistent)
static const size_t oRF = 109576192;               //  4,194,304 parW h/l (persistent)
static const size_t oRG = 113770496;               //  4,200,448 par (persistent)
static const size_t oRH = 117970944;               //  8,388,608 outb f32
// total 126,359,552 bytes

static const size_t PW1 = 0, PB1 = 524288, PW2 = 524800, PB2 = 1049088, PSZ = 1050112;

// ---------------- async global->LDS ----------------
__device__ __forceinline__ void gload_lds16(const u16* g, u16* l) {
    __builtin_amdgcn_global_load_lds(
        (const __attribute__((address_space(1))) unsigned int*)g,
        (__attribute__((address_space(3))) unsigned int*)l, 16, 0, 0);
}

// ---------------- split-bf16 MFMA GEMM:  C = act(A @ W^T + bias)  (main path) ----
// A as (Ah,Al) bf16 [M,K]; W as (Wh,Wl) bf16 [N,K].  N % 128 == 0, K % 32 == 0.
// Tile 128x128, BK=32, 4 waves (2x2), 16x16x32 MFMA, 3-product split (hh + hl + lh).
template<int ACTF, int WF32, int WSPLIT>
__global__ __launch_bounds__(256)
void gemm_mfma_k(const u16* __restrict__ Ah, const u16* __restrict__ Al,
                 const u16* __restrict__ Wh, const u16* __restrict__ Wl,
                 float* __restrict__ C, u16* __restrict__ Chi, u16* __restrict__ Clo,
                 int M, int N, int K, const float* __restrict__ bias)
{
    __shared__ u16 lds[16384];                 // 4 tiles x [128][32] bf16 = 32 KB
    const int tid = threadIdx.x;
    const int lane = tid & 63, wid = tid >> 6;
    const int wm = wid >> 1, wn = wid & 1;
    const int row0 = blockIdx.y * 128, col0 = blockIdx.x * 128;

    const u16* sp = (wid == 0) ? Ah : (wid == 1) ? Al : (wid == 2) ? Wh : Wl;
    const int rbase = (wid < 2) ? row0 : col0;
    const int lr = lane >> 2, lc = lane & 3;

    f32x4 acc[4][4] = {};
    const int frow = lane & 15, kblk = lane >> 4;

    for (int k0 = 0; k0 < K; k0 += 32) {
        #pragma unroll
        for (int i = 0; i < 8; ++i) {
            int r = i * 16 + lr;
            int gr = rbase + r;
            if (wid < 2 && gr >= M) gr = M - 1;
            int g = lc ^ ((r >> 1) & 3);
            gload_lds16(sp + (size_t)gr * K + k0 + g * 8, &lds[wid * 4096 + i * 512]);
        }
        __syncthreads();

        s16x8 bh[4], bl[4];
        #pragma unroll
        for (int ni = 0; ni < 4; ++ni) {
            int br = wn * 64 + ni * 16 + frow;
            int pc = kblk ^ ((br >> 1) & 3);
            bh[ni] = *(const s16x8*)&lds[2 * 4096 + br * 32 + pc * 8];
            bl[ni] = *(const s16x8*)&lds[3 * 4096 + br * 32 + pc * 8];
        }
        #pragma unroll
        for (int mi = 0; mi < 4; ++mi) {
            int ar = wm * 64 + mi * 16 + frow;
            int pc = kblk ^ ((ar >> 1) & 3);
            s16x8 ah = *(const s16x8*)&lds[0 * 4096 + ar * 32 + pc * 8];
            s16x8 al = *(const s16x8*)&lds[1 * 4096 + ar * 32 + pc * 8];
            #pragma unroll
            for (int ni = 0; ni < 4; ++ni) {
                acc[mi][ni] = __builtin_amdgcn_mfma_f32_16x16x32_bf16(ah, bh[ni], acc[mi][ni], 0, 0, 0);
                acc[mi][ni] = __builtin_amdgcn_mfma_f32_16x16x32_bf16(ah, bl[ni], acc[mi][ni], 0, 0, 0);
                acc[mi][ni] = __builtin_amdgcn_mfma_f32_16x16x32_bf16(al, bh[ni], acc[mi][ni], 0, 0, 0);
            }
        }
        __syncthreads();
    }

    const int erow = (lane >> 4) * 4, ecol = lane & 15;
    #pragma unroll
    for (int mi = 0; mi < 4; ++mi) {
        #pragma unroll
        for (int ni = 0; ni < 4; ++ni) {
            int c = col0 + wn * 64 + ni * 16 + ecol;
            float bv = bias ? bias[c] : 0.f;
            #pragma unroll
            for (int reg = 0; reg < 4; ++reg) {
                int r = row0 + wm * 64 + mi * 16 + erow + reg;
                if (r >= M) continue;
                float v = acc[mi][ni][reg] + bv;
                if (ACTF == 1) v = v / (1.f + __expf(-v));                 // silu
                else if (ACTF == 2) {                                      // gelu tanh
                    float u = 0.7978845608028654f * (v + 0.044715f * v * v * v);
                    v = 0.5f * v * (1.f + tanhf(u));
                }
                size_t o = (size_t)r * N + c;
                if (WF32) C[o] = v;
                if (WSPLIT) { u16 h, l; split2(v, h, l); Chi[o] = h; Clo[o] = l; }
            }
        }
    }
}

static void gemm_mfma(hipStream_t s, int act, int wf32, int wsplit,
                      const u16* Ah, const u16* Al, const u16* Wh, const u16* Wl,
                      float* C, u16* Ch, u16* Cl, int M, int N, int K, const float* bias)
{
    dim3 g(N / 128, (M + 127) / 128), b(256);
    if (act == 0 && wf32 == 1 && wsplit == 0)
        gemm_mfma_k<0,1,0><<<g,b,0,s>>>(Ah,Al,Wh,Wl,C,Ch,Cl,M,N,K,bias);
    else if (act == 0 && wf32 == 1 && wsplit == 1)
        gemm_mfma_k<0,1,1><<<g,b,0,s>>>(Ah,Al,Wh,Wl,C,Ch,Cl,M,N,K,bias);
    else if (act == 0 && wf32 == 0 && wsplit == 1)
        gemm_mfma_k<0,0,1><<<g,b,0,s>>>(Ah,Al,Wh,Wl,C,Ch,Cl,M,N,K,bias);
    else if (act == 1)
        gemm_mfma_k<1,0,1><<<g,b,0,s>>>(Ah,Al,Wh,Wl,C,Ch,Cl,M,N,K,bias);
    else
        gemm_mfma_k<2,0,1><<<g,b,0,s>>>(Ah,Al,Wh,Wl,C,Ch,Cl,M,N,K,bias);
}

// ---------------- scan-specialized split-bf16 MFMA GEMM ----------------
// Same main loop; epilogue MODE:
//  1: z1 = A@B^T + bias; write z1 f32; h=silu(z1) -> split + splitT
//  2: r = A@B^T + bias - add; write r f32; split + splitT
//  3: C = alpha * A@B^T  (f32 only)
//  4: dh = alpha*(A@B^T) * dsilu(Z); write dh f32; splitT only
template<int MODE>
__global__ __launch_bounds__(256)
void gemm_scan_k(const u16* __restrict__ Ah, const u16* __restrict__ Al,
                 const u16* __restrict__ Wh, const u16* __restrict__ Wl,
                 float* __restrict__ C, u16* __restrict__ Chi, u16* __restrict__ Clo,
                 u16* __restrict__ ChiT, u16* __restrict__ CloT,
                 const float* __restrict__ Zf, const float* __restrict__ add,
                 const float* __restrict__ bias, int M, int N, int K, float alpha)
{
    __shared__ u16 lds[16384];
    const int tid = threadIdx.x;
    const int lane = tid & 63, wid = tid >> 6;
    const int wm = wid >> 1, wn = wid & 1;
    const int row0 = blockIdx.y * 128, col0 = blockIdx.x * 128;

    const u16* sp = (wid == 0) ? Ah : (wid == 1) ? Al : (wid == 2) ? Wh : Wl;
    const int rbase = (wid < 2) ? row0 : col0;
    const int lr = lane >> 2, lc = lane & 3;

    f32x4 acc[4][4] = {};
    const int frow = lane & 15, kblk = lane >> 4;

    for (int k0 = 0; k0 < K; k0 += 32) {
        #pragma unroll
        for (int i = 0; i < 8; ++i) {
            int r = i * 16 + lr;
            int gr = rbase + r;                      // all scan dims are %128
            int g = lc ^ ((r >> 1) & 3);
            gload_lds16(sp + (size_t)gr * K + k0 + g * 8, &lds[wid * 4096 + i * 512]);
        }
        __syncthreads();

        s16x8 bh[4], bl[4];
        #pragma unroll
        for (int ni = 0; ni < 4; ++ni) {
            int br = wn * 64 + ni * 16 + frow;
            int pc = kblk ^ ((br >> 1) & 3);
            bh[ni] = *(const s16x8*)&lds[2 * 4096 + br * 32 + pc * 8];
            bl[ni] = *(const s16x8*)&lds[3 * 4096 + br * 32 + pc * 8];
        }
        #pragma unroll
        for (int mi = 0; mi < 4; ++mi) {
            int ar = wm * 64 + mi * 16 + frow;
            int pc = kblk ^ ((ar >> 1) & 3);
            s16x8 ah = *(const s16x8*)&lds[0 * 4096 + ar * 32 + pc * 8];
            s16x8 al = *(const s16x8*)&lds[1 * 4096 + ar * 32 + pc * 8];
            #pragma unroll
            for (int ni = 0; ni < 4; ++ni) {
                acc[mi][ni] = __builtin_amdgcn_mfma_f32_16x16x32_bf16(ah, bh[ni], acc[mi][ni], 0, 0, 0);
                acc[mi][ni] = __builtin_amdgcn_mfma_f32_16x16x32_bf16(ah, bl[ni], acc[mi][ni], 0, 0, 0);
                acc[mi][ni] = __builtin_amdgcn_mfma_f32_16x16x32_bf16(al, bh[ni], acc[mi][ni], 0, 0, 0);
            }
        }
        __syncthreads();
    }

    const int erow = (lane >> 4) * 4, ecol = lane & 15;
    #pragma unroll
    for (int mi = 0; mi < 4; ++mi) {
        #pragma unroll
        for (int ni = 0; ni < 4; ++ni) {
            int c = col0 + wn * 64 + ni * 16 + ecol;
            #pragma unroll
            for (int reg = 0; reg < 4; ++reg) {
                int r = row0 + wm * 64 + mi * 16 + erow + reg;
                float v = acc[mi][ni][reg];
                size_t o = (size_t)r * N + c;
                if (MODE == 1) {
                    v += bias[c];
                    C[o] = v;                                   // z1 pre-act
                    float hv = v / (1.f + __expf(-v));          // silu
                    u16 h, l; split2(hv, h, l);
                    Chi[o] = h; Clo[o] = l;
                    size_t ot = (size_t)c * M + r;
                    ChiT[ot] = h; CloT[ot] = l;
                } else if (MODE == 2) {
                    v += bias[c] - add[o];
                    C[o] = v;
                    u16 h, l; split2(v, h, l);
                    Chi[o] = h; Clo[o] = l;
                    size_t ot = (size_t)c * M + r;
                    ChiT[ot] = h; CloT[ot] = l;
                } else if (MODE == 3) {
                    C[o] = alpha * v;
                } else {                                        // MODE 4
                    v *= alpha;
                    float z = Zf[o];
                    float sg = 1.f / (1.f + __expf(-z));
                    v *= sg * (1.f + z * (1.f - sg));
                    C[o] = v;                                   // dh f32 (colsum)
                    u16 h, l; split2(v, h, l);
                    size_t ot = (size_t)c * M + r;
                    ChiT[ot] = h; CloT[ot] = l;
                }
            }
        }
    }
}

// ---------------- small kernels ----------------
__global__ void cvt_split_k(const float* __restrict__ in, u16* __restrict__ hi,
                            u16* __restrict__ lo, int n4) {
    int i = blockIdx.x * 256 + threadIdx.x;
    if (i >= n4) return;
    float4 v = *(const float4*)&in[(size_t)i * 4];
    u16 h0,l0,h1,l1,h2,l2,h3,l3;
    split2(v.x,h0,l0); split2(v.y,h1,l1); split2(v.z,h2,l2); split2(v.w,h3,l3);
    ushort4 hv = {h0,h1,h2,h3}, lv = {l0,l1,l2,l3};
    *(ushort4*)&hi[(size_t)i * 4] = hv;
    *(ushort4*)&lo[(size_t)i * 4] = lv;
}
// batched LDS-tiled transpose+split: in f32 [R,C] (batch stride R*C) -> out [C,R]
__global__ void transpose_split_k(const float* __restrict__ in, u16* __restrict__ outh,
                                  u16* __restrict__ outl, int R, int C) {
    __shared__ float t[32][33];
    const int c0 = blockIdx.x * 32, r0 = blockIdx.y * 32;
    const size_t zoff = (size_t)blockIdx.z * R * C;
    const int tx = threadIdx.x & 31, ty = threadIdx.x >> 5;
    #pragma unroll
    for (int p = 0; p < 4; ++p) {
        int r = ty + p * 8;
        t[r][tx] = in[zoff + (size_t)(r0 + r) * C + c0 + tx];
    }
    __syncthreads();
    #pragma unroll
    for (int p = 0; p < 4; ++p) {
        int cc = ty + p * 8;
        float v = t[tx][cc];
        u16 h, l; split2(v, h, l);
        size_t o = zoff + (size_t)(c0 + cc) * R + r0 + tx;
        outh[o] = h; outl[o] = l;
    }
}
__global__ void colsum_k(const float* __restrict__ X, float* __restrict__ out,
                         int M, int N, float alpha) {
    int j = blockIdx.x * 256 + threadIdx.x;
    if (j >= N) return;
    float s = 0.f;
    for (int m = 0; m < M; ++m) s += X[(size_t)m * N + j];
    out[j] = alpha * s;
}
// momentum update + maintain W1/W2 split forms
__global__ void update2_k(float* __restrict__ p, float* __restrict__ mo,
                          const float* __restrict__ g,
                          u16* __restrict__ w1h, u16* __restrict__ w1l,
                          u16* __restrict__ w2h, u16* __restrict__ w2l, int n) {
    int i = blockIdx.x * 256 + threadIdx.x;
    if (i >= n) return;
    float m = ETA_C * mo[i] - THETA_C * g[i];
    mo[i] = m;
    float pv = (1.f - ALPHA_C) * p[i] + m;
    p[i] = pv;
    if (i < 524288) {
        u16 h, l; split2(pv, h, l); w1h[i] = h; w1l[i] = l;
    } else if (i >= 524800 && i < 1049088) {
        int j = i - 524800;
        u16 h, l; split2(pv, h, l); w2h[j] = h; w2l[j] = l;
    }
}
__global__ void extractqkv2_k(const float* __restrict__ qkv, u16* __restrict__ Qh,
                              u16* __restrict__ Ql, float* __restrict__ Kb,
                              float* __restrict__ Vb) {
    size_t idx = (size_t)blockIdx.x * 256 + threadIdx.x;   // 2048*3072
    int m = (int)(idx / 3072), col = (int)(idx % 3072);
    int b = m >> 10, t = m & 1023;
    float v = qkv[idx];
    if (col < 1024) {
        size_t o = (size_t)m * 1024 + col;
        u16 h, l; split2(v, h, l); Qh[o] = h; Ql[o] = l;
    } else {
        int d = col & 1023;
        int ch = t >> 7, r = t & 127;
        size_t o = ((size_t)((ch * 2 + b) * 128 + r)) * 1024 + d;
        if (col < 2048) Kb[o] = v; else Vb[o] = v;
    }
}
__global__ void tokens_split_k(const float* __restrict__ P, const float* __restrict__ memtok,
                               const float* __restrict__ x, u16* __restrict__ th,
                               u16* __restrict__ tl) {
    size_t idx = (size_t)blockIdx.x * 256 + threadIdx.x;   // 4128*1024
    int d = (int)(idx & 1023);
    int n = (int)((idx >> 10) % NTOK);
    int b = (int)(idx / ((size_t)NTOK * 1024));
    float v;
    if (n < NPERS)            v = P[(size_t)n * 1024 + d];
    else if (n < NPERS + TSEQ) v = memtok[((size_t)b * TSEQ + (n - NPERS)) * 1024 + d];
    else                      v = x[((size_t)b * TSEQ + (n - NPERS - TSEQ)) * 1024 + d];
    u16 h, l; split2(v, h, l); th[idx] = h; tl[idx] = l;
}
__global__ void mul_k(const float* __restrict__ a, const float* __restrict__ b,
                      float* __restrict__ o, int n) {
    int i = blockIdx.x * 256 + threadIdx.x;
    if (i < n) o[i] = a[i] * b[i];
}

// ---------------- flash attention (fp32, causal, dh=64, q-rows 1040..2063) ----------
__global__ __launch_bounds__(256)
void flash_k(const float* __restrict__ aqkv, u16* __restrict__ oh, u16* __restrict__ ol)
{
    __shared__ float Qs[64][65];
    __shared__ float Ks[64][65];
    __shared__ float Vs[64][65];
    __shared__ float Ps[64][65];
    const int qt = blockIdx.x, h = blockIdx.y, b = blockIdx.z;
    const int tid = threadIdx.x;
    const int tx = tid & 15, ty = tid >> 4;
    const int q0 = NPERS + TSEQ + qt * 64;
    const size_t base = (size_t)b * NTOK * 3072 + (size_t)h * 64;

    {
        int d = tid & 63, rb = tid >> 6;
        #pragma unroll
        for (int p = 0; p < 16; ++p) {
            int r = rb * 16 + p;
            Qs[r][d] = 0.125f * aqkv[base + (size_t)(q0 + r) * 3072 + d];
        }
    }
    float Oa[4][4] = {{0.f}};
    float mrow[4], lrow[4];
    #pragma unroll
    for (int i = 0; i < 4; ++i) { mrow[i] = -INFINITY; lrow[i] = 0.f; }
    __syncthreads();

    const int jtmax = (q0 + 63) >> 6;
    for (int jt = 0; jt <= jtmax; ++jt) {
        const int j0 = jt * 64;
        {
            int d = tid & 63, rb = tid >> 6;
            #pragma unroll
            for (int p = 0; p < 16; ++p) {
                int r = rb * 16 + p;
                int n = j0 + r;
                if (n < NTOK) {
                    Ks[r][d] = aqkv[base + (size_t)n * 3072 + 1024 + d];
                    Vs[r][d] = aqkv[base + (size_t)n * 3072 + 2048 + d];
                } else { Ks[r][d] = 0.f; Vs[r][d] = 0.f; }
            }
        }
        __syncthreads();

        float s[4][4] = {{0.f}};
        #pragma unroll 8
        for (int d = 0; d < 64; ++d) {
            float a[4], bb[4];
            #pragma unroll
            for (int i = 0; i < 4; ++i) a[i] = Qs[ty * 4 + i][d];
            #pragma unroll
            for (int j = 0; j < 4; ++j) bb[j] = Ks[tx * 4 + j][d];
            #pragma unroll
            for (int i = 0; i < 4; ++i)
                #pragma unroll
                for (int j = 0; j < 4; ++j)
                    s[i][j] = fmaf(a[i], bb[j], s[i][j]);
        }
        #pragma unroll
        for (int i = 0; i < 4; ++i) {
            int qi = q0 + ty * 4 + i;
            float tmax = -INFINITY;
            #pragma unroll
            for (int j = 0; j < 4; ++j) {
                int kj = j0 + tx * 4 + j;
                if (kj > qi) s[i][j] = -INFINITY;
                tmax = fmaxf(tmax, s[i][j]);
            }
            #pragma unroll
            for (int off = 1; off < 16; off <<= 1)
                tmax = fmaxf(tmax, __shfl_xor(tmax, off));
            float mnew = fmaxf(mrow[i], tmax);
            float scale = __expf(mrow[i] - mnew);
            float p4[4], psum = 0.f;
            #pragma unroll
            for (int j = 0; j < 4; ++j) { p4[j] = __expf(s[i][j] - mnew); psum += p4[j]; }
            #pragma unroll
            for (int off = 1; off < 16; off <<= 1)
                psum += __shfl_xor(psum, off);
            lrow[i] = lrow[i] * scale + psum;
            mrow[i] = mnew;
            #pragma unroll
            for (int j = 0; j < 4; ++j) Oa[i][j] *= scale;
            #pragma unroll
            for (int j = 0; j < 4; ++j) Ps[ty * 4 + i][tx * 4 + j] = p4[j];
        }
        __syncthreads();
        #pragma unroll 8
        for (int kk = 0; kk < 64; ++kk) {
            float pv[4], vv[4];
            #pragma unroll
            for (int i = 0; i < 4; ++i) pv[i] = Ps[ty * 4 + i][kk];
            #pragma unroll
            for (int j = 0; j < 4; ++j) vv[j] = Vs[kk][tx * 4 + j];
            #pragma unroll
            for (int i = 0; i < 4; ++i)
                #pragma unroll
                for (int j = 0; j < 4; ++j)
                    Oa[i][j] = fmaf(pv[i], vv[j], Oa[i][j]);
        }
        __syncthreads();
    }

    #pragma unroll
    for (int i = 0; i < 4; ++i) {
        float inv = 1.f / lrow[i];
        #pragma unroll
        for (int j = 0; j < 4; ++j) {
            float v = Oa[i][j] * inv;
            size_t o = ((size_t)(b * 1024 + qt * 64 + ty * 4 + i)) * 1024 + h * 64 + tx * 4 + j;
            u16 hh, ll; split2(v, hh, ll); oh[o] = hh; ol[o] = ll;
        }
    }
}

// ---------------- launch ----------------
extern "C" void kernel_launch(void* const* d_in, const int* in_sizes, int n_in,
                              void* d_out, int out_size, void* d_ws, size_t ws_size,
                              hipStream_t stream)
{
    const float* x     = (const float*)d_in[0];
    const float* Wqkv  = (const float*)d_in[1];
    const float* mW1   = (const float*)d_in[2];
    const float* mb1   = (const float*)d_in[3];
    const float* mW2   = (const float*)d_in[4];
    const float* mb2   = (const float*)d_in[5];
    const float* Pp    = (const float*)d_in[6];
    const float* Wqa   = (const float*)d_in[7];
    const float* Wo    = (const float*)d_in[8];
    const float* ffW1  = (const float*)d_in[9];
    const float* ffb1  = (const float*)d_in[10];
    const float* ffW2  = (const float*)d_in[11];
    const float* ffb2  = (const float*)d_in[12];
    char* wsb = (char*)d_ws;
    float* outp = (float*)d_out;

    // region A (multiplexed)
    float* qkv   = (float*)(wsb + oRA);
    // scan tmps (region A, disjoint)
    float* z1    = (float*)(wsb + oRA);                 // [256,512]   0.5 MB
    float* rbuf  = (float*)(wsb + oRA + 1048576);       // [256,1024]  1 MB
    float* dhb   = (float*)(wsb + oRA + 2097152);       // [256,512]   0.5 MB
    float* grd   = (float*)(wsb + oRA + 3145728);       // PSZ         4.2 MB
    u16* hh_     = (u16*)(wsb + oRA + 8388608);         // h split [256,512]
    u16* hl_     = (u16*)(wsb + oRA + 8650752);
    u16* hTh     = (u16*)(wsb + oRA + 9437184);         // hT split [512,256]
    u16* hTl     = (u16*)(wsb + oRA + 9699328);
    u16* rh_     = (u16*)(wsb + oRA + 10485760);        // r split [256,1024]
    u16* rl_     = (u16*)(wsb + oRA + 11010048);
    u16* rTh     = (u16*)(wsb + oRA + 11534336);        // rT split [1024,256]
    u16* rTl     = (u16*)(wsb + oRA + 12058624);
    u16* dhTh    = (u16*)(wsb + oRA + 12582912);        // dhT split [512,256]
    u16* dhTl    = (u16*)(wsb + oRA + 12845056);
    u16* kcTh    = (u16*)(wsb + oRA + 16777216);        // kcT [8][1024][256]  4 MB
    u16* kcTl    = (u16*)(wsb + oRA + 20971520);        // 4 MB
    float* aqkv  = (float*)(wsb + oRA);
    u16* Woh     = (u16*)(wsb + oRA);
    u16* Wol     = (u16*)(wsb + oRA + 2097152);
    u16* ffhh    = (u16*)(wsb + oRA);
    u16* ffhl    = (u16*)(wsb + oRA + 16777216);
    u16* outbh   = (u16*)(wsb + oRA + 33554432);
    u16* outbl   = (u16*)(wsb + oRA + 37748736);
    u16* newQh   = (u16*)(wsb + oRA);
    u16* newQl   = (u16*)(wsb + oRA + 4194304);
    u16* hzh     = (u16*)(wsb + oRA + 8388608);
    u16* hzl     = (u16*)(wsb + oRA + 10485760);
    float* memq  = (float*)(wsb + oRA + 12582912);
    // region B
    float* Kb    = (float*)(wsb + oRB);
    float* Vb    = (float*)(wsb + oRB + 8388608);
    u16* tokh    = (u16*)(wsb + oRB);
    u16* tokl    = (u16*)(wsb + oRB + 8454144);
    u16* oh      = (u16*)(wsb + oRB);
    u16* ol      = (u16*)(wsb + oRB + 4194304);
    u16* y1h     = (u16*)(wsb + oRB + 8388608);
    u16* y1l     = (u16*)(wsb + oRB + 12582912);
    // region C (time-multiplexed: xh/xl -> mom|pW2T -> Wqah/Wqal)
    u16* xh      = (u16*)(wsb + oRC);
    u16* xl      = (u16*)(wsb + oRC + 4194304);
    float* mom   = (float*)(wsb + oRC);                 // scan only, 4.2 MB
    u16* pW2Th   = (u16*)(wsb + oRC + 5242880);         // W2^T split [512,1024] 1 MB
    u16* pW2Tl   = (u16*)(wsb + oRC + 6291456);
    u16* Wqah    = (u16*)(wsb + oRC);
    u16* Wqal    = (u16*)(wsb + oRC + 6291456);
    // region D (Qh/Ql + kc split -> t1/memtok -> ffW buffers)
    u16* Qh      = (u16*)(wsb + oRD);
    u16* Ql      = (u16*)(wsb + oRD + 4194304);
    u16* kchh    = (u16*)(wsb + oRD + 8388608);         // kc split [2048,1024] 4 MB
    u16* kchl    = (u16*)(wsb + oRD + 12582912);        // 4 MB
    u16* t1h     = (u16*)(wsb + oRD + 8388608);
    u16* t1l     = (u16*)(wsb + oRD + 10485760);
    float* memtok= (float*)(wsb + oRD);
    u16* ffW1h   = (u16*)(wsb + oRD);
    u16* ffW1l   = (u16*)(wsb + oRD + 8388608);
    u16* ffW2h   = (u16*)(wsb + oRD);
    u16* ffW2l   = (u16*)(wsb + oRD + 8388608);
    // persistent
    u16* Wqkvh   = (u16*)(wsb + oRE);
    u16* Wqkvl   = (u16*)(wsb + oRE + 6291456);
    u16* pW1h    = (u16*)(wsb + oRF);
    u16* pW1l    = (u16*)(wsb + oRF + 1048576);
    u16* pW2h    = (u16*)(wsb + oRF + 2097152);
    u16* pW2l    = (u16*)(wsb + oRF + 3145728);
    float* par   = (float*)(wsb + oRG);
    float* outb  = (float*)(wsb + oRH);

    // init memory-MLP params
    hipMemcpyAsync(par + PW1, mW1, 524288 * sizeof(float), hipMemcpyDeviceToDevice, stream);
    hipMemcpyAsync(par + PB1, mb1, 512 * sizeof(float), hipMemcpyDeviceToDevice, stream);
    hipMemcpyAsync(par + PW2, mW2, 524288 * sizeof(float), hipMemcpyDeviceToDevice, stream);
    hipMemcpyAsync(par + PB2, mb2, 1024 * sizeof(float), hipMemcpyDeviceToDevice, stream);

    // qkv = x @ Wqkv^T
    cvt_split_k<<<2048, 256, 0, stream>>>(x, xh, xl, 524288);
    cvt_split_k<<<3072, 256, 0, stream>>>(Wqkv, Wqkvh, Wqkvl, 786432);
    gemm_mfma(stream, 0, 1, 0, xh, xl, Wqkvh, Wqkvl, qkv, nullptr, nullptr, 2048, 3072, 1024, nullptr);
    extractqkv2_k<<<24576, 256, 0, stream>>>(qkv, Qh, Ql, Kb, Vb);

    // scan prep (region C xh/xl now dead; region A qkv now dead)
    hipMemsetAsync(mom, 0, PSZ * sizeof(float), stream);
    cvt_split_k<<<2048, 256, 0, stream>>>(Kb, kchh, kchl, 524288);                 // kc split
    transpose_split_k<<<dim3(32, 8, 8), 256, 0, stream>>>(Kb, kcTh, kcTl, 256, 1024); // kcT
    cvt_split_k<<<512, 256, 0, stream>>>(par + PW1, pW1h, pW1l, 131072);
    cvt_split_k<<<512, 256, 0, stream>>>(par + PW2, pW2h, pW2l, 131072);
    transpose_split_k<<<dim3(16, 32, 1), 256, 0, stream>>>(par + PW2, pW2Th, pW2Tl, 1024, 512);

    // memory scan: 8 chunks, all GEMMs split-bf16 MFMA
    const float cs = 2.f / (float)(BATCH * 128 * DIMD);
    for (int c = 0; c < NCH; ++c) {
        const u16* kch = kchh + (size_t)c * 262144;
        const u16* kcl = kchl + (size_t)c * 262144;
        const u16* kth = kcTh + (size_t)c * 262144;
        const u16* ktl = kcTl + (size_t)c * 262144;
        const float* vc = Vb + (size_t)c * 262144;
        // z1 = kc@W1^T + b1 ; h = silu(z1) (split + splitT)
        gemm_scan_k<1><<<dim3(4, 2), 256, 0, stream>>>(kch, kcl, pW1h, pW1l,
            z1, hh_, hl_, hTh, hTl, nullptr, nullptr, par + PB1, 256, 512, 1024, 1.f);
        // r = h@W2^T + b2 - vc (f32 + split + splitT)
        gemm_scan_k<2><<<dim3(8, 2), 256, 0, stream>>>(hh_, hl_, pW2h, pW2l,
            rbuf, rh_, rl_, rTh, rTl, nullptr, vc, par + PB2, 256, 1024, 512, 1.f);
        // gW2 = cs * rT @ hT^T
        gemm_scan_k<3><<<dim3(4, 8), 256, 0, stream>>>(rTh, rTl, hTh, hTl,
            grd + PW2, nullptr, nullptr, nullptr, nullptr, nullptr, nullptr, nullptr,
            1024, 512, 256, cs);
        colsum_k<<<4, 256, 0, stream>>>(rbuf, grd + PB2, 256, 1024, cs);
        // dh = cs * (r @ W2) * dsilu(z1)  (f32 + splitT)
        gemm_scan_k<4><<<dim3(4, 2), 256, 0, stream>>>(rh_, rl_, pW2Th, pW2Tl,
            dhb, nullptr, nullptr, dhTh, dhTl, z1, nullptr, nullptr, 256, 512, 1024, cs);
        // gW1 = dhT @ kcT^T
        gemm_scan_k<3><<<dim3(8, 4), 256, 0, stream>>>(dhTh, dhTl, kth, ktl,
            grd + PW1, nullptr, nullptr, nullptr, nullptr, nullptr, nullptr, nullptr,
            512, 1024, 256, 1.f);
        colsum_k<<<2, 256, 0, stream>>>(dhb, grd + PB1, 256, 512, 1.f);
        update2_k<<<4102, 256, 0, stream>>>(par, mom, grd, pW1h, pW1l, pW2h, pW2l, (int)PSZ);
        transpose_split_k<<<dim3(16, 32, 1), 256, 0, stream>>>(par + PW2, pW2Th, pW2Tl, 1024, 512);
    }

    // memory readout (pW1/pW2 splits maintained by update2_k)
    gemm_mfma(stream, 1, 0, 1, Qh, Ql, pW1h, pW1l, nullptr, t1h, t1l, 2048, 512, 1024, par + PB1);
    gemm_mfma(stream, 0, 1, 0, t1h, t1l, pW2h, pW2l, memtok, nullptr, nullptr, 2048, 1024, 512, par + PB2);

    // tokens (split) + attention qkv
    tokens_split_k<<<16512, 256, 0, stream>>>(Pp, memtok, x, tokh, tokl);
    cvt_split_k<<<3072, 256, 0, stream>>>(Wqa, Wqah, Wqal, 786432);
    gemm_mfma(stream, 0, 1, 0, tokh, tokl, Wqah, Wqal, aqkv, nullptr, nullptr, 4128, 3072, 1024, nullptr);

    // flash attention, q-rows restricted to the x block
    flash_k<<<dim3(16, 16, 2), 256, 0, stream>>>(aqkv, oh, ol);

    // Wo projection + FFN (M = 2048 compact rows)
    cvt_split_k<<<1024, 256, 0, stream>>>(Wo, Woh, Wol, 262144);
    gemm_mfma(stream, 0, 0, 1, oh, ol, Woh, Wol, nullptr, y1h, y1l, 2048, 1024, 1024, nullptr);
    cvt_split_k<<<4096, 256, 0, stream>>>(ffW1, ffW1h, ffW1l, 1048576);
    gemm_mfma(stream, 2, 0, 1, y1h, y1l, ffW1h, ffW1l, nullptr, ffhh, ffhl, 2048, 4096, 1024, ffb1);
    cvt_split_k<<<4096, 256, 0, stream>>>(ffW2, ffW2h, ffW2l, 1048576);
    gemm_mfma(stream, 0, 1, 1, ffhh, ffhl, ffW2h, ffW2l, outb, outbh, outbl, 2048, 1024, 4096, ffb2);

    // gate: newQ = out @ Wqkv_Q^T ; memq = mem_read(newQ) ; out *= memq
    gemm_mfma(stream, 0, 0, 1, outbh, outbl, Wqkvh, Wqkvl, nullptr, newQh, newQl, 2048, 1024, 1024, nullptr);
    gemm_mfma(stream, 1, 0, 1, newQh, newQl, pW1h, pW1l, nullptr, hzh, hzl, 2048, 512, 1024, par + PB1);
    gemm_mfma(stream, 0, 1, 0, hzh, hzl, pW2h, pW2l, memq, nullptr, nullptr, 2048, 1024, 512, par + PB2);
    mul_k<<<8192, 256, 0, stream>>>(outb, memq, outp, 2097152);
}

// Round 5
// 3025.075 us; speedup vs baseline: 3.3075x; 1.1306x over previous
//
#include <hip/hip_runtime.h>
#include <math.h>

// ---------------- problem constants ----------------
#define BATCH 2
#define TSEQ 1024
#define DIMD 1024
#define NPERS 16
#define NCH 8
#define NTOK 2064
#define ETA_C 0.9f
#define THETA_C 0.1f
#define ALPHA_C 0.02f

typedef __attribute__((ext_vector_type(4))) float f32x4;
typedef __attribute__((ext_vector_type(8))) short s16x8;
typedef unsigned short u16;

// ---------------- bf16 helpers ----------------
__device__ __forceinline__ u16 f2bf(float f) {
    unsigned int u = __float_as_uint(f);
    return (u16)((u + 0x7fffu + ((u >> 16) & 1u)) >> 16);
}
__device__ __forceinline__ float bf2f(u16 h) { return __uint_as_float(((unsigned)h) << 16); }
__device__ __forceinline__ void split2(float v, u16& h, u16& l) {
    h = f2bf(v); l = f2bf(v - bf2f(h));
}

// ---------------- workspace layout (byte offsets) ----------------
static const size_t oRA = 0;                       // 50,724,864 multiplexed
static const size_t oRB = 50724864;                // 16,908,288
static const size_t oRC = 67633152;                // 12,582,912
static const size_t oRD = 80216064;                // 16,777,216
static const size_t oRE = 96993280;                // 12,582,912 Wqkv h/l (persistent)
static const size_t oRF = 109576192;               //  4,194,304 parW h/l (persistent)
static const size_t oRG = 113770496;               //  4,200,448 par (persistent)
static const size_t oRH = 117970944;               //  8,388,608 outb f32 (Qs split during attn)
// total 126,359,552 bytes

static const size_t PW1 = 0, PB1 = 524288, PW2 = 524800, PB2 = 1049088, PSZ = 1050112;

// ---------------- async global->LDS ----------------
__device__ __forceinline__ void gload_lds16(const u16* g, u16* l) {
    __builtin_amdgcn_global_load_lds(
        (const __attribute__((address_space(1))) unsigned int*)g,
        (__attribute__((address_space(3))) unsigned int*)l, 16, 0, 0);
}

// ---------------- split-bf16 MFMA GEMM:  C = act(A @ W^T + bias)  (main path) ----
template<int ACTF, int WF32, int WSPLIT>
__global__ __launch_bounds__(256)
void gemm_mfma_k(const u16* __restrict__ Ah, const u16* __restrict__ Al,
                 const u16* __restrict__ Wh, const u16* __restrict__ Wl,
                 float* __restrict__ C, u16* __restrict__ Chi, u16* __restrict__ Clo,
                 int M, int N, int K, const float* __restrict__ bias)
{
    __shared__ u16 lds[16384];
    const int tid = threadIdx.x;
    const int lane = tid & 63, wid = tid >> 6;
    const int wm = wid >> 1, wn = wid & 1;
    const int row0 = blockIdx.y * 128, col0 = blockIdx.x * 128;

    const u16* sp = (wid == 0) ? Ah : (wid == 1) ? Al : (wid == 2) ? Wh : Wl;
    const int rbase = (wid < 2) ? row0 : col0;
    const int lr = lane >> 2, lc = lane & 3;

    f32x4 acc[4][4] = {};
    const int frow = lane & 15, kblk = lane >> 4;

    for (int k0 = 0; k0 < K; k0 += 32) {
        #pragma unroll
        for (int i = 0; i < 8; ++i) {
            int r = i * 16 + lr;
            int gr = rbase + r;
            if (wid < 2 && gr >= M) gr = M - 1;
            int g = lc ^ ((r >> 1) & 3);
            gload_lds16(sp + (size_t)gr * K + k0 + g * 8, &lds[wid * 4096 + i * 512]);
        }
        __syncthreads();

        s16x8 bh[4], bl[4];
        #pragma unroll
        for (int ni = 0; ni < 4; ++ni) {
            int br = wn * 64 + ni * 16 + frow;
            int pc = kblk ^ ((br >> 1) & 3);
            bh[ni] = *(const s16x8*)&lds[2 * 4096 + br * 32 + pc * 8];
            bl[ni] = *(const s16x8*)&lds[3 * 4096 + br * 32 + pc * 8];
        }
        #pragma unroll
        for (int mi = 0; mi < 4; ++mi) {
            int ar = wm * 64 + mi * 16 + frow;
            int pc = kblk ^ ((ar >> 1) & 3);
            s16x8 ah = *(const s16x8*)&lds[0 * 4096 + ar * 32 + pc * 8];
            s16x8 al = *(const s16x8*)&lds[1 * 4096 + ar * 32 + pc * 8];
            #pragma unroll
            for (int ni = 0; ni < 4; ++ni) {
                acc[mi][ni] = __builtin_amdgcn_mfma_f32_16x16x32_bf16(ah, bh[ni], acc[mi][ni], 0, 0, 0);
                acc[mi][ni] = __builtin_amdgcn_mfma_f32_16x16x32_bf16(ah, bl[ni], acc[mi][ni], 0, 0, 0);
                acc[mi][ni] = __builtin_amdgcn_mfma_f32_16x16x32_bf16(al, bh[ni], acc[mi][ni], 0, 0, 0);
            }
        }
        __syncthreads();
    }

    const int erow = (lane >> 4) * 4, ecol = lane & 15;
    #pragma unroll
    for (int mi = 0; mi < 4; ++mi) {
        #pragma unroll
        for (int ni = 0; ni < 4; ++ni) {
            int c = col0 + wn * 64 + ni * 16 + ecol;
            float bv = bias ? bias[c] : 0.f;
            #pragma unroll
            for (int reg = 0; reg < 4; ++reg) {
                int r = row0 + wm * 64 + mi * 16 + erow + reg;
                if (r >= M) continue;
                float v = acc[mi][ni][reg] + bv;
                if (ACTF == 1) v = v / (1.f + __expf(-v));
                else if (ACTF == 2) {
                    float u = 0.7978845608028654f * (v + 0.044715f * v * v * v);
                    v = 0.5f * v * (1.f + tanhf(u));
                }
                size_t o = (size_t)r * N + c;
                if (WF32) C[o] = v;
                if (WSPLIT) { u16 h, l; split2(v, h, l); Chi[o] = h; Clo[o] = l; }
            }
        }
    }
}

static void gemm_mfma(hipStream_t s, int act, int wf32, int wsplit,
                      const u16* Ah, const u16* Al, const u16* Wh, const u16* Wl,
                      float* C, u16* Ch, u16* Cl, int M, int N, int K, const float* bias)
{
    dim3 g(N / 128, (M + 127) / 128), b(256);
    if (act == 0 && wf32 == 1 && wsplit == 0)
        gemm_mfma_k<0,1,0><<<g,b,0,s>>>(Ah,Al,Wh,Wl,C,Ch,Cl,M,N,K,bias);
    else if (act == 0 && wf32 == 1 && wsplit == 1)
        gemm_mfma_k<0,1,1><<<g,b,0,s>>>(Ah,Al,Wh,Wl,C,Ch,Cl,M,N,K,bias);
    else if (act == 0 && wf32 == 0 && wsplit == 1)
        gemm_mfma_k<0,0,1><<<g,b,0,s>>>(Ah,Al,Wh,Wl,C,Ch,Cl,M,N,K,bias);
    else if (act == 1)
        gemm_mfma_k<1,0,1><<<g,b,0,s>>>(Ah,Al,Wh,Wl,C,Ch,Cl,M,N,K,bias);
    else
        gemm_mfma_k<2,0,1><<<g,b,0,s>>>(Ah,Al,Wh,Wl,C,Ch,Cl,M,N,K,bias);
}

// ---------------- scan-specialized split-bf16 MFMA GEMM ----------------
template<int MODE>
__global__ __launch_bounds__(256)
void gemm_scan_k(const u16* __restrict__ Ah, const u16* __restrict__ Al,
                 const u16* __restrict__ Wh, const u16* __restrict__ Wl,
                 float* __restrict__ C, u16* __restrict__ Chi, u16* __restrict__ Clo,
                 u16* __restrict__ ChiT, u16* __restrict__ CloT,
                 const float* __restrict__ Zf, const float* __restrict__ add,
                 const float* __restrict__ bias, int M, int N, int K, float alpha)
{
    __shared__ u16 lds[16384];
    const int tid = threadIdx.x;
    const int lane = tid & 63, wid = tid >> 6;
    const int wm = wid >> 1, wn = wid & 1;
    const int row0 = blockIdx.y * 128, col0 = blockIdx.x * 128;

    const u16* sp = (wid == 0) ? Ah : (wid == 1) ? Al : (wid == 2) ? Wh : Wl;
    const int rbase = (wid < 2) ? row0 : col0;
    const int lr = lane >> 2, lc = lane & 3;

    f32x4 acc[4][4] = {};
    const int frow = lane & 15, kblk = lane >> 4;

    for (int k0 = 0; k0 < K; k0 += 32) {
        #pragma unroll
        for (int i = 0; i < 8; ++i) {
            int r = i * 16 + lr;
            int gr = rbase + r;
            int g = lc ^ ((r >> 1) & 3);
            gload_lds16(sp + (size_t)gr * K + k0 + g * 8, &lds[wid * 4096 + i * 512]);
        }
        __syncthreads();

        s16x8 bh[4], bl[4];
        #pragma unroll
        for (int ni = 0; ni < 4; ++ni) {
            int br = wn * 64 + ni * 16 + frow;
            int pc = kblk ^ ((br >> 1) & 3);
            bh[ni] = *(const s16x8*)&lds[2 * 4096 + br * 32 + pc * 8];
            bl[ni] = *(const s16x8*)&lds[3 * 4096 + br * 32 + pc * 8];
        }
        #pragma unroll
        for (int mi = 0; mi < 4; ++mi) {
            int ar = wm * 64 + mi * 16 + frow;
            int pc = kblk ^ ((ar >> 1) & 3);
            s16x8 ah = *(const s16x8*)&lds[0 * 4096 + ar * 32 + pc * 8];
            s16x8 al = *(const s16x8*)&lds[1 * 4096 + ar * 32 + pc * 8];
            #pragma unroll
            for (int ni = 0; ni < 4; ++ni) {
                acc[mi][ni] = __builtin_amdgcn_mfma_f32_16x16x32_bf16(ah, bh[ni], acc[mi][ni], 0, 0, 0);
                acc[mi][ni] = __builtin_amdgcn_mfma_f32_16x16x32_bf16(ah, bl[ni], acc[mi][ni], 0, 0, 0);
                acc[mi][ni] = __builtin_amdgcn_mfma_f32_16x16x32_bf16(al, bh[ni], acc[mi][ni], 0, 0, 0);
            }
        }
        __syncthreads();
    }

    const int erow = (lane >> 4) * 4, ecol = lane & 15;
    #pragma unroll
    for (int mi = 0; mi < 4; ++mi) {
        #pragma unroll
        for (int ni = 0; ni < 4; ++ni) {
            int c = col0 + wn * 64 + ni * 16 + ecol;
            #pragma unroll
            for (int reg = 0; reg < 4; ++reg) {
                int r = row0 + wm * 64 + mi * 16 + erow + reg;
                float v = acc[mi][ni][reg];
                size_t o = (size_t)r * N + c;
                if (MODE == 1) {
                    v += bias[c];
                    C[o] = v;
                    float hv = v / (1.f + __expf(-v));
                    u16 h, l; split2(hv, h, l);
                    Chi[o] = h; Clo[o] = l;
                    size_t ot = (size_t)c * M + r;
                    ChiT[ot] = h; CloT[ot] = l;
                } else if (MODE == 2) {
                    v += bias[c] - add[o];
                    C[o] = v;
                    u16 h, l; split2(v, h, l);
                    Chi[o] = h; Clo[o] = l;
                    size_t ot = (size_t)c * M + r;
                    ChiT[ot] = h; CloT[ot] = l;
                } else if (MODE == 3) {
                    C[o] = alpha * v;
                } else {
                    v *= alpha;
                    float z = Zf[o];
                    float sg = 1.f / (1.f + __expf(-z));
                    v *= sg * (1.f + z * (1.f - sg));
                    C[o] = v;
                    u16 h, l; split2(v, h, l);
                    size_t ot = (size_t)c * M + r;
                    ChiT[ot] = h; CloT[ot] = l;
                }
            }
        }
    }
}

// ---------------- small kernels ----------------
__global__ void cvt_split_k(const float* __restrict__ in, u16* __restrict__ hi,
                            u16* __restrict__ lo, int n4) {
    int i = blockIdx.x * 256 + threadIdx.x;
    if (i >= n4) return;
    float4 v = *(const float4*)&in[(size_t)i * 4];
    u16 h0,l0,h1,l1,h2,l2,h3,l3;
    split2(v.x,h0,l0); split2(v.y,h1,l1); split2(v.z,h2,l2); split2(v.w,h3,l3);
    ushort4 hv = {h0,h1,h2,h3}, lv = {l0,l1,l2,l3};
    *(ushort4*)&hi[(size_t)i * 4] = hv;
    *(ushort4*)&lo[(size_t)i * 4] = lv;
}
__global__ void transpose_split_k(const float* __restrict__ in, u16* __restrict__ outh,
                                  u16* __restrict__ outl, int R, int C) {
    __shared__ float t[32][33];
    const int c0 = blockIdx.x * 32, r0 = blockIdx.y * 32;
    const size_t zoff = (size_t)blockIdx.z * R * C;
    const int tx = threadIdx.x & 31, ty = threadIdx.x >> 5;
    #pragma unroll
    for (int p = 0; p < 4; ++p) {
        int r = ty + p * 8;
        t[r][tx] = in[zoff + (size_t)(r0 + r) * C + c0 + tx];
    }
    __syncthreads();
    #pragma unroll
    for (int p = 0; p < 4; ++p) {
        int cc = ty + p * 8;
        float v = t[tx][cc];
        u16 h, l; split2(v, h, l);
        size_t o = zoff + (size_t)(c0 + cc) * R + r0 + tx;
        outh[o] = h; outl[o] = l;
    }
}
__global__ void colsum_k(const float* __restrict__ X, float* __restrict__ out,
                         int M, int N, float alpha) {
    int j = blockIdx.x * 256 + threadIdx.x;
    if (j >= N) return;
    float s = 0.f;
    for (int m = 0; m < M; ++m) s += X[(size_t)m * N + j];
    out[j] = alpha * s;
}
__global__ void update2_k(float* __restrict__ p, float* __restrict__ mo,
                          const float* __restrict__ g,
                          u16* __restrict__ w1h, u16* __restrict__ w1l,
                          u16* __restrict__ w2h, u16* __restrict__ w2l, int n) {
    int i = blockIdx.x * 256 + threadIdx.x;
    if (i >= n) return;
    float m = ETA_C * mo[i] - THETA_C * g[i];
    mo[i] = m;
    float pv = (1.f - ALPHA_C) * p[i] + m;
    p[i] = pv;
    if (i < 524288) {
        u16 h, l; split2(pv, h, l); w1h[i] = h; w1l[i] = l;
    } else if (i >= 524800 && i < 1049088) {
        int j = i - 524800;
        u16 h, l; split2(pv, h, l); w2h[j] = h; w2l[j] = l;
    }
}
__global__ void extractqkv2_k(const float* __restrict__ qkv, u16* __restrict__ Qh,
                              u16* __restrict__ Ql, float* __restrict__ Kb,
                              float* __restrict__ Vb) {
    size_t idx = (size_t)blockIdx.x * 256 + threadIdx.x;
    int m = (int)(idx / 3072), col = (int)(idx % 3072);
    int b = m >> 10, t = m & 1023;
    float v = qkv[idx];
    if (col < 1024) {
        size_t o = (size_t)m * 1024 + col;
        u16 h, l; split2(v, h, l); Qh[o] = h; Ql[o] = l;
    } else {
        int d = col & 1023;
        int ch = t >> 7, r = t & 127;
        size_t o = ((size_t)((ch * 2 + b) * 128 + r)) * 1024 + d;
        if (col < 2048) Kb[o] = v; else Vb[o] = v;
    }
}
__global__ void tokens_split_k(const float* __restrict__ P, const float* __restrict__ memtok,
                               const float* __restrict__ x, u16* __restrict__ th,
                               u16* __restrict__ tl) {
    size_t idx = (size_t)blockIdx.x * 256 + threadIdx.x;
    int d = (int)(idx & 1023);
    int n = (int)((idx >> 10) % NTOK);
    int b = (int)(idx / ((size_t)NTOK * 1024));
    float v;
    if (n < NPERS)            v = P[(size_t)n * 1024 + d];
    else if (n < NPERS + TSEQ) v = memtok[((size_t)b * TSEQ + (n - NPERS)) * 1024 + d];
    else                      v = x[((size_t)b * TSEQ + (n - NPERS - TSEQ)) * 1024 + d];
    u16 h, l; split2(v, h, l); th[idx] = h; tl[idx] = l;
}
__global__ void mul_k(const float* __restrict__ a, const float* __restrict__ b,
                      float* __restrict__ o, int n) {
    int i = blockIdx.x * 256 + threadIdx.x;
    if (i < n) o[i] = a[i] * b[i];
}

// ---------------- attention prep: split aqkv into bf16 buffers ----------------
// Qs [b][h][1024][64] (pre-scaled 0.125, hi+lo), Ks [b][h][2064][64] (hi+lo),
// Vt [b][h][64][2064] (hi only, transposed)
__global__ void prep_q_k(const float* __restrict__ aqkv, u16* __restrict__ Qh,
                         u16* __restrict__ Ql) {
    size_t idx = (size_t)blockIdx.x * 256 + threadIdx.x;   // 2*16*1024*64
    int d = (int)(idx & 63);
    int row = (int)((idx >> 6) & 1023);
    int h = (int)((idx >> 16) & 15);
    int b = (int)(idx >> 20);
    float v = 0.125f * aqkv[((size_t)b * NTOK + NPERS + TSEQ + row) * 3072 + h * 64 + d];
    u16 hh, ll; split2(v, hh, ll);
    Qh[idx] = hh; Ql[idx] = ll;
}
__global__ void prep_kk_k(const float* __restrict__ aqkv, u16* __restrict__ Kh,
                          u16* __restrict__ Kl) {
    size_t idx = (size_t)blockIdx.x * 256 + threadIdx.x;   // 2*16*2064*64 = 4,227,072
    int d = (int)(idx & 63);
    int n = (int)((idx >> 6) % NTOK);
    int t = (int)(idx / (64 * NTOK));
    int h = t & 15, b = t >> 4;
    float v = aqkv[((size_t)b * NTOK + n) * 3072 + 1024 + h * 64 + d];
    u16 hh, ll; split2(v, hh, ll);
    Kh[idx] = hh; Kl[idx] = ll;
}
__global__ void prep_vt_k(const float* __restrict__ aqkv, u16* __restrict__ Vt) {
    __shared__ float t[64][65];
    const int nt = blockIdx.x, h = blockIdx.y, b = blockIdx.z;
    const int j0 = nt * 64;
    const int lx = threadIdx.x & 63, rg = threadIdx.x >> 6;
    #pragma unroll
    for (int p = 0; p < 16; ++p) {
        int r = rg * 16 + p;
        int n = j0 + r;
        t[r][lx] = (n < NTOK) ? aqkv[((size_t)b * NTOK + n) * 3072 + 2048 + h * 64 + lx] : 0.f;
    }
    __syncthreads();
    #pragma unroll
    for (int p = 0; p < 16; ++p) {
        int d = rg * 16 + p;
        int n = j0 + lx;
        if (n < NTOK)
            Vt[((size_t)(b * 16 + h) * 64 + d) * NTOK + n] = f2bf(t[lx][d]);
    }
}

// ---------------- MFMA flash attention ----------------
// grid (16, 16, 2) = (qt, h, b), 256 threads = 4 waves; wave w owns q rows w*16..+15.
// QK^T full split (3 prods), softmax fp32 in regs, PV = (Ph+Pl) @ Vh (2 prods).
__global__ __launch_bounds__(256)
void flash_mfma_k(const u16* __restrict__ Qsh, const u16* __restrict__ Qsl,
                  const u16* __restrict__ Ksh, const u16* __restrict__ Ksl,
                  const u16* __restrict__ Vts, u16* __restrict__ oh, u16* __restrict__ ol)
{
    __shared__ u16 lds[7 * 4096];          // QH QL KH KL VT PH PL, each [64][64]
    u16* QH = lds;            u16* QL = lds + 4096;
    u16* KH = lds + 8192;     u16* KL = lds + 12288;
    u16* VT = lds + 16384;
    u16* PH = lds + 20480;    u16* PL = lds + 24576;

    const int qt = blockIdx.x, h = blockIdx.y, b = blockIdx.z;
    const int tid = threadIdx.x;
    const int lane = tid & 63, wid = tid >> 6;
    const int fr = lane & 15, kq = lane >> 4;
    const int bh = b * 16 + h;
    const int q0c = qt * 64;                         // compact q row base (0..1023)
    const int q0a = NPERS + TSEQ + q0c;              // absolute token index

    // ---- stage Q (once): 16 gload instrs, wave does 4 ----
    {
        const int l8 = lane & 7, lr = lane >> 3;
        #pragma unroll
        for (int jj = 0; jj < 4; ++jj) {
            int j = wid * 4 + jj;
            int buf = j >> 3, i8 = j & 7;
            int row = i8 * 8 + lr;
            int c = l8 ^ (row & 7);
            const u16* src = (buf == 0 ? Qsh : Qsl) +
                             (((size_t)bh * 1024 + q0c + row) << 6) + c * 8;
            gload_lds16(src, (buf == 0 ? QH : QL) + i8 * 512);
        }
    }
    __syncthreads();

    // persistent Q fragments
    s16x8 qh[2], ql[2];
    #pragma unroll
    for (int kb = 0; kb < 2; ++kb) {
        int r = wid * 16 + fr;
        int sl = (kb * 4 + kq) ^ (fr & 7);
        qh[kb] = *(const s16x8*)&QH[r * 64 + sl * 8];
        ql[kb] = *(const s16x8*)&QL[r * 64 + sl * 8];
    }

    f32x4 Oa[4] = {};
    float mrow[4], lrow[4];
    #pragma unroll
    for (int r = 0; r < 4; ++r) { mrow[r] = -INFINITY; lrow[r] = 0.f; }

    const int jtmax = (q0a + 63) >> 6;
    for (int jt = 0; jt <= jtmax; ++jt) {
        const int j0 = jt * 64;
        // ---- stage K hi/lo + V^T hi: 24 gload instrs, wave does 6 ----
        {
            const int l8 = lane & 7, lr = lane >> 3;
            #pragma unroll
            for (int jj = 0; jj < 6; ++jj) {
                int j = wid * 6 + jj;
                int buf = j >> 3, i8 = j & 7;
                if (buf < 2) {
                    int row = i8 * 8 + lr;
                    int grow = j0 + row; if (grow > NTOK - 1) grow = NTOK - 1;
                    int c = l8 ^ (row & 7);
                    const u16* src = (buf == 0 ? Ksh : Ksl) +
                                     (((size_t)bh * NTOK + grow) << 6) + c * 8;
                    gload_lds16(src, (buf == 0 ? KH : KL) + i8 * 512);
                } else {
                    int d = i8 * 8 + lr;
                    int c = l8 ^ (d & 7);
                    int col = j0 + c * 8; if (col > NTOK - 8) col = NTOK - 8;
                    const u16* src = Vts + ((size_t)bh * 64 + d) * NTOK + col;
                    gload_lds16(src, VT + i8 * 512);
                }
            }
        }
        __syncthreads();

        // ---- S = Q @ K^T (split: hh + lh + hl) ----
        f32x4 sacc[4] = {};
        #pragma unroll
        for (int nt = 0; nt < 4; ++nt) {
            #pragma unroll
            for (int kb = 0; kb < 2; ++kb) {
                int br = nt * 16 + fr;
                int sl = (kb * 4 + kq) ^ (fr & 7);
                s16x8 kh = *(const s16x8*)&KH[br * 64 + sl * 8];
                s16x8 kl = *(const s16x8*)&KL[br * 64 + sl * 8];
                sacc[nt] = __builtin_amdgcn_mfma_f32_16x16x32_bf16(qh[kb], kh, sacc[nt], 0, 0, 0);
                sacc[nt] = __builtin_amdgcn_mfma_f32_16x16x32_bf16(ql[kb], kh, sacc[nt], 0, 0, 0);
                sacc[nt] = __builtin_amdgcn_mfma_f32_16x16x32_bf16(qh[kb], kl, sacc[nt], 0, 0, 0);
            }
        }

        // ---- online softmax (each lane: 4 rows x 4 col-tiles) ----
        #pragma unroll
        for (int r = 0; r < 4; ++r) {
            const int qloc = kq * 4 + r;
            const int qi = q0a + wid * 16 + qloc;
            float sv[4], tmax = -INFINITY;
            #pragma unroll
            for (int nt = 0; nt < 4; ++nt) {
                int kj = j0 + nt * 16 + fr;
                sv[nt] = (kj <= qi) ? sacc[nt][r] : -INFINITY;
                tmax = fmaxf(tmax, sv[nt]);
            }
            #pragma unroll
            for (int off = 1; off < 16; off <<= 1)
                tmax = fmaxf(tmax, __shfl_xor(tmax, off));
            float mnew = fmaxf(mrow[r], tmax);
            float scale = __expf(mrow[r] - mnew);
            float psum = 0.f;
            float p4[4];
            #pragma unroll
            for (int nt = 0; nt < 4; ++nt) { p4[nt] = __expf(sv[nt] - mnew); psum += p4[nt]; }
            #pragma unroll
            for (int off = 1; off < 16; off <<= 1)
                psum += __shfl_xor(psum, off);
            lrow[r] = lrow[r] * scale + psum;
            mrow[r] = mnew;
            #pragma unroll
            for (int dt = 0; dt < 4; ++dt) Oa[dt][r] *= scale;
            // write P split to LDS (swizzled for A-fragment reads)
            const int prow = wid * 16 + qloc;
            #pragma unroll
            for (int nt = 0; nt < 4; ++nt) {
                u16 ph, pl; split2(p4[nt], ph, pl);
                int col = nt * 16 + fr;
                int sl = (col >> 3) ^ (qloc & 7);
                int off = prow * 64 + sl * 8 + (col & 7);
                PH[off] = ph; PL[off] = pl;
            }
        }

        // ---- O += P @ V  (A = P rows of this wave, B = V^T) ----
        #pragma unroll
        for (int kb = 0; kb < 2; ++kb) {
            int pr = wid * 16 + fr;
            int sl = (kb * 4 + kq) ^ (fr & 7);
            s16x8 pa = *(const s16x8*)&PH[pr * 64 + sl * 8];
            s16x8 pb = *(const s16x8*)&PL[pr * 64 + sl * 8];
            #pragma unroll
            for (int dt = 0; dt < 4; ++dt) {
                int vr = dt * 16 + fr;
                s16x8 vb = *(const s16x8*)&VT[vr * 64 + sl * 8];
                Oa[dt] = __builtin_amdgcn_mfma_f32_16x16x32_bf16(pa, vb, Oa[dt], 0, 0, 0);
                Oa[dt] = __builtin_amdgcn_mfma_f32_16x16x32_bf16(pb, vb, Oa[dt], 0, 0, 0);
            }
        }
        __syncthreads();
    }

    // ---- epilogue ----
    #pragma unroll
    for (int r = 0; r < 4; ++r) {
        float inv = 1.f / lrow[r];
        int row = b * 1024 + q0c + wid * 16 + kq * 4 + r;
        #pragma unroll
        for (int dt = 0; dt < 4; ++dt) {
            float v = Oa[dt][r] * inv;
            size_t o = (size_t)row * 1024 + h * 64 + dt * 16 + fr;
            u16 hh, ll; split2(v, hh, ll);
            oh[o] = hh; ol[o] = ll;
        }
    }
}

// ---------------- launch ----------------
extern "C" void kernel_launch(void* const* d_in, const int* in_sizes, int n_in,
                              void* d_out, int out_size, void* d_ws, size_t ws_size,
                              hipStream_t stream)
{
    const float* x     = (const float*)d_in[0];
    const float* Wqkv  = (const float*)d_in[1];
    const float* mW1   = (const float*)d_in[2];
    const float* mb1   = (const float*)d_in[3];
    const float* mW2   = (const float*)d_in[4];
    const float* mb2   = (const float*)d_in[5];
    const float* Pp    = (const float*)d_in[6];
    const float* Wqa   = (const float*)d_in[7];
    const float* Wo    = (const float*)d_in[8];
    const float* ffW1  = (const float*)d_in[9];
    const float* ffb1  = (const float*)d_in[10];
    const float* ffW2  = (const float*)d_in[11];
    const float* ffb2  = (const float*)d_in[12];
    char* wsb = (char*)d_ws;
    float* outp = (float*)d_out;

    // region A (multiplexed)
    float* qkv   = (float*)(wsb + oRA);
    float* z1    = (float*)(wsb + oRA);
    float* rbuf  = (float*)(wsb + oRA + 1048576);
    float* dhb   = (float*)(wsb + oRA + 2097152);
    float* grd   = (float*)(wsb + oRA + 3145728);
    u16* hh_     = (u16*)(wsb + oRA + 8388608);
    u16* hl_     = (u16*)(wsb + oRA + 8650752);
    u16* hTh     = (u16*)(wsb + oRA + 9437184);
    u16* hTl     = (u16*)(wsb + oRA + 9699328);
    u16* rh_     = (u16*)(wsb + oRA + 10485760);
    u16* rl_     = (u16*)(wsb + oRA + 11010048);
    u16* rTh     = (u16*)(wsb + oRA + 11534336);
    u16* rTl     = (u16*)(wsb + oRA + 12058624);
    u16* dhTh    = (u16*)(wsb + oRA + 12582912);
    u16* dhTl    = (u16*)(wsb + oRA + 12845056);
    u16* kcTh    = (u16*)(wsb + oRA + 16777216);
    u16* kcTl    = (u16*)(wsb + oRA + 20971520);
    float* aqkv  = (float*)(wsb + oRA);
    u16* Woh     = (u16*)(wsb + oRA);
    u16* Wol     = (u16*)(wsb + oRA + 2097152);
    u16* ffhh    = (u16*)(wsb + oRA);
    u16* ffhl    = (u16*)(wsb + oRA + 16777216);
    u16* outbh   = (u16*)(wsb + oRA + 33554432);
    u16* outbl   = (u16*)(wsb + oRA + 37748736);
    u16* newQh   = (u16*)(wsb + oRA);
    u16* newQl   = (u16*)(wsb + oRA + 4194304);
    u16* hzh     = (u16*)(wsb + oRA + 8388608);
    u16* hzl     = (u16*)(wsb + oRA + 10485760);
    float* memq  = (float*)(wsb + oRA + 12582912);
    // region B
    float* Kb    = (float*)(wsb + oRB);
    float* Vb    = (float*)(wsb + oRB + 8388608);
    u16* tokh    = (u16*)(wsb + oRB);
    u16* tokl    = (u16*)(wsb + oRB + 8454144);
    u16* oh      = (u16*)(wsb + oRB);
    u16* ol      = (u16*)(wsb + oRB + 4194304);
    u16* fVth    = (u16*)(wsb + oRB + 8388608);          // V^T hi [b][h][64][2064] 8,454,144
    u16* y1h     = (u16*)(wsb + oRB + 8388608);          // after flash (fVt dead)
    u16* y1l     = (u16*)(wsb + oRB + 12582912);
    // region C (xh/xl -> mom|pW2T -> Wqah/Wqal -> fKl)
    u16* xh      = (u16*)(wsb + oRC);
    u16* xl      = (u16*)(wsb + oRC + 4194304);
    float* mom   = (float*)(wsb + oRC);
    u16* pW2Th   = (u16*)(wsb + oRC + 5242880);
    u16* pW2Tl   = (u16*)(wsb + oRC + 6291456);
    u16* Wqah    = (u16*)(wsb + oRC);
    u16* Wqal    = (u16*)(wsb + oRC + 6291456);
    u16* fKl     = (u16*)(wsb + oRC);                    // K lo [b][h][2064][64] 8,454,144
    // region D
    u16* Qh      = (u16*)(wsb + oRD);
    u16* Ql      = (u16*)(wsb + oRD + 4194304);
    u16* kchh    = (u16*)(wsb + oRD + 8388608);
    u16* kchl    = (u16*)(wsb + oRD + 12582912);
    u16* t1h     = (u16*)(wsb + oRD + 8388608);
    u16* t1l     = (u16*)(wsb + oRD + 10485760);
    float* memtok= (float*)(wsb + oRD);
    u16* fKh     = (u16*)(wsb + oRD);                    // K hi [b][h][2064][64] 8,454,144
    u16* ffW1h   = (u16*)(wsb + oRD);
    u16* ffW1l   = (u16*)(wsb + oRD + 8388608);
    u16* ffW2h   = (u16*)(wsb + oRD);
    u16* ffW2l   = (u16*)(wsb + oRD + 8388608);
    // persistent
    u16* Wqkvh   = (u16*)(wsb + oRE);
    u16* Wqkvl   = (u16*)(wsb + oRE + 6291456);
    u16* pW1h    = (u16*)(wsb + oRF);
    u16* pW1l    = (u16*)(wsb + oRF + 1048576);
    u16* pW2h    = (u16*)(wsb + oRF + 2097152);
    u16* pW2l    = (u16*)(wsb + oRF + 3145728);
    float* par   = (float*)(wsb + oRG);
    float* outb  = (float*)(wsb + oRH);
    u16* fQh     = (u16*)(wsb + oRH);                    // Q split (during attn; outb dead)
    u16* fQl     = (u16*)(wsb + oRH + 4194304);

    // init memory-MLP params
    hipMemcpyAsync(par + PW1, mW1, 524288 * sizeof(float), hipMemcpyDeviceToDevice, stream);
    hipMemcpyAsync(par + PB1, mb1, 512 * sizeof(float), hipMemcpyDeviceToDevice, stream);
    hipMemcpyAsync(par + PW2, mW2, 524288 * sizeof(float), hipMemcpyDeviceToDevice, stream);
    hipMemcpyAsync(par + PB2, mb2, 1024 * sizeof(float), hipMemcpyDeviceToDevice, stream);

    // qkv = x @ Wqkv^T
    cvt_split_k<<<2048, 256, 0, stream>>>(x, xh, xl, 524288);
    cvt_split_k<<<3072, 256, 0, stream>>>(Wqkv, Wqkvh, Wqkvl, 786432);
    gemm_mfma(stream, 0, 1, 0, xh, xl, Wqkvh, Wqkvl, qkv, nullptr, nullptr, 2048, 3072, 1024, nullptr);
    extractqkv2_k<<<24576, 256, 0, stream>>>(qkv, Qh, Ql, Kb, Vb);

    // scan prep
    hipMemsetAsync(mom, 0, PSZ * sizeof(float), stream);
    cvt_split_k<<<2048, 256, 0, stream>>>(Kb, kchh, kchl, 524288);
    transpose_split_k<<<dim3(32, 8, 8), 256, 0, stream>>>(Kb, kcTh, kcTl, 256, 1024);
    cvt_split_k<<<512, 256, 0, stream>>>(par + PW1, pW1h, pW1l, 131072);
    cvt_split_k<<<512, 256, 0, stream>>>(par + PW2, pW2h, pW2l, 131072);
    transpose_split_k<<<dim3(16, 32, 1), 256, 0, stream>>>(par + PW2, pW2Th, pW2Tl, 1024, 512);

    // memory scan
    const float cs = 2.f / (float)(BATCH * 128 * DIMD);
    for (int c = 0; c < NCH; ++c) {
        const u16* kch = kchh + (size_t)c * 262144;
        const u16* kcl = kchl + (size_t)c * 262144;
        const u16* kth = kcTh + (size_t)c * 262144;
        const u16* ktl = kcTl + (size_t)c * 262144;
        const float* vc = Vb + (size_t)c * 262144;
        gemm_scan_k<1><<<dim3(4, 2), 256, 0, stream>>>(kch, kcl, pW1h, pW1l,
            z1, hh_, hl_, hTh, hTl, nullptr, nullptr, par + PB1, 256, 512, 1024, 1.f);
        gemm_scan_k<2><<<dim3(8, 2), 256, 0, stream>>>(hh_, hl_, pW2h, pW2l,
            rbuf, rh_, rl_, rTh, rTl, nullptr, vc, par + PB2, 256, 1024, 512, 1.f);
        gemm_scan_k<3><<<dim3(4, 8), 256, 0, stream>>>(rTh, rTl, hTh, hTl,
            grd + PW2, nullptr, nullptr, nullptr, nullptr, nullptr, nullptr, nullptr,
            1024, 512, 256, cs);
        colsum_k<<<4, 256, 0, stream>>>(rbuf, grd + PB2, 256, 1024, cs);
        gemm_scan_k<4><<<dim3(4, 2), 256, 0, stream>>>(rh_, rl_, pW2Th, pW2Tl,
            dhb, nullptr, nullptr, dhTh, dhTl, z1, nullptr, nullptr, 256, 512, 1024, cs);
        gemm_scan_k<3><<<dim3(8, 4), 256, 0, stream>>>(dhTh, dhTl, kth, ktl,
            grd + PW1, nullptr, nullptr, nullptr, nullptr, nullptr, nullptr, nullptr,
            512, 1024, 256, 1.f);
        colsum_k<<<2, 256, 0, stream>>>(dhb, grd + PB1, 256, 512, 1.f);
        update2_k<<<4102, 256, 0, stream>>>(par, mom, grd, pW1h, pW1l, pW2h, pW2l, (int)PSZ);
        transpose_split_k<<<dim3(16, 32, 1), 256, 0, stream>>>(par + PW2, pW2Th, pW2Tl, 1024, 512);
    }

    // memory readout
    gemm_mfma(stream, 1, 0, 1, Qh, Ql, pW1h, pW1l, nullptr, t1h, t1l, 2048, 512, 1024, par + PB1);
    gemm_mfma(stream, 0, 1, 0, t1h, t1l, pW2h, pW2l, memtok, nullptr, nullptr, 2048, 1024, 512, par + PB2);

    // tokens + attention qkv
    tokens_split_k<<<16512, 256, 0, stream>>>(Pp, memtok, x, tokh, tokl);
    cvt_split_k<<<3072, 256, 0, stream>>>(Wqa, Wqah, Wqal, 786432);
    gemm_mfma(stream, 0, 1, 0, tokh, tokl, Wqah, Wqal, aqkv, nullptr, nullptr, 4128, 3072, 1024, nullptr);

    // attention prep (tokh/tokl, Wqah/Wqal, Qh/Ql, memtok all dead now)
    prep_q_k<<<8192, 256, 0, stream>>>(aqkv, fQh, fQl);
    prep_kk_k<<<16512, 256, 0, stream>>>(aqkv, fKh, fKl);
    prep_vt_k<<<dim3(33, 16, 2), 256, 0, stream>>>(aqkv, fVth);

    // MFMA flash attention
    flash_mfma_k<<<dim3(16, 16, 2), 256, 0, stream>>>(fQh, fQl, fKh, fKl, fVth, oh, ol);

    // Wo projection + FFN (M = 2048 compact rows)
    cvt_split_k<<<1024, 256, 0, stream>>>(Wo, Woh, Wol, 262144);
    gemm_mfma(stream, 0, 0, 1, oh, ol, Woh, Wol, nullptr, y1h, y1l, 2048, 1024, 1024, nullptr);
    cvt_split_k<<<4096, 256, 0, stream>>>(ffW1, ffW1h, ffW1l, 1048576);
    gemm_mfma(stream, 2, 0, 1, y1h, y1l, ffW1h, ffW1l, nullptr, ffhh, ffhl, 2048, 4096, 1024, ffb1);
    cvt_split_k<<<4096, 256, 0, stream>>>(ffW2, ffW2h, ffW2l, 1048576);
    gemm_mfma(stream, 0, 1, 1, ffhh, ffhl, ffW2h, ffW2l, outb, outbh, outbl, 2048, 1024, 4096, ffb2);

    // gate
    gemm_mfma(stream, 0, 0, 1, outbh, outbl, Wqkvh, Wqkvl, nullptr, newQh, newQl, 2048, 1024, 1024, nullptr);
    gemm_mfma(stream, 1, 0, 1, newQh, newQl, pW1h, pW1l, nullptr, hzh, hzl, 2048, 512, 1024, par + PB1);
    gemm_mfma(stream, 0, 1, 0, hzh, hzl, pW2h, pW2l, memq, nullptr, nullptr, 2048, 1024, 512, par + PB2);
    mul_k<<<8192, 256, 0, stream>>>(outb, memq, outp, 2097152);
}

// Round 6
// 2063.747 us; speedup vs baseline: 4.8481x; 1.4658x over previous
//
#include <hip/hip_runtime.h>
#include <math.h>

// ---------------- problem constants ----------------
#define BATCH 2
#define TSEQ 1024
#define DIMD 1024
#define NPERS 16
#define NCH 8
#define NTOK 2064
#define ETA_C 0.9f
#define THETA_C 0.1f
#define ALPHA_C 0.02f

typedef __attribute__((ext_vector_type(4))) float f32x4;
typedef __attribute__((ext_vector_type(8))) short s16x8;
typedef unsigned short u16;

// ---------------- bf16 helpers ----------------
__device__ __forceinline__ u16 f2bf(float f) {
    unsigned int u = __float_as_uint(f);
    return (u16)((u + 0x7fffu + ((u >> 16) & 1u)) >> 16);
}
__device__ __forceinline__ float bf2f(u16 h) { return __uint_as_float(((unsigned)h) << 16); }
__device__ __forceinline__ void split2(float v, u16& h, u16& l) {
    h = f2bf(v); l = f2bf(v - bf2f(h));
}

// ---------------- workspace layout (byte offsets) ----------------
static const size_t oRA = 0;                       // 50,724,864 multiplexed
static const size_t oRB = 50724864;                // 16,908,288
static const size_t oRC = 67633152;                // 12,582,912
static const size_t oRD = 80216064;                // 16,777,216
static const size_t oRE = 96993280;                // 12,582,912 Wqkv h/l (persistent)
static const size_t oRF = 109576192;               //  4,194,304 parW h/l (persistent)
static const size_t oRG = 113770496;               //  4,200,448 par (persistent)
static const size_t oRH = 117970944;               //  8,388,608 outb f32 (Qs split during attn)
// total 126,359,552 bytes

static const size_t PW1 = 0, PB1 = 524288, PW2 = 524800, PB2 = 1049088, PSZ = 1050112;

// ---------------- async global->LDS ----------------
__device__ __forceinline__ void gload_lds16(const u16* g, u16* l) {
    __builtin_amdgcn_global_load_lds(
        (const __attribute__((address_space(1))) unsigned int*)g,
        (__attribute__((address_space(3))) unsigned int*)l, 16, 0, 0);
}

// XCD-chunked block swizzle: each XCD gets a contiguous row-major chunk of tiles
// (bijective when nwg % 8 == 0; identity fallback otherwise).
__device__ __forceinline__ void xcd_swizzle(int& bx, int& by) {
    int gx = gridDim.x, nwg = gx * gridDim.y;
    int lid = blockIdx.y * gx + blockIdx.x;
    int t = lid;
    if ((nwg & 7) == 0) {
        int q = nwg >> 3;
        t = (lid & 7) * q + (lid >> 3);
    }
    bx = t % gx; by = t / gx;
}

// ---------------- split-bf16 MFMA GEMM:  C = act(A @ W^T + bias)  (main path) ----
template<int ACTF, int WF32, int WSPLIT>
__global__ __launch_bounds__(256)
void gemm_mfma_k(const u16* __restrict__ Ah, const u16* __restrict__ Al,
                 const u16* __restrict__ Wh, const u16* __restrict__ Wl,
                 float* __restrict__ C, u16* __restrict__ Chi, u16* __restrict__ Clo,
                 int M, int N, int K, const float* __restrict__ bias)
{
    __shared__ u16 lds[16384];
    const int tid = threadIdx.x;
    const int lane = tid & 63, wid = tid >> 6;
    const int wm = wid >> 1, wn = wid & 1;
    int bx, by; xcd_swizzle(bx, by);
    const int row0 = by * 128, col0 = bx * 128;

    const u16* sp = (wid == 0) ? Ah : (wid == 1) ? Al : (wid == 2) ? Wh : Wl;
    const int rbase = (wid < 2) ? row0 : col0;
    const int lr = lane >> 2, lc = lane & 3;

    f32x4 acc[4][4] = {};
    const int frow = lane & 15, kblk = lane >> 4;

    for (int k0 = 0; k0 < K; k0 += 32) {
        #pragma unroll
        for (int i = 0; i < 8; ++i) {
            int r = i * 16 + lr;
            int gr = rbase + r;
            if (wid < 2 && gr >= M) gr = M - 1;
            int g = lc ^ ((r >> 1) & 3);
            gload_lds16(sp + (size_t)gr * K + k0 + g * 8, &lds[wid * 4096 + i * 512]);
        }
        __syncthreads();

        s16x8 bh[4], bl[4];
        #pragma unroll
        for (int ni = 0; ni < 4; ++ni) {
            int br = wn * 64 + ni * 16 + frow;
            int pc = kblk ^ ((br >> 1) & 3);
            bh[ni] = *(const s16x8*)&lds[2 * 4096 + br * 32 + pc * 8];
            bl[ni] = *(const s16x8*)&lds[3 * 4096 + br * 32 + pc * 8];
        }
        #pragma unroll
        for (int mi = 0; mi < 4; ++mi) {
            int ar = wm * 64 + mi * 16 + frow;
            int pc = kblk ^ ((ar >> 1) & 3);
            s16x8 ah = *(const s16x8*)&lds[0 * 4096 + ar * 32 + pc * 8];
            s16x8 al = *(const s16x8*)&lds[1 * 4096 + ar * 32 + pc * 8];
            #pragma unroll
            for (int ni = 0; ni < 4; ++ni) {
                acc[mi][ni] = __builtin_amdgcn_mfma_f32_16x16x32_bf16(ah, bh[ni], acc[mi][ni], 0, 0, 0);
                acc[mi][ni] = __builtin_amdgcn_mfma_f32_16x16x32_bf16(ah, bl[ni], acc[mi][ni], 0, 0, 0);
                acc[mi][ni] = __builtin_amdgcn_mfma_f32_16x16x32_bf16(al, bh[ni], acc[mi][ni], 0, 0, 0);
            }
        }
        __syncthreads();
    }

    const int erow = (lane >> 4) * 4, ecol = lane & 15;
    #pragma unroll
    for (int mi = 0; mi < 4; ++mi) {
        #pragma unroll
        for (int ni = 0; ni < 4; ++ni) {
            int c = col0 + wn * 64 + ni * 16 + ecol;
            float bv = bias ? bias[c] : 0.f;
            #pragma unroll
            for (int reg = 0; reg < 4; ++reg) {
                int r = row0 + wm * 64 + mi * 16 + erow + reg;
                if (r >= M) continue;
                float v = acc[mi][ni][reg] + bv;
                if (ACTF == 1) v = v / (1.f + __expf(-v));
                else if (ACTF == 2) {
                    float u = 0.7978845608028654f * (v + 0.044715f * v * v * v);
                    v = 0.5f * v * (1.f + tanhf(u));
                }
                size_t o = (size_t)r * N + c;
                if (WF32) C[o] = v;
                if (WSPLIT) { u16 h, l; split2(v, h, l); Chi[o] = h; Clo[o] = l; }
            }
        }
    }
}

static void gemm_mfma(hipStream_t s, int act, int wf32, int wsplit,
                      const u16* Ah, const u16* Al, const u16* Wh, const u16* Wl,
                      float* C, u16* Ch, u16* Cl, int M, int N, int K, const float* bias)
{
    dim3 g(N / 128, (M + 127) / 128), b(256);
    if (act == 0 && wf32 == 1 && wsplit == 0)
        gemm_mfma_k<0,1,0><<<g,b,0,s>>>(Ah,Al,Wh,Wl,C,Ch,Cl,M,N,K,bias);
    else if (act == 0 && wf32 == 1 && wsplit == 1)
        gemm_mfma_k<0,1,1><<<g,b,0,s>>>(Ah,Al,Wh,Wl,C,Ch,Cl,M,N,K,bias);
    else if (act == 0 && wf32 == 0 && wsplit == 1)
        gemm_mfma_k<0,0,1><<<g,b,0,s>>>(Ah,Al,Wh,Wl,C,Ch,Cl,M,N,K,bias);
    else if (act == 1)
        gemm_mfma_k<1,0,1><<<g,b,0,s>>>(Ah,Al,Wh,Wl,C,Ch,Cl,M,N,K,bias);
    else
        gemm_mfma_k<2,0,1><<<g,b,0,s>>>(Ah,Al,Wh,Wl,C,Ch,Cl,M,N,K,bias);
}

// ---------------- scan-specialized split-bf16 MFMA GEMM ----------------
// MODE 1: z1 = A@B^T + bias (f32); h = silu(z1) -> split + splitT
// MODE 2: r = A@B^T + bias - add; split + splitT; col-partials CP[4][N] *= alpha
// MODE 3: C = alpha * A@B^T (f32)
// MODE 4: dh = alpha*(A@B^T)*dsilu(Z); splitT; col-partials CP[4][N]
template<int MODE>
__global__ __launch_bounds__(256)
void gemm_scan_k(const u16* __restrict__ Ah, const u16* __restrict__ Al,
                 const u16* __restrict__ Wh, const u16* __restrict__ Wl,
                 float* __restrict__ C, u16* __restrict__ Chi, u16* __restrict__ Clo,
                 u16* __restrict__ ChiT, u16* __restrict__ CloT,
                 const float* __restrict__ Zf, const float* __restrict__ add,
                 const float* __restrict__ bias, float* __restrict__ CP,
                 int M, int N, int K, float alpha)
{
    __shared__ u16 lds[16384];
    const int tid = threadIdx.x;
    const int lane = tid & 63, wid = tid >> 6;
    const int wm = wid >> 1, wn = wid & 1;
    int bx, by; xcd_swizzle(bx, by);
    const int row0 = by * 128, col0 = bx * 128;

    const u16* sp = (wid == 0) ? Ah : (wid == 1) ? Al : (wid == 2) ? Wh : Wl;
    const int rbase = (wid < 2) ? row0 : col0;
    const int lr = lane >> 2, lc = lane & 3;

    f32x4 acc[4][4] = {};
    const int frow = lane & 15, kblk = lane >> 4;

    for (int k0 = 0; k0 < K; k0 += 32) {
        #pragma unroll
        for (int i = 0; i < 8; ++i) {
            int r = i * 16 + lr;
            int gr = rbase + r;
            int g = lc ^ ((r >> 1) & 3);
            gload_lds16(sp + (size_t)gr * K + k0 + g * 8, &lds[wid * 4096 + i * 512]);
        }
        __syncthreads();

        s16x8 bh[4], bl[4];
        #pragma unroll
        for (int ni = 0; ni < 4; ++ni) {
            int br = wn * 64 + ni * 16 + frow;
            int pc = kblk ^ ((br >> 1) & 3);
            bh[ni] = *(const s16x8*)&lds[2 * 4096 + br * 32 + pc * 8];
            bl[ni] = *(const s16x8*)&lds[3 * 4096 + br * 32 + pc * 8];
        }
        #pragma unroll
        for (int mi = 0; mi < 4; ++mi) {
            int ar = wm * 64 + mi * 16 + frow;
            int pc = kblk ^ ((ar >> 1) & 3);
            s16x8 ah = *(const s16x8*)&lds[0 * 4096 + ar * 32 + pc * 8];
            s16x8 al = *(const s16x8*)&lds[1 * 4096 + ar * 32 + pc * 8];
            #pragma unroll
            for (int ni = 0; ni < 4; ++ni) {
                acc[mi][ni] = __builtin_amdgcn_mfma_f32_16x16x32_bf16(ah, bh[ni], acc[mi][ni], 0, 0, 0);
                acc[mi][ni] = __builtin_amdgcn_mfma_f32_16x16x32_bf16(ah, bl[ni], acc[mi][ni], 0, 0, 0);
                acc[mi][ni] = __builtin_amdgcn_mfma_f32_16x16x32_bf16(al, bh[ni], acc[mi][ni], 0, 0, 0);
            }
        }
        __syncthreads();
    }

    const int erow = (lane >> 4) * 4, ecol = lane & 15;
    float csum[4] = {0.f, 0.f, 0.f, 0.f};
    #pragma unroll
    for (int mi = 0; mi < 4; ++mi) {
        #pragma unroll
        for (int ni = 0; ni < 4; ++ni) {
            int c = col0 + wn * 64 + ni * 16 + ecol;
            #pragma unroll
            for (int reg = 0; reg < 4; ++reg) {
                int r = row0 + wm * 64 + mi * 16 + erow + reg;
                float v = acc[mi][ni][reg];
                size_t o = (size_t)r * N + c;
                if (MODE == 1) {
                    v += bias[c];
                    C[o] = v;
                    float hv = v / (1.f + __expf(-v));
                    u16 h, l; split2(hv, h, l);
                    Chi[o] = h; Clo[o] = l;
                    size_t ot = (size_t)c * M + r;
                    ChiT[ot] = h; CloT[ot] = l;
                } else if (MODE == 2) {
                    v += bias[c] - add[o];
                    u16 h, l; split2(v, h, l);
                    Chi[o] = h; Clo[o] = l;
                    size_t ot = (size_t)c * M + r;
                    ChiT[ot] = h; CloT[ot] = l;
                    csum[ni] += v;
                } else if (MODE == 3) {
                    C[o] = alpha * v;
                } else {
                    v *= alpha;
                    float z = Zf[o];
                    float sg = 1.f / (1.f + __expf(-z));
                    v *= sg * (1.f + z * (1.f - sg));
                    u16 h, l; split2(v, h, l);
                    size_t ot = (size_t)c * M + r;
                    ChiT[ot] = h; CloT[ot] = l;
                    csum[ni] += v;
                }
            }
        }
    }
    if (MODE == 2 || MODE == 4) {
        // deterministic column partial per (row-half): reduce the 4 lane-groups
        #pragma unroll
        for (int ni = 0; ni < 4; ++ni) {
            float s = csum[ni];
            s += __shfl_xor(s, 16);
            s += __shfl_xor(s, 32);
            if ((lane >> 4) == 0) {
                int c = col0 + wn * 64 + ni * 16 + ecol;
                float w = (MODE == 2) ? alpha * s : s;
                CP[(size_t)(by * 2 + wm) * N + c] = w;
            }
        }
    }
}

// ---------------- small kernels ----------------
__global__ void cvt_split_k(const float* __restrict__ in, u16* __restrict__ hi,
                            u16* __restrict__ lo, int n4) {
    int i = blockIdx.x * 256 + threadIdx.x;
    if (i >= n4) return;
    float4 v = *(const float4*)&in[(size_t)i * 4];
    u16 h0,l0,h1,l1,h2,l2,h3,l3;
    split2(v.x,h0,l0); split2(v.y,h1,l1); split2(v.z,h2,l2); split2(v.w,h3,l3);
    ushort4 hv = {h0,h1,h2,h3}, lv = {l0,l1,l2,l3};
    *(ushort4*)&hi[(size_t)i * 4] = hv;
    *(ushort4*)&lo[(size_t)i * 4] = lv;
}
__global__ void transpose_split_k(const float* __restrict__ in, u16* __restrict__ outh,
                                  u16* __restrict__ outl, int R, int C) {
    __shared__ float t[32][33];
    const int c0 = blockIdx.x * 32, r0 = blockIdx.y * 32;
    const size_t zoff = (size_t)blockIdx.z * R * C;
    const int tx = threadIdx.x & 31, ty = threadIdx.x >> 5;
    #pragma unroll
    for (int p = 0; p < 4; ++p) {
        int r = ty + p * 8;
        t[r][tx] = in[zoff + (size_t)(r0 + r) * C + c0 + tx];
    }
    __syncthreads();
    #pragma unroll
    for (int p = 0; p < 4; ++p) {
        int cc = ty + p * 8;
        float v = t[tx][cc];
        u16 h, l; split2(v, h, l);
        size_t o = zoff + (size_t)(c0 + cc) * R + r0 + tx;
        outh[o] = h; outl[o] = l;
    }
}
// momentum update; bias grads from col-partials; maintain W1/W2/W2T split forms
__global__ void update3_k(float* __restrict__ p, float* __restrict__ mo,
                          const float* __restrict__ g,
                          const float* __restrict__ cp1, const float* __restrict__ cp2,
                          u16* __restrict__ w1h, u16* __restrict__ w1l,
                          u16* __restrict__ w2h, u16* __restrict__ w2l,
                          u16* __restrict__ w2th, u16* __restrict__ w2tl, int n) {
    int i = blockIdx.x * 256 + threadIdx.x;
    if (i >= n) return;
    float gi;
    if (i < 524288) gi = g[i];
    else if (i < 524800) {
        int j = i - 524288;
        gi = cp1[j] + cp1[512 + j] + cp1[1024 + j] + cp1[1536 + j];
    } else if (i < 1049088) gi = g[i];
    else {
        int j = i - 1049088;
        gi = cp2[j] + cp2[1024 + j] + cp2[2048 + j] + cp2[3072 + j];
    }
    float m = ETA_C * mo[i] - THETA_C * gi;
    mo[i] = m;
    float pv = (1.f - ALPHA_C) * p[i] + m;
    p[i] = pv;
    if (i < 524288) {
        u16 h, l; split2(pv, h, l); w1h[i] = h; w1l[i] = l;
    } else if (i >= 524800 && i < 1049088) {
        int j = i - 524800;
        u16 h, l; split2(pv, h, l);
        w2h[j] = h; w2l[j] = l;
        int tj = (j & 511) * 1024 + (j >> 9);
        w2th[tj] = h; w2tl[tj] = l;
    }
}
__global__ void extractqkv2_k(const float* __restrict__ qkv, u16* __restrict__ Qh,
                              u16* __restrict__ Ql, float* __restrict__ Kb,
                              float* __restrict__ Vb) {
    size_t idx = (size_t)blockIdx.x * 256 + threadIdx.x;
    int m = (int)(idx / 3072), col = (int)(idx % 3072);
    int b = m >> 10, t = m & 1023;
    float v = qkv[idx];
    if (col < 1024) {
        size_t o = (size_t)m * 1024 + col;
        u16 h, l; split2(v, h, l); Qh[o] = h; Ql[o] = l;
    } else {
        int d = col & 1023;
        int ch = t >> 7, r = t & 127;
        size_t o = ((size_t)((ch * 2 + b) * 128 + r)) * 1024 + d;
        if (col < 2048) Kb[o] = v; else Vb[o] = v;
    }
}
__global__ void tokens_split_k(const float* __restrict__ P, const float* __restrict__ memtok,
                               const float* __restrict__ x, u16* __restrict__ th,
                               u16* __restrict__ tl) {
    size_t idx = (size_t)blockIdx.x * 256 + threadIdx.x;
    int d = (int)(idx & 1023);
    int n = (int)((idx >> 10) % NTOK);
    int b = (int)(idx / ((size_t)NTOK * 1024));
    float v;
    if (n < NPERS)            v = P[(size_t)n * 1024 + d];
    else if (n < NPERS + TSEQ) v = memtok[((size_t)b * TSEQ + (n - NPERS)) * 1024 + d];
    else                      v = x[((size_t)b * TSEQ + (n - NPERS - TSEQ)) * 1024 + d];
    u16 h, l; split2(v, h, l); th[idx] = h; tl[idx] = l;
}
__global__ void mul_k(const float* __restrict__ a, const float* __restrict__ b,
                      float* __restrict__ o, int n) {
    int i = blockIdx.x * 256 + threadIdx.x;
    if (i < n) o[i] = a[i] * b[i];
}

// ---------------- attention prep ----------------
__global__ void prep_q_k(const float* __restrict__ aqkv, u16* __restrict__ Qh,
                         u16* __restrict__ Ql) {
    size_t idx = (size_t)blockIdx.x * 256 + threadIdx.x;
    int d = (int)(idx & 63);
    int row = (int)((idx >> 6) & 1023);
    int h = (int)((idx >> 16) & 15);
    int b = (int)(idx >> 20);
    float v = 0.125f * aqkv[((size_t)b * NTOK + NPERS + TSEQ + row) * 3072 + h * 64 + d];
    u16 hh, ll; split2(v, hh, ll);
    Qh[idx] = hh; Ql[idx] = ll;
}
__global__ void prep_kk_k(const float* __restrict__ aqkv, u16* __restrict__ Kh,
                          u16* __restrict__ Kl) {
    size_t idx = (size_t)blockIdx.x * 256 + threadIdx.x;
    int d = (int)(idx & 63);
    int n = (int)((idx >> 6) % NTOK);
    int t = (int)(idx / (64 * NTOK));
    int h = t & 15, b = t >> 4;
    float v = aqkv[((size_t)b * NTOK + n) * 3072 + 1024 + h * 64 + d];
    u16 hh, ll; split2(v, hh, ll);
    Kh[idx] = hh; Kl[idx] = ll;
}
__global__ void prep_vt_k(const float* __restrict__ aqkv, u16* __restrict__ Vt) {
    __shared__ float t[64][65];
    const int nt = blockIdx.x, h = blockIdx.y, b = blockIdx.z;
    const int j0 = nt * 64;
    const int lx = threadIdx.x & 63, rg = threadIdx.x >> 6;
    #pragma unroll
    for (int p = 0; p < 16; ++p) {
        int r = rg * 16 + p;
        int n = j0 + r;
        t[r][lx] = (n < NTOK) ? aqkv[((size_t)b * NTOK + n) * 3072 + 2048 + h * 64 + lx] : 0.f;
    }
    __syncthreads();
    #pragma unroll
    for (int p = 0; p < 16; ++p) {
        int d = rg * 16 + p;
        int n = j0 + lx;
        if (n < NTOK)
            Vt[((size_t)(b * 16 + h) * 64 + d) * NTOK + n] = f2bf(t[lx][d]);
    }
}

// ---------------- MFMA flash attention ----------------
__global__ __launch_bounds__(256)
void flash_mfma_k(const u16* __restrict__ Qsh, const u16* __restrict__ Qsl,
                  const u16* __restrict__ Ksh, const u16* __restrict__ Ksl,
                  const u16* __restrict__ Vts, u16* __restrict__ oh, u16* __restrict__ ol)
{
    __shared__ u16 lds[7 * 4096];
    u16* QH = lds;            u16* QL = lds + 4096;
    u16* KH = lds + 8192;     u16* KL = lds + 12288;
    u16* VT = lds + 16384;
    u16* PH = lds + 20480;    u16* PL = lds + 24576;

    const int qt = blockIdx.x, h = blockIdx.y, b = blockIdx.z;
    const int tid = threadIdx.x;
    const int lane = tid & 63, wid = tid >> 6;
    const int fr = lane & 15, kq = lane >> 4;
    const int bh = b * 16 + h;
    const int q0c = qt * 64;
    const int q0a = NPERS + TSEQ + q0c;

    {
        const int l8 = lane & 7, lr = lane >> 3;
        #pragma unroll
        for (int jj = 0; jj < 4; ++jj) {
            int j = wid * 4 + jj;
            int buf = j >> 3, i8 = j & 7;
            int row = i8 * 8 + lr;
            int c = l8 ^ (row & 7);
            const u16* src = (buf == 0 ? Qsh : Qsl) +
                             (((size_t)bh * 1024 + q0c + row) << 6) + c * 8;
            gload_lds16(src, (buf == 0 ? QH : QL) + i8 * 512);
        }
    }
    __syncthreads();

    s16x8 qh[2], ql[2];
    #pragma unroll
    for (int kb = 0; kb < 2; ++kb) {
        int r = wid * 16 + fr;
        int sl = (kb * 4 + kq) ^ (fr & 7);
        qh[kb] = *(const s16x8*)&QH[r * 64 + sl * 8];
        ql[kb] = *(const s16x8*)&QL[r * 64 + sl * 8];
    }

    f32x4 Oa[4] = {};
    float mrow[4], lrow[4];
    #pragma unroll
    for (int r = 0; r < 4; ++r) { mrow[r] = -INFINITY; lrow[r] = 0.f; }

    const int jtmax = (q0a + 63) >> 6;
    for (int jt = 0; jt <= jtmax; ++jt) {
        const int j0 = jt * 64;
        {
            const int l8 = lane & 7, lr = lane >> 3;
            #pragma unroll
            for (int jj = 0; jj < 6; ++jj) {
                int j = wid * 6 + jj;
                int buf = j >> 3, i8 = j & 7;
                if (buf < 2) {
                    int row = i8 * 8 + lr;
                    int grow = j0 + row; if (grow > NTOK - 1) grow = NTOK - 1;
                    int c = l8 ^ (row & 7);
                    const u16* src = (buf == 0 ? Ksh : Ksl) +
                                     (((size_t)bh * NTOK + grow) << 6) + c * 8;
                    gload_lds16(src, (buf == 0 ? KH : KL) + i8 * 512);
                } else {
                    int d = i8 * 8 + lr;
                    int c = l8 ^ (d & 7);
                    int col = j0 + c * 8; if (col > NTOK - 8) col = NTOK - 8;
                    const u16* src = Vts + ((size_t)bh * 64 + d) * NTOK + col;
                    gload_lds16(src, VT + i8 * 512);
                }
            }
        }
        __syncthreads();

        f32x4 sacc[4] = {};
        #pragma unroll
        for (int nt = 0; nt < 4; ++nt) {
            #pragma unroll
            for (int kb = 0; kb < 2; ++kb) {
                int br = nt * 16 + fr;
                int sl = (kb * 4 + kq) ^ (fr & 7);
                s16x8 kh = *(const s16x8*)&KH[br * 64 + sl * 8];
                s16x8 kl = *(const s16x8*)&KL[br * 64 + sl * 8];
                sacc[nt] = __builtin_amdgcn_mfma_f32_16x16x32_bf16(qh[kb], kh, sacc[nt], 0, 0, 0);
                sacc[nt] = __builtin_amdgcn_mfma_f32_16x16x32_bf16(ql[kb], kh, sacc[nt], 0, 0, 0);
                sacc[nt] = __builtin_amdgcn_mfma_f32_16x16x32_bf16(qh[kb], kl, sacc[nt], 0, 0, 0);
            }
        }

        #pragma unroll
        for (int r = 0; r < 4; ++r) {
            const int qloc = kq * 4 + r;
            const int qi = q0a + wid * 16 + qloc;
            float sv[4], tmax = -INFINITY;
            #pragma unroll
            for (int nt = 0; nt < 4; ++nt) {
                int kj = j0 + nt * 16 + fr;
                sv[nt] = (kj <= qi) ? sacc[nt][r] : -INFINITY;
                tmax = fmaxf(tmax, sv[nt]);
            }
            #pragma unroll
            for (int off = 1; off < 16; off <<= 1)
                tmax = fmaxf(tmax, __shfl_xor(tmax, off));
            float mnew = fmaxf(mrow[r], tmax);
            float scale = __expf(mrow[r] - mnew);
            float psum = 0.f;
            float p4[4];
            #pragma unroll
            for (int nt = 0; nt < 4; ++nt) { p4[nt] = __expf(sv[nt] - mnew); psum += p4[nt]; }
            #pragma unroll
            for (int off = 1; off < 16; off <<= 1)
                psum += __shfl_xor(psum, off);
            lrow[r] = lrow[r] * scale + psum;
            mrow[r] = mnew;
            #pragma unroll
            for (int dt = 0; dt < 4; ++dt) Oa[dt][r] *= scale;
            const int prow = wid * 16 + qloc;
            #pragma unroll
            for (int nt = 0; nt < 4; ++nt) {
                u16 ph, pl; split2(p4[nt], ph, pl);
                int col = nt * 16 + fr;
                int sl = (col >> 3) ^ (qloc & 7);
                int off = prow * 64 + sl * 8 + (col & 7);
                PH[off] = ph; PL[off] = pl;
            }
        }

        #pragma unroll
        for (int kb = 0; kb < 2; ++kb) {
            int pr = wid * 16 + fr;
            int sl = (kb * 4 + kq) ^ (fr & 7);
            s16x8 pa = *(const s16x8*)&PH[pr * 64 + sl * 8];
            s16x8 pb = *(const s16x8*)&PL[pr * 64 + sl * 8];
            #pragma unroll
            for (int dt = 0; dt < 4; ++dt) {
                int vr = dt * 16 + fr;
                s16x8 vb = *(const s16x8*)&VT[vr * 64 + sl * 8];
                Oa[dt] = __builtin_amdgcn_mfma_f32_16x16x32_bf16(pa, vb, Oa[dt], 0, 0, 0);
                Oa[dt] = __builtin_amdgcn_mfma_f32_16x16x32_bf16(pb, vb, Oa[dt], 0, 0, 0);
            }
        }
        __syncthreads();
    }

    #pragma unroll
    for (int r = 0; r < 4; ++r) {
        float inv = 1.f / lrow[r];
        int row = b * 1024 + q0c + wid * 16 + kq * 4 + r;
        #pragma unroll
        for (int dt = 0; dt < 4; ++dt) {
            float v = Oa[dt][r] * inv;
            size_t o = (size_t)row * 1024 + h * 64 + dt * 16 + fr;
            u16 hh, ll; split2(v, hh, ll);
            oh[o] = hh; ol[o] = ll;
        }
    }
}

// ---------------- launch ----------------
extern "C" void kernel_launch(void* const* d_in, const int* in_sizes, int n_in,
                              void* d_out, int out_size, void* d_ws, size_t ws_size,
                              hipStream_t stream)
{
    const float* x     = (const float*)d_in[0];
    const float* Wqkv  = (const float*)d_in[1];
    const float* mW1   = (const float*)d_in[2];
    const float* mb1   = (const float*)d_in[3];
    const float* mW2   = (const float*)d_in[4];
    const float* mb2   = (const float*)d_in[5];
    const float* Pp    = (const float*)d_in[6];
    const float* Wqa   = (const float*)d_in[7];
    const float* Wo    = (const float*)d_in[8];
    const float* ffW1  = (const float*)d_in[9];
    const float* ffb1  = (const float*)d_in[10];
    const float* ffW2  = (const float*)d_in[11];
    const float* ffb2  = (const float*)d_in[12];
    char* wsb = (char*)d_ws;
    float* outp = (float*)d_out;

    // region A (multiplexed)
    float* qkv   = (float*)(wsb + oRA);
    float* z1    = (float*)(wsb + oRA);                 // [256,512] f32
    float* grd   = (float*)(wsb + oRA + 3145728);       // PSZ floats
    float* cp2   = (float*)(wsb + oRA + 7346176);       // [4][1024]
    float* cp1   = (float*)(wsb + oRA + 7362560);       // [4][512]
    u16* hh_     = (u16*)(wsb + oRA + 8388608);
    u16* hl_     = (u16*)(wsb + oRA + 8650752);
    u16* hTh     = (u16*)(wsb + oRA + 9437184);
    u16* hTl     = (u16*)(wsb + oRA + 9699328);
    u16* rh_     = (u16*)(wsb + oRA + 10485760);
    u16* rl_     = (u16*)(wsb + oRA + 11010048);
    u16* rTh     = (u16*)(wsb + oRA + 11534336);
    u16* rTl     = (u16*)(wsb + oRA + 12058624);
    u16* dhTh    = (u16*)(wsb + oRA + 12582912);
    u16* dhTl    = (u16*)(wsb + oRA + 12845056);
    u16* kcTh    = (u16*)(wsb + oRA + 16777216);
    u16* kcTl    = (u16*)(wsb + oRA + 20971520);
    float* aqkv  = (float*)(wsb + oRA);
    u16* Woh     = (u16*)(wsb + oRA);
    u16* Wol     = (u16*)(wsb + oRA + 2097152);
    u16* ffhh    = (u16*)(wsb + oRA);
    u16* ffhl    = (u16*)(wsb + oRA + 16777216);
    u16* outbh   = (u16*)(wsb + oRA + 33554432);
    u16* outbl   = (u16*)(wsb + oRA + 37748736);
    u16* newQh   = (u16*)(wsb + oRA);
    u16* newQl   = (u16*)(wsb + oRA + 4194304);
    u16* hzh     = (u16*)(wsb + oRA + 8388608);
    u16* hzl     = (u16*)(wsb + oRA + 10485760);
    float* memq  = (float*)(wsb + oRA + 12582912);
    // region B
    float* Kb    = (float*)(wsb + oRB);
    float* Vb    = (float*)(wsb + oRB + 8388608);
    u16* tokh    = (u16*)(wsb + oRB);
    u16* tokl    = (u16*)(wsb + oRB + 8454144);
    u16* oh      = (u16*)(wsb + oRB);
    u16* ol      = (u16*)(wsb + oRB + 4194304);
    u16* fVth    = (u16*)(wsb + oRB + 8388608);
    u16* y1h     = (u16*)(wsb + oRB + 8388608);
    u16* y1l     = (u16*)(wsb + oRB + 12582912);
    // region C
    u16* xh      = (u16*)(wsb + oRC);
    u16* xl      = (u16*)(wsb + oRC + 4194304);
    float* mom   = (float*)(wsb + oRC);
    u16* pW2Th   = (u16*)(wsb + oRC + 5242880);
    u16* pW2Tl   = (u16*)(wsb + oRC + 6291456);
    u16* Wqah    = (u16*)(wsb + oRC);
    u16* Wqal    = (u16*)(wsb + oRC + 6291456);
    u16* fKl     = (u16*)(wsb + oRC);
    // region D
    u16* Qh      = (u16*)(wsb + oRD);
    u16* Ql      = (u16*)(wsb + oRD + 4194304);
    u16* kchh    = (u16*)(wsb + oRD + 8388608);
    u16* kchl    = (u16*)(wsb + oRD + 12582912);
    u16* t1h     = (u16*)(wsb + oRD + 8388608);
    u16* t1l     = (u16*)(wsb + oRD + 10485760);
    float* memtok= (float*)(wsb + oRD);
    u16* fKh     = (u16*)(wsb + oRD);
    u16* ffW1h   = (u16*)(wsb + oRD);
    u16* ffW1l   = (u16*)(wsb + oRD + 8388608);
    u16* ffW2h   = (u16*)(wsb + oRD);
    u16* ffW2l   = (u16*)(wsb + oRD + 8388608);
    // persistent
    u16* Wqkvh   = (u16*)(wsb + oRE);
    u16* Wqkvl   = (u16*)(wsb + oRE + 6291456);
    u16* pW1h    = (u16*)(wsb + oRF);
    u16* pW1l    = (u16*)(wsb + oRF + 1048576);
    u16* pW2h    = (u16*)(wsb + oRF + 2097152);
    u16* pW2l    = (u16*)(wsb + oRF + 3145728);
    float* par   = (float*)(wsb + oRG);
    float* outb  = (float*)(wsb + oRH);
    u16* fQh     = (u16*)(wsb + oRH);
    u16* fQl     = (u16*)(wsb + oRH + 4194304);

    // init memory-MLP params
    hipMemcpyAsync(par + PW1, mW1, 524288 * sizeof(float), hipMemcpyDeviceToDevice, stream);
    hipMemcpyAsync(par + PB1, mb1, 512 * sizeof(float), hipMemcpyDeviceToDevice, stream);
    hipMemcpyAsync(par + PW2, mW2, 524288 * sizeof(float), hipMemcpyDeviceToDevice, stream);
    hipMemcpyAsync(par + PB2, mb2, 1024 * sizeof(float), hipMemcpyDeviceToDevice, stream);

    // qkv = x @ Wqkv^T
    cvt_split_k<<<2048, 256, 0, stream>>>(x, xh, xl, 524288);
    cvt_split_k<<<3072, 256, 0, stream>>>(Wqkv, Wqkvh, Wqkvl, 786432);
    gemm_mfma(stream, 0, 1, 0, xh, xl, Wqkvh, Wqkvl, qkv, nullptr, nullptr, 2048, 3072, 1024, nullptr);
    extractqkv2_k<<<24576, 256, 0, stream>>>(qkv, Qh, Ql, Kb, Vb);

    // scan prep
    hipMemsetAsync(mom, 0, PSZ * sizeof(float), stream);
    cvt_split_k<<<2048, 256, 0, stream>>>(Kb, kchh, kchl, 524288);
    transpose_split_k<<<dim3(32, 8, 8), 256, 0, stream>>>(Kb, kcTh, kcTl, 256, 1024);
    cvt_split_k<<<512, 256, 0, stream>>>(par + PW1, pW1h, pW1l, 131072);
    cvt_split_k<<<512, 256, 0, stream>>>(par + PW2, pW2h, pW2l, 131072);
    transpose_split_k<<<dim3(16, 32, 1), 256, 0, stream>>>(par + PW2, pW2Th, pW2Tl, 1024, 512);

    // memory scan: 8 chunks, all GEMMs split-bf16 MFMA, colsums fused in epilogues
    const float cs = 2.f / (float)(BATCH * 128 * DIMD);
    for (int c = 0; c < NCH; ++c) {
        const u16* kch = kchh + (size_t)c * 262144;
        const u16* kcl = kchl + (size_t)c * 262144;
        const u16* kth = kcTh + (size_t)c * 262144;
        const u16* ktl = kcTl + (size_t)c * 262144;
        const float* vc = Vb + (size_t)c * 262144;
        // z1 = kc@W1^T + b1 ; h = silu(z1) (split + splitT)
        gemm_scan_k<1><<<dim3(4, 2), 256, 0, stream>>>(kch, kcl, pW1h, pW1l,
            z1, hh_, hl_, hTh, hTl, nullptr, nullptr, par + PB1, nullptr, 256, 512, 1024, 1.f);
        // r = h@W2^T + b2 - vc (split + splitT) + col-partials cp2 (x cs)
        gemm_scan_k<2><<<dim3(8, 2), 256, 0, stream>>>(hh_, hl_, pW2h, pW2l,
            nullptr, rh_, rl_, rTh, rTl, nullptr, vc, par + PB2, cp2, 256, 1024, 512, cs);
        // gW2 = cs * rT @ hT^T
        gemm_scan_k<3><<<dim3(4, 8), 256, 0, stream>>>(rTh, rTl, hTh, hTl,
            grd + PW2, nullptr, nullptr, nullptr, nullptr, nullptr, nullptr, nullptr, nullptr,
            1024, 512, 256, cs);
        // dh = cs * (r @ W2) * dsilu(z1)  (splitT) + col-partials cp1
        gemm_scan_k<4><<<dim3(4, 2), 256, 0, stream>>>(rh_, rl_, pW2Th, pW2Tl,
            nullptr, nullptr, nullptr, dhTh, dhTl, z1, nullptr, nullptr, cp1, 256, 512, 1024, cs);
        // gW1 = dhT @ kcT^T
        gemm_scan_k<3><<<dim3(8, 4), 256, 0, stream>>>(dhTh, dhTl, kth, ktl,
            grd + PW1, nullptr, nullptr, nullptr, nullptr, nullptr, nullptr, nullptr, nullptr,
            512, 1024, 256, 1.f);
        update3_k<<<4102, 256, 0, stream>>>(par, mom, grd, cp1, cp2,
            pW1h, pW1l, pW2h, pW2l, pW2Th, pW2Tl, (int)PSZ);
    }

    // memory readout
    gemm_mfma(stream, 1, 0, 1, Qh, Ql, pW1h, pW1l, nullptr, t1h, t1l, 2048, 512, 1024, par + PB1);
    gemm_mfma(stream, 0, 1, 0, t1h, t1l, pW2h, pW2l, memtok, nullptr, nullptr, 2048, 1024, 512, par + PB2);

    // tokens + attention qkv
    tokens_split_k<<<16512, 256, 0, stream>>>(Pp, memtok, x, tokh, tokl);
    cvt_split_k<<<3072, 256, 0, stream>>>(Wqa, Wqah, Wqal, 786432);
    gemm_mfma(stream, 0, 1, 0, tokh, tokl, Wqah, Wqal, aqkv, nullptr, nullptr, 4128, 3072, 1024, nullptr);

    // attention prep
    prep_q_k<<<8192, 256, 0, stream>>>(aqkv, fQh, fQl);
    prep_kk_k<<<16512, 256, 0, stream>>>(aqkv, fKh, fKl);
    prep_vt_k<<<dim3(33, 16, 2), 256, 0, stream>>>(aqkv, fVth);

    // MFMA flash attention
    flash_mfma_k<<<dim3(16, 16, 2), 256, 0, stream>>>(fQh, fQl, fKh, fKl, fVth, oh, ol);

    // Wo projection + FFN (M = 2048 compact rows)
    cvt_split_k<<<1024, 256, 0, stream>>>(Wo, Woh, Wol, 262144);
    gemm_mfma(stream, 0, 0, 1, oh, ol, Woh, Wol, nullptr, y1h, y1l, 2048, 1024, 1024, nullptr);
    cvt_split_k<<<4096, 256, 0, stream>>>(ffW1, ffW1h, ffW1l, 1048576);
    gemm_mfma(stream, 2, 0, 1, y1h, y1l, ffW1h, ffW1l, nullptr, ffhh, ffhl, 2048, 4096, 1024, ffb1);
    cvt_split_k<<<4096, 256, 0, stream>>>(ffW2, ffW2h, ffW2l, 1048576);
    gemm_mfma(stream, 0, 1, 1, ffhh, ffhl, ffW2h, ffW2l, outb, outbh, outbl, 2048, 1024, 4096, ffb2);

    // gate
    gemm_mfma(stream, 0, 0, 1, outbh, outbl, Wqkvh, Wqkvl, nullptr, newQh, newQl, 2048, 1024, 1024, nullptr);
    gemm_mfma(stream, 1, 0, 1, newQh, newQl, pW1h, pW1l, nullptr, hzh, hzl, 2048, 512, 1024, par + PB1);
    gemm_mfma(stream, 0, 1, 0, hzh, hzl, pW2h, pW2l, memq, nullptr, nullptr, 2048, 1024, 512, par + PB2);
    mul_k<<<8192, 256, 0, stream>>>(outb, memq, outp, 2097152);
}

// Round 7
// 1610.245 us; speedup vs baseline: 6.2136x; 1.2816x over previous
//
#include <hip/hip_runtime.h>
#include <math.h>

// ---------------- problem constants ----------------
#define BATCH 2
#define TSEQ 1024
#define DIMD 1024
#define NPERS 16
#define NCH 8
#define NTOK 2064
#define ETA_C 0.9f
#define THETA_C 0.1f
#define ALPHA_C 0.02f

typedef __attribute__((ext_vector_type(4))) float f32x4;
typedef __attribute__((ext_vector_type(8))) short s16x8;
typedef unsigned short u16;

// ---------------- bf16 helpers ----------------
__device__ __forceinline__ u16 f2bf(float f) {
    unsigned int u = __float_as_uint(f);
    return (u16)((u + 0x7fffu + ((u >> 16) & 1u)) >> 16);
}
__device__ __forceinline__ float bf2f(u16 h) { return __uint_as_float(((unsigned)h) << 16); }
__device__ __forceinline__ void split2(float v, u16& h, u16& l) {
    h = f2bf(v); l = f2bf(v - bf2f(h));
}

// ---------------- workspace layout (byte offsets) ----------------
static const size_t oRA = 0;                       // 50,724,864 multiplexed
static const size_t oRB = 50724864;                // 16,908,288
static const size_t oRC = 67633152;                // 12,582,912
static const size_t oRD = 80216064;                // 16,777,216
static const size_t oRE = 96993280;                // 12,582,912 Wqkv h/l (persistent)
static const size_t oRF = 109576192;               //  4,194,304 parW h/l (persistent)
static const size_t oRG = 113770496;               //  4,200,448 par (persistent)
static const size_t oRH = 117970944;               //  8,388,608 outb f32 (Qs split during attn)
// total 126,359,552 bytes

static const size_t PW1 = 0, PB1 = 524288, PW2 = 524800, PB2 = 1049088, PSZ = 1050112;

// ---------------- async global->LDS ----------------
__device__ __forceinline__ void gload_lds16(const u16* g, u16* l) {
    __builtin_amdgcn_global_load_lds(
        (const __attribute__((address_space(1))) unsigned int*)g,
        (__attribute__((address_space(3))) unsigned int*)l, 16, 0, 0);
}

// XCD-chunked block swizzle (bijective when nwg % 8 == 0; identity fallback).
__device__ __forceinline__ void xcd_swizzle(int& bx, int& by) {
    int gx = gridDim.x, nwg = gx * gridDim.y;
    int lid = blockIdx.y * gx + blockIdx.x;
    int t = lid;
    if ((nwg & 7) == 0) {
        int q = nwg >> 3;
        t = (lid & 7) * q + (lid >> 3);
    }
    bx = t % gx; by = t / gx;
}

// stage one 128x32 bf16 tile (this wave's quarter) into buf + wid*4096
__device__ __forceinline__ void stage_tile(const u16* sp, u16* buf, int rbase,
                                           int M, int clampM, int K, int k0,
                                           int wid, int lane) {
    const int lr = lane >> 2, lc = lane & 3;
    #pragma unroll
    for (int i = 0; i < 8; ++i) {
        int r = i * 16 + lr;
        int gr = rbase + r;
        if (clampM && gr >= M) gr = M - 1;
        int g = lc ^ ((r >> 1) & 3);
        gload_lds16(sp + (size_t)gr * K + k0 + g * 8, buf + wid * 4096 + i * 512);
    }
}

// ---------------- split-bf16 MFMA GEMM:  C = act(A @ W^T + bias)  (main path) ----
// Double-buffered K-loop, ONE barrier per K-step: stage(t+1) overlaps compute(t).
template<int ACTF, int WF32, int WSPLIT>
__global__ __launch_bounds__(256)
void gemm_mfma_k(const u16* __restrict__ Ah, const u16* __restrict__ Al,
                 const u16* __restrict__ Wh, const u16* __restrict__ Wl,
                 float* __restrict__ C, u16* __restrict__ Chi, u16* __restrict__ Clo,
                 int M, int N, int K, const float* __restrict__ bias)
{
    __shared__ u16 lds[2][16384];              // dbuf x 4 tiles x [128][32] bf16
    const int tid = threadIdx.x;
    const int lane = tid & 63, wid = tid >> 6;
    const int wm = wid >> 1, wn = wid & 1;
    int bx, by; xcd_swizzle(bx, by);
    const int row0 = by * 128, col0 = bx * 128;

    const u16* sp = (wid == 0) ? Ah : (wid == 1) ? Al : (wid == 2) ? Wh : Wl;
    const int rbase = (wid < 2) ? row0 : col0;
    const int clampM = (wid < 2) ? 1 : 0;

    f32x4 acc[4][4] = {};
    const int frow = lane & 15, kblk = lane >> 4;
    const int nt = K >> 5;

    stage_tile(sp, lds[0], rbase, M, clampM, K, 0, wid, lane);

    for (int t = 0; t < nt; ++t) {
        __syncthreads();                       // stage(t) landed; compute(t-1) done
        if (t + 1 < nt)
            stage_tile(sp, lds[(t + 1) & 1], rbase, M, clampM, K, (t + 1) << 5, wid, lane);
        const u16* cb = lds[t & 1];

        s16x8 bh[4], bl[4];
        #pragma unroll
        for (int ni = 0; ni < 4; ++ni) {
            int br = wn * 64 + ni * 16 + frow;
            int pc = kblk ^ ((br >> 1) & 3);
            bh[ni] = *(const s16x8*)&cb[2 * 4096 + br * 32 + pc * 8];
            bl[ni] = *(const s16x8*)&cb[3 * 4096 + br * 32 + pc * 8];
        }
        #pragma unroll
        for (int mi = 0; mi < 4; ++mi) {
            int ar = wm * 64 + mi * 16 + frow;
            int pc = kblk ^ ((ar >> 1) & 3);
            s16x8 ah = *(const s16x8*)&cb[0 * 4096 + ar * 32 + pc * 8];
            s16x8 al = *(const s16x8*)&cb[1 * 4096 + ar * 32 + pc * 8];
            #pragma unroll
            for (int ni = 0; ni < 4; ++ni) {
                acc[mi][ni] = __builtin_amdgcn_mfma_f32_16x16x32_bf16(ah, bh[ni], acc[mi][ni], 0, 0, 0);
                acc[mi][ni] = __builtin_amdgcn_mfma_f32_16x16x32_bf16(ah, bl[ni], acc[mi][ni], 0, 0, 0);
                acc[mi][ni] = __builtin_amdgcn_mfma_f32_16x16x32_bf16(al, bh[ni], acc[mi][ni], 0, 0, 0);
            }
        }
    }

    const int erow = (lane >> 4) * 4, ecol = lane & 15;
    #pragma unroll
    for (int mi = 0; mi < 4; ++mi) {
        #pragma unroll
        for (int ni = 0; ni < 4; ++ni) {
            int c = col0 + wn * 64 + ni * 16 + ecol;
            float bv = bias ? bias[c] : 0.f;
            #pragma unroll
            for (int reg = 0; reg < 4; ++reg) {
                int r = row0 + wm * 64 + mi * 16 + erow + reg;
                if (r >= M) continue;
                float v = acc[mi][ni][reg] + bv;
                if (ACTF == 1) v = v / (1.f + __expf(-v));
                else if (ACTF == 2) {
                    float u = 0.7978845608028654f * (v + 0.044715f * v * v * v);
                    v = 0.5f * v * (1.f + tanhf(u));
                }
                size_t o = (size_t)r * N + c;
                if (WF32) C[o] = v;
                if (WSPLIT) { u16 h, l; split2(v, h, l); Chi[o] = h; Clo[o] = l; }
            }
        }
    }
}

static void gemm_mfma(hipStream_t s, int act, int wf32, int wsplit,
                      const u16* Ah, const u16* Al, const u16* Wh, const u16* Wl,
                      float* C, u16* Ch, u16* Cl, int M, int N, int K, const float* bias)
{
    dim3 g(N / 128, (M + 127) / 128), b(256);
    if (act == 0 && wf32 == 1 && wsplit == 0)
        gemm_mfma_k<0,1,0><<<g,b,0,s>>>(Ah,Al,Wh,Wl,C,Ch,Cl,M,N,K,bias);
    else if (act == 0 && wf32 == 1 && wsplit == 1)
        gemm_mfma_k<0,1,1><<<g,b,0,s>>>(Ah,Al,Wh,Wl,C,Ch,Cl,M,N,K,bias);
    else if (act == 0 && wf32 == 0 && wsplit == 1)
        gemm_mfma_k<0,0,1><<<g,b,0,s>>>(Ah,Al,Wh,Wl,C,Ch,Cl,M,N,K,bias);
    else if (act == 1)
        gemm_mfma_k<1,0,1><<<g,b,0,s>>>(Ah,Al,Wh,Wl,C,Ch,Cl,M,N,K,bias);
    else
        gemm_mfma_k<2,0,1><<<g,b,0,s>>>(Ah,Al,Wh,Wl,C,Ch,Cl,M,N,K,bias);
}

// ---------------- scan-specialized split-bf16 MFMA GEMM (same dbuf loop) -------
// MODE 1: z1 = A@B^T + bias (f32); h = silu(z1) -> split + splitT
// MODE 2: r = A@B^T + bias - add; split + splitT; col-partials CP (x alpha)
// MODE 3: C = alpha * A@B^T (f32)
// MODE 4: dh = alpha*(A@B^T)*dsilu(Z); splitT; col-partials CP
template<int MODE>
__global__ __launch_bounds__(256)
void gemm_scan_k(const u16* __restrict__ Ah, const u16* __restrict__ Al,
                 const u16* __restrict__ Wh, const u16* __restrict__ Wl,
                 float* __restrict__ C, u16* __restrict__ Chi, u16* __restrict__ Clo,
                 u16* __restrict__ ChiT, u16* __restrict__ CloT,
                 const float* __restrict__ Zf, const float* __restrict__ add,
                 const float* __restrict__ bias, float* __restrict__ CP,
                 int M, int N, int K, float alpha)
{
    __shared__ u16 lds[2][16384];
    const int tid = threadIdx.x;
    const int lane = tid & 63, wid = tid >> 6;
    const int wm = wid >> 1, wn = wid & 1;
    int bx, by; xcd_swizzle(bx, by);
    const int row0 = by * 128, col0 = bx * 128;

    const u16* sp = (wid == 0) ? Ah : (wid == 1) ? Al : (wid == 2) ? Wh : Wl;
    const int rbase = (wid < 2) ? row0 : col0;

    f32x4 acc[4][4] = {};
    const int frow = lane & 15, kblk = lane >> 4;
    const int nt = K >> 5;

    stage_tile(sp, lds[0], rbase, M, 0, K, 0, wid, lane);

    for (int t = 0; t < nt; ++t) {
        __syncthreads();
        if (t + 1 < nt)
            stage_tile(sp, lds[(t + 1) & 1], rbase, M, 0, K, (t + 1) << 5, wid, lane);
        const u16* cb = lds[t & 1];

        s16x8 bh[4], bl[4];
        #pragma unroll
        for (int ni = 0; ni < 4; ++ni) {
            int br = wn * 64 + ni * 16 + frow;
            int pc = kblk ^ ((br >> 1) & 3);
            bh[ni] = *(const s16x8*)&cb[2 * 4096 + br * 32 + pc * 8];
            bl[ni] = *(const s16x8*)&cb[3 * 4096 + br * 32 + pc * 8];
        }
        #pragma unroll
        for (int mi = 0; mi < 4; ++mi) {
            int ar = wm * 64 + mi * 16 + frow;
            int pc = kblk ^ ((ar >> 1) & 3);
            s16x8 ah = *(const s16x8*)&cb[0 * 4096 + ar * 32 + pc * 8];
            s16x8 al = *(const s16x8*)&cb[1 * 4096 + ar * 32 + pc * 8];
            #pragma unroll
            for (int ni = 0; ni < 4; ++ni) {
                acc[mi][ni] = __builtin_amdgcn_mfma_f32_16x16x32_bf16(ah, bh[ni], acc[mi][ni], 0, 0, 0);
                acc[mi][ni] = __builtin_amdgcn_mfma_f32_16x16x32_bf16(ah, bl[ni], acc[mi][ni], 0, 0, 0);
                acc[mi][ni] = __builtin_amdgcn_mfma_f32_16x16x32_bf16(al, bh[ni], acc[mi][ni], 0, 0, 0);
            }
        }
    }

    const int erow = (lane >> 4) * 4, ecol = lane & 15;
    float csum[4] = {0.f, 0.f, 0.f, 0.f};
    #pragma unroll
    for (int mi = 0; mi < 4; ++mi) {
        #pragma unroll
        for (int ni = 0; ni < 4; ++ni) {
            int c = col0 + wn * 64 + ni * 16 + ecol;
            #pragma unroll
            for (int reg = 0; reg < 4; ++reg) {
                int r = row0 + wm * 64 + mi * 16 + erow + reg;
                float v = acc[mi][ni][reg];
                size_t o = (size_t)r * N + c;
                if (MODE == 1) {
                    v += bias[c];
                    C[o] = v;
                    float hv = v / (1.f + __expf(-v));
                    u16 h, l; split2(hv, h, l);
                    Chi[o] = h; Clo[o] = l;
                    size_t ot = (size_t)c * M + r;
                    ChiT[ot] = h; CloT[ot] = l;
                } else if (MODE == 2) {
                    v += bias[c] - add[o];
                    u16 h, l; split2(v, h, l);
                    Chi[o] = h; Clo[o] = l;
                    size_t ot = (size_t)c * M + r;
                    ChiT[ot] = h; CloT[ot] = l;
                    csum[ni] += v;
                } else if (MODE == 3) {
                    C[o] = alpha * v;
                } else {
                    v *= alpha;
                    float z = Zf[o];
                    float sg = 1.f / (1.f + __expf(-z));
                    v *= sg * (1.f + z * (1.f - sg));
                    u16 h, l; split2(v, h, l);
                    size_t ot = (size_t)c * M + r;
                    ChiT[ot] = h; CloT[ot] = l;
                    csum[ni] += v;
                }
            }
        }
    }
    if (MODE == 2 || MODE == 4) {
        #pragma unroll
        for (int ni = 0; ni < 4; ++ni) {
            float s = csum[ni];
            s += __shfl_xor(s, 16);
            s += __shfl_xor(s, 32);
            if ((lane >> 4) == 0) {
                int c = col0 + wn * 64 + ni * 16 + ecol;
                float w = (MODE == 2) ? alpha * s : s;
                CP[(size_t)(by * 2 + wm) * N + c] = w;
            }
        }
    }
}

// ---------------- small kernels ----------------
__global__ void cvt_split_k(const float* __restrict__ in, u16* __restrict__ hi,
                            u16* __restrict__ lo, int n4) {
    int i = blockIdx.x * 256 + threadIdx.x;
    if (i >= n4) return;
    float4 v = *(const float4*)&in[(size_t)i * 4];
    u16 h0,l0,h1,l1,h2,l2,h3,l3;
    split2(v.x,h0,l0); split2(v.y,h1,l1); split2(v.z,h2,l2); split2(v.w,h3,l3);
    ushort4 hv = {h0,h1,h2,h3}, lv = {l0,l1,l2,l3};
    *(ushort4*)&hi[(size_t)i * 4] = hv;
    *(ushort4*)&lo[(size_t)i * 4] = lv;
}
__global__ void transpose_split_k(const float* __restrict__ in, u16* __restrict__ outh,
                                  u16* __restrict__ outl, int R, int C) {
    __shared__ float t[32][33];
    const int c0 = blockIdx.x * 32, r0 = blockIdx.y * 32;
    const size_t zoff = (size_t)blockIdx.z * R * C;
    const int tx = threadIdx.x & 31, ty = threadIdx.x >> 5;
    #pragma unroll
    for (int p = 0; p < 4; ++p) {
        int r = ty + p * 8;
        t[r][tx] = in[zoff + (size_t)(r0 + r) * C + c0 + tx];
    }
    __syncthreads();
    #pragma unroll
    for (int p = 0; p < 4; ++p) {
        int cc = ty + p * 8;
        float v = t[tx][cc];
        u16 h, l; split2(v, h, l);
        size_t o = zoff + (size_t)(c0 + cc) * R + r0 + tx;
        outh[o] = h; outl[o] = l;
    }
}
// momentum update; bias grads from col-partials; maintain W1/W2/W2T split forms
__global__ void update3_k(float* __restrict__ p, float* __restrict__ mo,
                          const float* __restrict__ g,
                          const float* __restrict__ cp1, const float* __restrict__ cp2,
                          u16* __restrict__ w1h, u16* __restrict__ w1l,
                          u16* __restrict__ w2h, u16* __restrict__ w2l,
                          u16* __restrict__ w2th, u16* __restrict__ w2tl, int n) {
    int i = blockIdx.x * 256 + threadIdx.x;
    if (i >= n) return;
    float gi;
    if (i < 524288) gi = g[i];
    else if (i < 524800) {
        int j = i - 524288;
        gi = cp1[j] + cp1[512 + j] + cp1[1024 + j] + cp1[1536 + j];
    } else if (i < 1049088) gi = g[i];
    else {
        int j = i - 1049088;
        gi = cp2[j] + cp2[1024 + j] + cp2[2048 + j] + cp2[3072 + j];
    }
    float m = ETA_C * mo[i] - THETA_C * gi;
    mo[i] = m;
    float pv = (1.f - ALPHA_C) * p[i] + m;
    p[i] = pv;
    if (i < 524288) {
        u16 h, l; split2(pv, h, l); w1h[i] = h; w1l[i] = l;
    } else if (i >= 524800 && i < 1049088) {
        int j = i - 524800;
        u16 h, l; split2(pv, h, l);
        w2h[j] = h; w2l[j] = l;
        int tj = (j & 511) * 1024 + (j >> 9);
        w2th[tj] = h; w2tl[tj] = l;
    }
}
__global__ void extractqkv2_k(const float* __restrict__ qkv, u16* __restrict__ Qh,
                              u16* __restrict__ Ql, float* __restrict__ Kb,
                              float* __restrict__ Vb) {
    size_t idx = (size_t)blockIdx.x * 256 + threadIdx.x;
    int m = (int)(idx / 3072), col = (int)(idx % 3072);
    int b = m >> 10, t = m & 1023;
    float v = qkv[idx];
    if (col < 1024) {
        size_t o = (size_t)m * 1024 + col;
        u16 h, l; split2(v, h, l); Qh[o] = h; Ql[o] = l;
    } else {
        int d = col & 1023;
        int ch = t >> 7, r = t & 127;
        size_t o = ((size_t)((ch * 2 + b) * 128 + r)) * 1024 + d;
        if (col < 2048) Kb[o] = v; else Vb[o] = v;
    }
}
__global__ void tokens_split_k(const float* __restrict__ P, const float* __restrict__ memtok,
                               const float* __restrict__ x, u16* __restrict__ th,
                               u16* __restrict__ tl) {
    size_t idx = (size_t)blockIdx.x * 256 + threadIdx.x;
    int d = (int)(idx & 1023);
    int n = (int)((idx >> 10) % NTOK);
    int b = (int)(idx / ((size_t)NTOK * 1024));
    float v;
    if (n < NPERS)            v = P[(size_t)n * 1024 + d];
    else if (n < NPERS + TSEQ) v = memtok[((size_t)b * TSEQ + (n - NPERS)) * 1024 + d];
    else                      v = x[((size_t)b * TSEQ + (n - NPERS - TSEQ)) * 1024 + d];
    u16 h, l; split2(v, h, l); th[idx] = h; tl[idx] = l;
}
__global__ void mul_k(const float* __restrict__ a, const float* __restrict__ b,
                      float* __restrict__ o, int n) {
    int i = blockIdx.x * 256 + threadIdx.x;
    if (i < n) o[i] = a[i] * b[i];
}

// ---------------- attention prep ----------------
__global__ void prep_q_k(const float* __restrict__ aqkv, u16* __restrict__ Qh,
                         u16* __restrict__ Ql) {
    size_t idx = (size_t)blockIdx.x * 256 + threadIdx.x;
    int d = (int)(idx & 63);
    int row = (int)((idx >> 6) & 1023);
    int h = (int)((idx >> 16) & 15);
    int b = (int)(idx >> 20);
    float v = 0.125f * aqkv[((size_t)b * NTOK + NPERS + TSEQ + row) * 3072 + h * 64 + d];
    u16 hh, ll; split2(v, hh, ll);
    Qh[idx] = hh; Ql[idx] = ll;
}
__global__ void prep_kk_k(const float* __restrict__ aqkv, u16* __restrict__ Kh,
                          u16* __restrict__ Kl) {
    size_t idx = (size_t)blockIdx.x * 256 + threadIdx.x;
    int d = (int)(idx & 63);
    int n = (int)((idx >> 6) % NTOK);
    int t = (int)(idx / (64 * NTOK));
    int h = t & 15, b = t >> 4;
    float v = aqkv[((size_t)b * NTOK + n) * 3072 + 1024 + h * 64 + d];
    u16 hh, ll; split2(v, hh, ll);
    Kh[idx] = hh; Kl[idx] = ll;
}
__global__ void prep_vt_k(const float* __restrict__ aqkv, u16* __restrict__ Vt) {
    __shared__ float t[64][65];
    const int nt = blockIdx.x, h = blockIdx.y, b = blockIdx.z;
    const int j0 = nt * 64;
    const int lx = threadIdx.x & 63, rg = threadIdx.x >> 6;
    #pragma unroll
    for (int p = 0; p < 16; ++p) {
        int r = rg * 16 + p;
        int n = j0 + r;
        t[r][lx] = (n < NTOK) ? aqkv[((size_t)b * NTOK + n) * 3072 + 2048 + h * 64 + lx] : 0.f;
    }
    __syncthreads();
    #pragma unroll
    for (int p = 0; p < 16; ++p) {
        int d = rg * 16 + p;
        int n = j0 + lx;
        if (n < NTOK)
            Vt[((size_t)(b * 16 + h) * 64 + d) * NTOK + n] = f2bf(t[lx][d]);
    }
}

// ---------------- MFMA flash attention (KV double-buffered) ----------------
__global__ __launch_bounds__(256)
void flash_mfma_k(const u16* __restrict__ Qsh, const u16* __restrict__ Qsl,
                  const u16* __restrict__ Ksh, const u16* __restrict__ Ksl,
                  const u16* __restrict__ Vts, u16* __restrict__ oh, u16* __restrict__ ol)
{
    __shared__ u16 lds[40960];             // QH QL | kv0{KH KL VT} | kv1{...} | PH PL
    u16* QH = lds;            u16* QL = lds + 4096;
    u16* KV0 = lds + 8192;    u16* KV1 = lds + 20480;
    u16* PH = lds + 32768;    u16* PL = lds + 36864;

    const int qt = blockIdx.x, h = blockIdx.y, b = blockIdx.z;
    const int tid = threadIdx.x;
    const int lane = tid & 63, wid = tid >> 6;
    const int fr = lane & 15, kq = lane >> 4;
    const int bh = b * 16 + h;
    const int q0c = qt * 64;
    const int q0a = NPERS + TSEQ + q0c;
    const int jtmax = (q0a + 63) >> 6;
    const int l8 = lane & 7, lr8 = lane >> 3;

    // KV staging: 24 gload instrs, wave does 6, into kvb{KH,KL,VT}
    auto stageKV = [&](int jt, u16* kvb) {
        const int j0 = jt * 64;
        #pragma unroll
        for (int jj = 0; jj < 6; ++jj) {
            int j = wid * 6 + jj;
            int buf = j >> 3, i8 = j & 7;
            if (buf < 2) {
                int row = i8 * 8 + lr8;
                int grow = j0 + row; if (grow > NTOK - 1) grow = NTOK - 1;
                int c = l8 ^ (row & 7);
                const u16* src = (buf == 0 ? Ksh : Ksl) +
                                 (((size_t)bh * NTOK + grow) << 6) + c * 8;
                gload_lds16(src, kvb + buf * 4096 + i8 * 512);
            } else {
                int d = i8 * 8 + lr8;
                int c = l8 ^ (d & 7);
                int col = j0 + c * 8; if (col > NTOK - 8) col = NTOK - 8;
                const u16* src = Vts + ((size_t)bh * 64 + d) * NTOK + col;
                gload_lds16(src, kvb + 8192 + i8 * 512);
            }
        }
    };

    {   // stage Q (once): 16 gload instrs, wave does 4
        #pragma unroll
        for (int jj = 0; jj < 4; ++jj) {
            int j = wid * 4 + jj;
            int buf = j >> 3, i8 = j & 7;
            int row = i8 * 8 + lr8;
            int c = l8 ^ (row & 7);
            const u16* src = (buf == 0 ? Qsh : Qsl) +
                             (((size_t)bh * 1024 + q0c + row) << 6) + c * 8;
            gload_lds16(src, (buf == 0 ? QH : QL) + i8 * 512);
        }
    }
    stageKV(0, KV0);
    __syncthreads();                        // Q + KV(0) landed

    s16x8 qh[2], ql[2];
    #pragma unroll
    for (int kb = 0; kb < 2; ++kb) {
        int r = wid * 16 + fr;
        int sl = (kb * 4 + kq) ^ (fr & 7);
        qh[kb] = *(const s16x8*)&QH[r * 64 + sl * 8];
        ql[kb] = *(const s16x8*)&QL[r * 64 + sl * 8];
    }

    f32x4 Oa[4] = {};
    float mrow[4], lrow[4];
    #pragma unroll
    for (int r = 0; r < 4; ++r) { mrow[r] = -INFINITY; lrow[r] = 0.f; }

    for (int jt = 0; jt <= jtmax; ++jt) {
        const int j0 = jt * 64;
        if (jt) __syncthreads();            // KV(jt) landed; compute(jt-1) done
        if (jt + 1 <= jtmax) stageKV(jt + 1, (jt & 1) ? KV0 : KV1);
        u16* kvb = (jt & 1) ? KV1 : KV0;
        u16* KH = kvb; u16* KL = kvb + 4096; u16* VT = kvb + 8192;

        f32x4 sacc[4] = {};
        #pragma unroll
        for (int nt = 0; nt < 4; ++nt) {
            #pragma unroll
            for (int kb = 0; kb < 2; ++kb) {
                int br = nt * 16 + fr;
                int sl = (kb * 4 + kq) ^ (fr & 7);
                s16x8 kh = *(const s16x8*)&KH[br * 64 + sl * 8];
                s16x8 kl = *(const s16x8*)&KL[br * 64 + sl * 8];
                sacc[nt] = __builtin_amdgcn_mfma_f32_16x16x32_bf16(qh[kb], kh, sacc[nt], 0, 0, 0);
                sacc[nt] = __builtin_amdgcn_mfma_f32_16x16x32_bf16(ql[kb], kh, sacc[nt], 0, 0, 0);
                sacc[nt] = __builtin_amdgcn_mfma_f32_16x16x32_bf16(qh[kb], kl, sacc[nt], 0, 0, 0);
            }
        }

        #pragma unroll
        for (int r = 0; r < 4; ++r) {
            const int qloc = kq * 4 + r;
            const int qi = q0a + wid * 16 + qloc;
            float sv[4], tmax = -INFINITY;
            #pragma unroll
            for (int nt = 0; nt < 4; ++nt) {
                int kj = j0 + nt * 16 + fr;
                sv[nt] = (kj <= qi) ? sacc[nt][r] : -INFINITY;
                tmax = fmaxf(tmax, sv[nt]);
            }
            #pragma unroll
            for (int off = 1; off < 16; off <<= 1)
                tmax = fmaxf(tmax, __shfl_xor(tmax, off));
            float mnew = fmaxf(mrow[r], tmax);
            float scale = __expf(mrow[r] - mnew);
            float psum = 0.f;
            float p4[4];
            #pragma unroll
            for (int nt = 0; nt < 4; ++nt) { p4[nt] = __expf(sv[nt] - mnew); psum += p4[nt]; }
            #pragma unroll
            for (int off = 1; off < 16; off <<= 1)
                psum += __shfl_xor(psum, off);
            lrow[r] = lrow[r] * scale + psum;
            mrow[r] = mnew;
            #pragma unroll
            for (int dt = 0; dt < 4; ++dt) Oa[dt][r] *= scale;
            const int prow = wid * 16 + qloc;
            #pragma unroll
            for (int nt = 0; nt < 4; ++nt) {
                u16 ph, pl; split2(p4[nt], ph, pl);
                int col = nt * 16 + fr;
                int sl = (col >> 3) ^ (qloc & 7);
                int off = prow * 64 + sl * 8 + (col & 7);
                PH[off] = ph; PL[off] = pl;
            }
        }

        #pragma unroll
        for (int kb = 0; kb < 2; ++kb) {
            int pr = wid * 16 + fr;
            int sl = (kb * 4 + kq) ^ (fr & 7);
            s16x8 pa = *(const s16x8*)&PH[pr * 64 + sl * 8];
            s16x8 pb = *(const s16x8*)&PL[pr * 64 + sl * 8];
            #pragma unroll
            for (int dt = 0; dt < 4; ++dt) {
                int vr = dt * 16 + fr;
                s16x8 vb = *(const s16x8*)&VT[vr * 64 + sl * 8];
                Oa[dt] = __builtin_amdgcn_mfma_f32_16x16x32_bf16(pa, vb, Oa[dt], 0, 0, 0);
                Oa[dt] = __builtin_amdgcn_mfma_f32_16x16x32_bf16(pb, vb, Oa[dt], 0, 0, 0);
            }
        }
    }

    #pragma unroll
    for (int r = 0; r < 4; ++r) {
        float inv = 1.f / lrow[r];
        int row = b * 1024 + q0c + wid * 16 + kq * 4 + r;
        #pragma unroll
        for (int dt = 0; dt < 4; ++dt) {
            float v = Oa[dt][r] * inv;
            size_t o = (size_t)row * 1024 + h * 64 + dt * 16 + fr;
            u16 hh, ll; split2(v, hh, ll);
            oh[o] = hh; ol[o] = ll;
        }
    }
}

// ---------------- launch ----------------
extern "C" void kernel_launch(void* const* d_in, const int* in_sizes, int n_in,
                              void* d_out, int out_size, void* d_ws, size_t ws_size,
                              hipStream_t stream)
{
    const float* x     = (const float*)d_in[0];
    const float* Wqkv  = (const float*)d_in[1];
    const float* mW1   = (const float*)d_in[2];
    const float* mb1   = (const float*)d_in[3];
    const float* mW2   = (const float*)d_in[4];
    const float* mb2   = (const float*)d_in[5];
    const float* Pp    = (const float*)d_in[6];
    const float* Wqa   = (const float*)d_in[7];
    const float* Wo    = (const float*)d_in[8];
    const float* ffW1  = (const float*)d_in[9];
    const float* ffb1  = (const float*)d_in[10];
    const float* ffW2  = (const float*)d_in[11];
    const float* ffb2  = (const float*)d_in[12];
    char* wsb = (char*)d_ws;
    float* outp = (float*)d_out;

    // region A (multiplexed)
    float* qkv   = (float*)(wsb + oRA);
    float* z1    = (float*)(wsb + oRA);
    float* grd   = (float*)(wsb + oRA + 3145728);
    float* cp2   = (float*)(wsb + oRA + 7346176);
    float* cp1   = (float*)(wsb + oRA + 7362560);
    u16* hh_     = (u16*)(wsb + oRA + 8388608);
    u16* hl_     = (u16*)(wsb + oRA + 8650752);
    u16* hTh     = (u16*)(wsb + oRA + 9437184);
    u16* hTl     = (u16*)(wsb + oRA + 9699328);
    u16* rh_     = (u16*)(wsb + oRA + 10485760);
    u16* rl_     = (u16*)(wsb + oRA + 11010048);
    u16* rTh     = (u16*)(wsb + oRA + 11534336);
    u16* rTl     = (u16*)(wsb + oRA + 12058624);
    u16* dhTh    = (u16*)(wsb + oRA + 12582912);
    u16* dhTl    = (u16*)(wsb + oRA + 12845056);
    u16* kcTh    = (u16*)(wsb + oRA + 16777216);
    u16* kcTl    = (u16*)(wsb + oRA + 20971520);
    float* aqkv  = (float*)(wsb + oRA);
    u16* Woh     = (u16*)(wsb + oRA);
    u16* Wol     = (u16*)(wsb + oRA + 2097152);
    u16* ffhh    = (u16*)(wsb + oRA);
    u16* ffhl    = (u16*)(wsb + oRA + 16777216);
    u16* outbh   = (u16*)(wsb + oRA + 33554432);
    u16* outbl   = (u16*)(wsb + oRA + 37748736);
    u16* newQh   = (u16*)(wsb + oRA);
    u16* newQl   = (u16*)(wsb + oRA + 4194304);
    u16* hzh     = (u16*)(wsb + oRA + 8388608);
    u16* hzl     = (u16*)(wsb + oRA + 10485760);
    float* memq  = (float*)(wsb + oRA + 12582912);
    // region B
    float* Kb    = (float*)(wsb + oRB);
    float* Vb    = (float*)(wsb + oRB + 8388608);
    u16* tokh    = (u16*)(wsb + oRB);
    u16* tokl    = (u16*)(wsb + oRB + 8454144);
    u16* oh      = (u16*)(wsb + oRB);
    u16* ol      = (u16*)(wsb + oRB + 4194304);
    u16* fVth    = (u16*)(wsb + oRB + 8388608);
    u16* y1h     = (u16*)(wsb + oRB + 8388608);
    u16* y1l     = (u16*)(wsb + oRB + 12582912);
    // region C
    u16* xh      = (u16*)(wsb + oRC);
    u16* xl      = (u16*)(wsb + oRC + 4194304);
    float* mom   = (float*)(wsb + oRC);
    u16* pW2Th   = (u16*)(wsb + oRC + 5242880);
    u16* pW2Tl   = (u16*)(wsb + oRC + 6291456);
    u16* Wqah    = (u16*)(wsb + oRC);
    u16* Wqal    = (u16*)(wsb + oRC + 6291456);
    u16* fKl     = (u16*)(wsb + oRC);
    // region D
    u16* Qh      = (u16*)(wsb + oRD);
    u16* Ql      = (u16*)(wsb + oRD + 4194304);
    u16* kchh    = (u16*)(wsb + oRD + 8388608);
    u16* kchl    = (u16*)(wsb + oRD + 12582912);
    u16* t1h     = (u16*)(wsb + oRD + 8388608);
    u16* t1l     = (u16*)(wsb + oRD + 10485760);
    float* memtok= (float*)(wsb + oRD);
    u16* fKh     = (u16*)(wsb + oRD);
    u16* ffW1h   = (u16*)(wsb + oRD);
    u16* ffW1l   = (u16*)(wsb + oRD + 8388608);
    u16* ffW2h   = (u16*)(wsb + oRD);
    u16* ffW2l   = (u16*)(wsb + oRD + 8388608);
    // persistent
    u16* Wqkvh   = (u16*)(wsb + oRE);
    u16* Wqkvl   = (u16*)(wsb + oRE + 6291456);
    u16* pW1h    = (u16*)(wsb + oRF);
    u16* pW1l    = (u16*)(wsb + oRF + 1048576);
    u16* pW2h    = (u16*)(wsb + oRF + 2097152);
    u16* pW2l    = (u16*)(wsb + oRF + 3145728);
    float* par   = (float*)(wsb + oRG);
    float* outb  = (float*)(wsb + oRH);
    u16* fQh     = (u16*)(wsb + oRH);
    u16* fQl     = (u16*)(wsb + oRH + 4194304);

    // init memory-MLP params
    hipMemcpyAsync(par + PW1, mW1, 524288 * sizeof(float), hipMemcpyDeviceToDevice, stream);
    hipMemcpyAsync(par + PB1, mb1, 512 * sizeof(float), hipMemcpyDeviceToDevice, stream);
    hipMemcpyAsync(par + PW2, mW2, 524288 * sizeof(float), hipMemcpyDeviceToDevice, stream);
    hipMemcpyAsync(par + PB2, mb2, 1024 * sizeof(float), hipMemcpyDeviceToDevice, stream);

    // qkv = x @ Wqkv^T
    cvt_split_k<<<2048, 256, 0, stream>>>(x, xh, xl, 524288);
    cvt_split_k<<<3072, 256, 0, stream>>>(Wqkv, Wqkvh, Wqkvl, 786432);
    gemm_mfma(stream, 0, 1, 0, xh, xl, Wqkvh, Wqkvl, qkv, nullptr, nullptr, 2048, 3072, 1024, nullptr);
    extractqkv2_k<<<24576, 256, 0, stream>>>(qkv, Qh, Ql, Kb, Vb);

    // scan prep
    hipMemsetAsync(mom, 0, PSZ * sizeof(float), stream);
    cvt_split_k<<<2048, 256, 0, stream>>>(Kb, kchh, kchl, 524288);
    transpose_split_k<<<dim3(32, 8, 8), 256, 0, stream>>>(Kb, kcTh, kcTl, 256, 1024);
    cvt_split_k<<<512, 256, 0, stream>>>(par + PW1, pW1h, pW1l, 131072);
    cvt_split_k<<<512, 256, 0, stream>>>(par + PW2, pW2h, pW2l, 131072);
    transpose_split_k<<<dim3(16, 32, 1), 256, 0, stream>>>(par + PW2, pW2Th, pW2Tl, 1024, 512);

    // memory scan
    const float cs = 2.f / (float)(BATCH * 128 * DIMD);
    for (int c = 0; c < NCH; ++c) {
        const u16* kch = kchh + (size_t)c * 262144;
        const u16* kcl = kchl + (size_t)c * 262144;
        const u16* kth = kcTh + (size_t)c * 262144;
        const u16* ktl = kcTl + (size_t)c * 262144;
        const float* vc = Vb + (size_t)c * 262144;
        gemm_scan_k<1><<<dim3(4, 2), 256, 0, stream>>>(kch, kcl, pW1h, pW1l,
            z1, hh_, hl_, hTh, hTl, nullptr, nullptr, par + PB1, nullptr, 256, 512, 1024, 1.f);
        gemm_scan_k<2><<<dim3(8, 2), 256, 0, stream>>>(hh_, hl_, pW2h, pW2l,
            nullptr, rh_, rl_, rTh, rTl, nullptr, vc, par + PB2, cp2, 256, 1024, 512, cs);
        gemm_scan_k<3><<<dim3(4, 8), 256, 0, stream>>>(rTh, rTl, hTh, hTl,
            grd + PW2, nullptr, nullptr, nullptr, nullptr, nullptr, nullptr, nullptr, nullptr,
            1024, 512, 256, cs);
        gemm_scan_k<4><<<dim3(4, 2), 256, 0, stream>>>(rh_, rl_, pW2Th, pW2Tl,
            nullptr, nullptr, nullptr, dhTh, dhTl, z1, nullptr, nullptr, cp1, 256, 512, 1024, cs);
        gemm_scan_k<3><<<dim3(8, 4), 256, 0, stream>>>(dhTh, dhTl, kth, ktl,
            grd + PW1, nullptr, nullptr, nullptr, nullptr, nullptr, nullptr, nullptr, nullptr,
            512, 1024, 256, 1.f);
        update3_k<<<4102, 256, 0, stream>>>(par, mom, grd, cp1, cp2,
            pW1h, pW1l, pW2h, pW2l, pW2Th, pW2Tl, (int)PSZ);
    }

    // memory readout
    gemm_mfma(stream, 1, 0, 1, Qh, Ql, pW1h, pW1l, nullptr, t1h, t1l, 2048, 512, 1024, par + PB1);
    gemm_mfma(stream, 0, 1, 0, t1h, t1l, pW2h, pW2l, memtok, nullptr, nullptr, 2048, 1024, 512, par + PB2);

    // tokens + attention qkv
    tokens_split_k<<<16512, 256, 0, stream>>>(Pp, memtok, x, tokh, tokl);
    cvt_split_k<<<3072, 256, 0, stream>>>(Wqa, Wqah, Wqal, 786432);
    gemm_mfma(stream, 0, 1, 0, tokh, tokl, Wqah, Wqal, aqkv, nullptr, nullptr, 4128, 3072, 1024, nullptr);

    // attention prep
    prep_q_k<<<8192, 256, 0, stream>>>(aqkv, fQh, fQl);
    prep_kk_k<<<16512, 256, 0, stream>>>(aqkv, fKh, fKl);
    prep_vt_k<<<dim3(33, 16, 2), 256, 0, stream>>>(aqkv, fVth);

    // MFMA flash attention
    flash_mfma_k<<<dim3(16, 16, 2), 256, 0, stream>>>(fQh, fQl, fKh, fKl, fVth, oh, ol);

    // Wo projection + FFN (M = 2048 compact rows)
    cvt_split_k<<<1024, 256, 0, stream>>>(Wo, Woh, Wol, 262144);
    gemm_mfma(stream, 0, 0, 1, oh, ol, Woh, Wol, nullptr, y1h, y1l, 2048, 1024, 1024, nullptr);
    cvt_split_k<<<4096, 256, 0, stream>>>(ffW1, ffW1h, ffW1l, 1048576);
    gemm_mfma(stream, 2, 0, 1, y1h, y1l, ffW1h, ffW1l, nullptr, ffhh, ffhl, 2048, 4096, 1024, ffb1);
    cvt_split_k<<<4096, 256, 0, stream>>>(ffW2, ffW2h, ffW2l, 1048576);
    gemm_mfma(stream, 0, 1, 1, ffhh, ffhl, ffW2h, ffW2l, outb, outbh, outbl, 2048, 1024, 4096, ffb2);

    // gate
    gemm_mfma(stream, 0, 0, 1, outbh, outbl, Wqkvh, Wqkvl, nullptr, newQh, newQl, 2048, 1024, 1024, nullptr);
    gemm_mfma(stream, 1, 0, 1, newQh, newQl, pW1h, pW1l, nullptr, hzh, hzl, 2048, 512, 1024, par + PB1);
    gemm_mfma(stream, 0, 1, 0, hzh, hzl, pW2h, pW2l, memq, nullptr, nullptr, 2048, 1024, 512, par + PB2);
    mul_k<<<8192, 256, 0, stream>>>(outb, memq, outp, 2097152);
}

// Round 8
// 1509.548 us; speedup vs baseline: 6.6280x; 1.0667x over previous
//
#include <hip/hip_runtime.h>
#include <math.h>

// ---------------- problem constants ----------------
#define BATCH 2
#define TSEQ 1024
#define DIMD 1024
#define NPERS 16
#define NCH 8
#define NTOK 2064
#define ETA_C 0.9f
#define THETA_C 0.1f
#define ALPHA_C 0.02f

typedef __attribute__((ext_vector_type(4))) float f32x4;
typedef __attribute__((ext_vector_type(8))) short s16x8;
typedef unsigned short u16;

// ---------------- bf16 helpers ----------------
__device__ __forceinline__ u16 f2bf(float f) {
    unsigned int u = __float_as_uint(f);
    return (u16)((u + 0x7fffu + ((u >> 16) & 1u)) >> 16);
}
__device__ __forceinline__ float bf2f(u16 h) { return __uint_as_float(((unsigned)h) << 16); }
__device__ __forceinline__ void split2(float v, u16& h, u16& l) {
    h = f2bf(v); l = f2bf(v - bf2f(h));
}

// ---------------- workspace layout (byte offsets) ----------------
static const size_t oRA = 0;                       // 50,724,864 multiplexed
static const size_t oRB = 50724864;                // 16,908,288
static const size_t oRC = 67633152;                // 12,582,912
static const size_t oRD = 80216064;                // 16,777,216
static const size_t oRE = 96993280;                // 12,582,912 Wqkv h/l (persistent)
static const size_t oRF = 109576192;               //  4,194,304 parW h/l (persistent)
static const size_t oRG = 113770496;               //  4,200,448 par (persistent)
static const size_t oRH = 117970944;               //  8,388,608 outb f32 (Qs split during attn)
// total 126,359,552 bytes

static const size_t PW1 = 0, PB1 = 524288, PW2 = 524800, PB2 = 1049088, PSZ = 1050112;

// ---------------- async global->LDS ----------------
__device__ __forceinline__ void gload_lds16(const u16* g, u16* l) {
    __builtin_amdgcn_global_load_lds(
        (const __attribute__((address_space(1))) unsigned int*)g,
        (__attribute__((address_space(3))) unsigned int*)l, 16, 0, 0);
}

// XCD-chunked block swizzle (bijective when nwg % 8 == 0; identity fallback).
__device__ __forceinline__ void xcd_swizzle(int& bx, int& by) {
    int gx = gridDim.x, nwg = gx * gridDim.y;
    int lid = blockIdx.y * gx + blockIdx.x;
    int t = lid;
    if ((nwg & 7) == 0) {
        int q = nwg >> 3;
        t = (lid & 7) * q + (lid >> 3);
    }
    bx = t % gx; by = t / gx;
}

// stage one 128x32 bf16 tile (this wave's quarter) into buf + wid*4096
__device__ __forceinline__ void stage_tile(const u16* sp, u16* buf, int rbase,
                                           int M, int clampM, int K, int k0,
                                           int wid, int lane) {
    const int lr = lane >> 2, lc = lane & 3;
    #pragma unroll
    for (int i = 0; i < 8; ++i) {
        int r = i * 16 + lr;
        int gr = rbase + r;
        if (clampM && gr >= M) gr = M - 1;
        int g = lc ^ ((r >> 1) & 3);
        gload_lds16(sp + (size_t)gr * K + k0 + g * 8, buf + wid * 4096 + i * 512);
    }
}

// ---------------- split-bf16 MFMA GEMM:  C = act(A @ W^T + bias) ----------------
// Double-buffered K-loop, ONE barrier per K-step.  PARTIAL: gridDim.z = S K-slices,
// each block writes raw f32 partial to C[(z*M + r)*N + c]; epilogue in reduce_k.
template<int ACTF, int WF32, int WSPLIT, int PARTIAL>
__global__ __launch_bounds__(256)
void gemm_mfma_k(const u16* __restrict__ Ah, const u16* __restrict__ Al,
                 const u16* __restrict__ Wh, const u16* __restrict__ Wl,
                 float* __restrict__ C, u16* __restrict__ Chi, u16* __restrict__ Clo,
                 int M, int N, int K, const float* __restrict__ bias)
{
    __shared__ u16 lds[2][16384];              // dbuf x 4 tiles x [128][32] bf16
    const int tid = threadIdx.x;
    const int lane = tid & 63, wid = tid >> 6;
    const int wm = wid >> 1, wn = wid & 1;
    int bx, by; xcd_swizzle(bx, by);
    const int row0 = by * 128, col0 = bx * 128;

    const u16* sp = (wid == 0) ? Ah : (wid == 1) ? Al : (wid == 2) ? Wh : Wl;
    const int rbase = (wid < 2) ? row0 : col0;
    const int clampM = (wid < 2) ? 1 : 0;

    f32x4 acc[4][4] = {};
    const int frow = lane & 15, kblk = lane >> 4;

    int kbeg = 0, kend = K;
    if (PARTIAL) {
        int Kseg = K / gridDim.z;
        kbeg = blockIdx.z * Kseg;
        kend = kbeg + Kseg;
    }
    const int nt = (kend - kbeg) >> 5;

    stage_tile(sp, lds[0], rbase, M, clampM, K, kbeg, wid, lane);

    for (int t = 0; t < nt; ++t) {
        __syncthreads();                       // stage(t) landed; compute(t-1) done
        if (t + 1 < nt)
            stage_tile(sp, lds[(t + 1) & 1], rbase, M, clampM, K, kbeg + ((t + 1) << 5), wid, lane);
        const u16* cb = lds[t & 1];

        s16x8 bh[4], bl[4];
        #pragma unroll
        for (int ni = 0; ni < 4; ++ni) {
            int br = wn * 64 + ni * 16 + frow;
            int pc = kblk ^ ((br >> 1) & 3);
            bh[ni] = *(const s16x8*)&cb[2 * 4096 + br * 32 + pc * 8];
            bl[ni] = *(const s16x8*)&cb[3 * 4096 + br * 32 + pc * 8];
        }
        #pragma unroll
        for (int mi = 0; mi < 4; ++mi) {
            int ar = wm * 64 + mi * 16 + frow;
            int pc = kblk ^ ((ar >> 1) & 3);
            s16x8 ah = *(const s16x8*)&cb[0 * 4096 + ar * 32 + pc * 8];
            s16x8 al = *(const s16x8*)&cb[1 * 4096 + ar * 32 + pc * 8];
            #pragma unroll
            for (int ni = 0; ni < 4; ++ni) {
                acc[mi][ni] = __builtin_amdgcn_mfma_f32_16x16x32_bf16(ah, bh[ni], acc[mi][ni], 0, 0, 0);
                acc[mi][ni] = __builtin_amdgcn_mfma_f32_16x16x32_bf16(ah, bl[ni], acc[mi][ni], 0, 0, 0);
                acc[mi][ni] = __builtin_amdgcn_mfma_f32_16x16x32_bf16(al, bh[ni], acc[mi][ni], 0, 0, 0);
            }
        }
    }

    const int erow = (lane >> 4) * 4, ecol = lane & 15;
    #pragma unroll
    for (int mi = 0; mi < 4; ++mi) {
        #pragma unroll
        for (int ni = 0; ni < 4; ++ni) {
            int c = col0 + wn * 64 + ni * 16 + ecol;
            float bv = (!PARTIAL && bias) ? bias[c] : 0.f;
            #pragma unroll
            for (int reg = 0; reg < 4; ++reg) {
                int r = row0 + wm * 64 + mi * 16 + erow + reg;
                if (r >= M) continue;
                float v = acc[mi][ni][reg] + bv;
                if (PARTIAL) {
                    C[((size_t)blockIdx.z * M + r) * N + c] = v;
                    continue;
                }
                if (ACTF == 1) v = v / (1.f + __expf(-v));
                else if (ACTF == 2) {
                    float u = 0.7978845608028654f * (v + 0.044715f * v * v * v);
                    v = 0.5f * v * (1.f + tanhf(u));
                }
                size_t o = (size_t)r * N + c;
                if (WF32) C[o] = v;
                if (WSPLIT) { u16 h, l; split2(v, h, l); Chi[o] = h; Clo[o] = l; }
            }
        }
    }
}

// split-K reduce + epilogue: sums S slices, applies bias/act, writes f32/split
template<int ACTF, int WF32, int WSPLIT>
__global__ __launch_bounds__(256)
void reduce_k(const float* __restrict__ Cp, int S,
              float* __restrict__ C, u16* __restrict__ Chi, u16* __restrict__ Clo,
              const float* __restrict__ bias, int M, int N)
{
    int i = blockIdx.x * 256 + threadIdx.x;
    int n4 = (int)((size_t)M * N / 4);
    if (i >= n4) return;
    size_t off = (size_t)i * 4;
    float4 v = *(const float4*)&Cp[off];
    for (int z = 1; z < S; ++z) {
        float4 u = *(const float4*)&Cp[(size_t)z * M * N + off];
        v.x += u.x; v.y += u.y; v.z += u.z; v.w += u.w;
    }
    int c = (int)(off % N);
    float vv[4] = {v.x, v.y, v.z, v.w};
    #pragma unroll
    for (int j = 0; j < 4; ++j) {
        float w = vv[j];
        if (bias) w += bias[c + j];
        if (ACTF == 1) w = w / (1.f + __expf(-w));
        else if (ACTF == 2) {
            float u = 0.7978845608028654f * (w + 0.044715f * w * w * w);
            w = 0.5f * w * (1.f + tanhf(u));
        }
        if (WF32) C[off + j] = w;
        if (WSPLIT) { u16 h, l; split2(w, h, l); Chi[off + j] = h; Clo[off + j] = l; }
    }
}

static void gemm_mfma(hipStream_t s, int act, int wf32, int wsplit,
                      const u16* Ah, const u16* Al, const u16* Wh, const u16* Wl,
                      float* C, u16* Ch, u16* Cl, int M, int N, int K, const float* bias)
{
    dim3 g(N / 128, (M + 127) / 128), b(256);
    if (act == 0 && wf32 == 1 && wsplit == 0)
        gemm_mfma_k<0,1,0,0><<<g,b,0,s>>>(Ah,Al,Wh,Wl,C,Ch,Cl,M,N,K,bias);
    else if (act == 0 && wf32 == 1 && wsplit == 1)
        gemm_mfma_k<0,1,1,0><<<g,b,0,s>>>(Ah,Al,Wh,Wl,C,Ch,Cl,M,N,K,bias);
    else if (act == 0 && wf32 == 0 && wsplit == 1)
        gemm_mfma_k<0,0,1,0><<<g,b,0,s>>>(Ah,Al,Wh,Wl,C,Ch,Cl,M,N,K,bias);
    else if (act == 1)
        gemm_mfma_k<1,0,1,0><<<g,b,0,s>>>(Ah,Al,Wh,Wl,C,Ch,Cl,M,N,K,bias);
    else
        gemm_mfma_k<2,0,1,0><<<g,b,0,s>>>(Ah,Al,Wh,Wl,C,Ch,Cl,M,N,K,bias);
}

// split-K variant: partial GEMM over gridDim.z slices + reduce epilogue
static void gemm_mfma_sk(hipStream_t s, int act, int wf32, int wsplit,
                         const u16* Ah, const u16* Al, const u16* Wh, const u16* Wl,
                         float* C, u16* Ch, u16* Cl, int M, int N, int K,
                         const float* bias, int S, float* part)
{
    if (S <= 1) { gemm_mfma(s, act, wf32, wsplit, Ah, Al, Wh, Wl, C, Ch, Cl, M, N, K, bias); return; }
    dim3 g(N / 128, (M + 127) / 128, S), b(256);
    gemm_mfma_k<0,0,0,1><<<g,b,0,s>>>(Ah,Al,Wh,Wl,part,nullptr,nullptr,M,N,K,nullptr);
    int n4 = (int)((size_t)M * N / 4);
    dim3 rg((n4 + 255) / 256), rb(256);
    if (act == 0 && wf32 == 1 && wsplit == 0)
        reduce_k<0,1,0><<<rg,rb,0,s>>>(part, S, C, Ch, Cl, bias, M, N);
    else if (act == 0 && wf32 == 1 && wsplit == 1)
        reduce_k<0,1,1><<<rg,rb,0,s>>>(part, S, C, Ch, Cl, bias, M, N);
    else if (act == 0 && wf32 == 0 && wsplit == 1)
        reduce_k<0,0,1><<<rg,rb,0,s>>>(part, S, C, Ch, Cl, bias, M, N);
    else if (act == 1)
        reduce_k<1,0,1><<<rg,rb,0,s>>>(part, S, C, Ch, Cl, bias, M, N);
    else
        reduce_k<2,0,1><<<rg,rb,0,s>>>(part, S, C, Ch, Cl, bias, M, N);
}

// ---------------- scan-specialized split-bf16 MFMA GEMM (dbuf loop) -------
// MODE 1: z1 = A@B^T + bias (f32); h = silu(z1) -> split + splitT
// MODE 2: r = A@B^T + bias - add; split + splitT; col-partials CP (x alpha)
// MODE 3: C = alpha * A@B^T (f32)
// MODE 4: dh = alpha*(A@B^T)*dsilu(Z); splitT; col-partials CP
template<int MODE>
__global__ __launch_bounds__(256)
void gemm_scan_k(const u16* __restrict__ Ah, const u16* __restrict__ Al,
                 const u16* __restrict__ Wh, const u16* __restrict__ Wl,
                 float* __restrict__ C, u16* __restrict__ Chi, u16* __restrict__ Clo,
                 u16* __restrict__ ChiT, u16* __restrict__ CloT,
                 const float* __restrict__ Zf, const float* __restrict__ add,
                 const float* __restrict__ bias, float* __restrict__ CP,
                 int M, int N, int K, float alpha)
{
    __shared__ u16 lds[2][16384];
    const int tid = threadIdx.x;
    const int lane = tid & 63, wid = tid >> 6;
    const int wm = wid >> 1, wn = wid & 1;
    int bx, by; xcd_swizzle(bx, by);
    const int row0 = by * 128, col0 = bx * 128;

    const u16* sp = (wid == 0) ? Ah : (wid == 1) ? Al : (wid == 2) ? Wh : Wl;
    const int rbase = (wid < 2) ? row0 : col0;

    f32x4 acc[4][4] = {};
    const int frow = lane & 15, kblk = lane >> 4;
    const int nt = K >> 5;

    stage_tile(sp, lds[0], rbase, M, 0, K, 0, wid, lane);

    for (int t = 0; t < nt; ++t) {
        __syncthreads();
        if (t + 1 < nt)
            stage_tile(sp, lds[(t + 1) & 1], rbase, M, 0, K, (t + 1) << 5, wid, lane);
        const u16* cb = lds[t & 1];

        s16x8 bh[4], bl[4];
        #pragma unroll
        for (int ni = 0; ni < 4; ++ni) {
            int br = wn * 64 + ni * 16 + frow;
            int pc = kblk ^ ((br >> 1) & 3);
            bh[ni] = *(const s16x8*)&cb[2 * 4096 + br * 32 + pc * 8];
            bl[ni] = *(const s16x8*)&cb[3 * 4096 + br * 32 + pc * 8];
        }
        #pragma unroll
        for (int mi = 0; mi < 4; ++mi) {
            int ar = wm * 64 + mi * 16 + frow;
            int pc = kblk ^ ((ar >> 1) & 3);
            s16x8 ah = *(const s16x8*)&cb[0 * 4096 + ar * 32 + pc * 8];
            s16x8 al = *(const s16x8*)&cb[1 * 4096 + ar * 32 + pc * 8];
            #pragma unroll
            for (int ni = 0; ni < 4; ++ni) {
                acc[mi][ni] = __builtin_amdgcn_mfma_f32_16x16x32_bf16(ah, bh[ni], acc[mi][ni], 0, 0, 0);
                acc[mi][ni] = __builtin_amdgcn_mfma_f32_16x16x32_bf16(ah, bl[ni], acc[mi][ni], 0, 0, 0);
                acc[mi][ni] = __builtin_amdgcn_mfma_f32_16x16x32_bf16(al, bh[ni], acc[mi][ni], 0, 0, 0);
            }
        }
    }

    const int erow = (lane >> 4) * 4, ecol = lane & 15;
    float csum[4] = {0.f, 0.f, 0.f, 0.f};
    #pragma unroll
    for (int mi = 0; mi < 4; ++mi) {
        #pragma unroll
        for (int ni = 0; ni < 4; ++ni) {
            int c = col0 + wn * 64 + ni * 16 + ecol;
            #pragma unroll
            for (int reg = 0; reg < 4; ++reg) {
                int r = row0 + wm * 64 + mi * 16 + erow + reg;
                float v = acc[mi][ni][reg];
                size_t o = (size_t)r * N + c;
                if (MODE == 1) {
                    v += bias[c];
                    C[o] = v;
                    float hv = v / (1.f + __expf(-v));
                    u16 h, l; split2(hv, h, l);
                    Chi[o] = h; Clo[o] = l;
                    size_t ot = (size_t)c * M + r;
                    ChiT[ot] = h; CloT[ot] = l;
                } else if (MODE == 2) {
                    v += bias[c] - add[o];
                    u16 h, l; split2(v, h, l);
                    Chi[o] = h; Clo[o] = l;
                    size_t ot = (size_t)c * M + r;
                    ChiT[ot] = h; CloT[ot] = l;
                    csum[ni] += v;
                } else if (MODE == 3) {
                    C[o] = alpha * v;
                } else {
                    v *= alpha;
                    float z = Zf[o];
                    float sg = 1.f / (1.f + __expf(-z));
                    v *= sg * (1.f + z * (1.f - sg));
                    u16 h, l; split2(v, h, l);
                    size_t ot = (size_t)c * M + r;
                    ChiT[ot] = h; CloT[ot] = l;
                    csum[ni] += v;
                }
            }
        }
    }
    if (MODE == 2 || MODE == 4) {
        #pragma unroll
        for (int ni = 0; ni < 4; ++ni) {
            float s = csum[ni];
            s += __shfl_xor(s, 16);
            s += __shfl_xor(s, 32);
            if ((lane >> 4) == 0) {
                int c = col0 + wn * 64 + ni * 16 + ecol;
                float w = (MODE == 2) ? alpha * s : s;
                CP[(size_t)(by * 2 + wm) * N + c] = w;
            }
        }
    }
}

// ---------------- small kernels ----------------
__global__ void cvt_split_k(const float* __restrict__ in, u16* __restrict__ hi,
                            u16* __restrict__ lo, int n4) {
    int i = blockIdx.x * 256 + threadIdx.x;
    if (i >= n4) return;
    float4 v = *(const float4*)&in[(size_t)i * 4];
    u16 h0,l0,h1,l1,h2,l2,h3,l3;
    split2(v.x,h0,l0); split2(v.y,h1,l1); split2(v.z,h2,l2); split2(v.w,h3,l3);
    ushort4 hv = {h0,h1,h2,h3}, lv = {l0,l1,l2,l3};
    *(ushort4*)&hi[(size_t)i * 4] = hv;
    *(ushort4*)&lo[(size_t)i * 4] = lv;
}
__global__ void transpose_split_k(const float* __restrict__ in, u16* __restrict__ outh,
                                  u16* __restrict__ outl, int R, int C) {
    __shared__ float t[32][33];
    const int c0 = blockIdx.x * 32, r0 = blockIdx.y * 32;
    const size_t zoff = (size_t)blockIdx.z * R * C;
    const int tx = threadIdx.x & 31, ty = threadIdx.x >> 5;
    #pragma unroll
    for (int p = 0; p < 4; ++p) {
        int r = ty + p * 8;
        t[r][tx] = in[zoff + (size_t)(r0 + r) * C + c0 + tx];
    }
    __syncthreads();
    #pragma unroll
    for (int p = 0; p < 4; ++p) {
        int cc = ty + p * 8;
        float v = t[tx][cc];
        u16 h, l; split2(v, h, l);
        size_t o = zoff + (size_t)(c0 + cc) * R + r0 + tx;
        outh[o] = h; outl[o] = l;
    }
}
// momentum update; bias grads from col-partials; maintain W1/W2/W2T split forms
__global__ void update3_k(float* __restrict__ p, float* __restrict__ mo,
                          const float* __restrict__ g,
                          const float* __restrict__ cp1, const float* __restrict__ cp2,
                          u16* __restrict__ w1h, u16* __restrict__ w1l,
                          u16* __restrict__ w2h, u16* __restrict__ w2l,
                          u16* __restrict__ w2th, u16* __restrict__ w2tl, int n) {
    int i = blockIdx.x * 256 + threadIdx.x;
    if (i >= n) return;
    float gi;
    if (i < 524288) gi = g[i];
    else if (i < 524800) {
        int j = i - 524288;
        gi = cp1[j] + cp1[512 + j] + cp1[1024 + j] + cp1[1536 + j];
    } else if (i < 1049088) gi = g[i];
    else {
        int j = i - 1049088;
        gi = cp2[j] + cp2[1024 + j] + cp2[2048 + j] + cp2[3072 + j];
    }
    float m = ETA_C * mo[i] - THETA_C * gi;
    mo[i] = m;
    float pv = (1.f - ALPHA_C) * p[i] + m;
    p[i] = pv;
    if (i < 524288) {
        u16 h, l; split2(pv, h, l); w1h[i] = h; w1l[i] = l;
    } else if (i >= 524800 && i < 1049088) {
        int j = i - 524800;
        u16 h, l; split2(pv, h, l);
        w2h[j] = h; w2l[j] = l;
        int tj = (j & 511) * 1024 + (j >> 9);
        w2th[tj] = h; w2tl[tj] = l;
    }
}
__global__ void extractqkv2_k(const float* __restrict__ qkv, u16* __restrict__ Qh,
                              u16* __restrict__ Ql, float* __restrict__ Kb,
                              float* __restrict__ Vb) {
    size_t idx = (size_t)blockIdx.x * 256 + threadIdx.x;
    int m = (int)(idx / 3072), col = (int)(idx % 3072);
    int b = m >> 10, t = m & 1023;
    float v = qkv[idx];
    if (col < 1024) {
        size_t o = (size_t)m * 1024 + col;
        u16 h, l; split2(v, h, l); Qh[o] = h; Ql[o] = l;
    } else {
        int d = col & 1023;
        int ch = t >> 7, r = t & 127;
        size_t o = ((size_t)((ch * 2 + b) * 128 + r)) * 1024 + d;
        if (col < 2048) Kb[o] = v; else Vb[o] = v;
    }
}
__global__ void tokens_split_k(const float* __restrict__ P, const float* __restrict__ memtok,
                               const float* __restrict__ x, u16* __restrict__ th,
                               u16* __restrict__ tl) {
    size_t idx = (size_t)blockIdx.x * 256 + threadIdx.x;
    int d = (int)(idx & 1023);
    int n = (int)((idx >> 10) % NTOK);
    int b = (int)(idx / ((size_t)NTOK * 1024));
    float v;
    if (n < NPERS)            v = P[(size_t)n * 1024 + d];
    else if (n < NPERS + TSEQ) v = memtok[((size_t)b * TSEQ + (n - NPERS)) * 1024 + d];
    else                      v = x[((size_t)b * TSEQ + (n - NPERS - TSEQ)) * 1024 + d];
    u16 h, l; split2(v, h, l); th[idx] = h; tl[idx] = l;
}
__global__ void mul_k(const float* __restrict__ a, const float* __restrict__ b,
                      float* __restrict__ o, int n) {
    int i = blockIdx.x * 256 + threadIdx.x;
    if (i < n) o[i] = a[i] * b[i];
}

// ---------------- attention prep ----------------
__global__ void prep_q_k(const float* __restrict__ aqkv, u16* __restrict__ Qh,
                         u16* __restrict__ Ql) {
    size_t idx = (size_t)blockIdx.x * 256 + threadIdx.x;
    int d = (int)(idx & 63);
    int row = (int)((idx >> 6) & 1023);
    int h = (int)((idx >> 16) & 15);
    int b = (int)(idx >> 20);
    float v = 0.125f * aqkv[((size_t)b * NTOK + NPERS + TSEQ + row) * 3072 + h * 64 + d];
    u16 hh, ll; split2(v, hh, ll);
    Qh[idx] = hh; Ql[idx] = ll;
}
__global__ void prep_kk_k(const float* __restrict__ aqkv, u16* __restrict__ Kh,
                          u16* __restrict__ Kl) {
    size_t idx = (size_t)blockIdx.x * 256 + threadIdx.x;
    int d = (int)(idx & 63);
    int n = (int)((idx >> 6) % NTOK);
    int t = (int)(idx / (64 * NTOK));
    int h = t & 15, b = t >> 4;
    float v = aqkv[((size_t)b * NTOK + n) * 3072 + 1024 + h * 64 + d];
    u16 hh, ll; split2(v, hh, ll);
    Kh[idx] = hh; Kl[idx] = ll;
}
__global__ void prep_vt_k(const float* __restrict__ aqkv, u16* __restrict__ Vt) {
    __shared__ float t[64][65];
    const int nt = blockIdx.x, h = blockIdx.y, b = blockIdx.z;
    const int j0 = nt * 64;
    const int lx = threadIdx.x & 63, rg = threadIdx.x >> 6;
    #pragma unroll
    for (int p = 0; p < 16; ++p) {
        int r = rg * 16 + p;
        int n = j0 + r;
        t[r][lx] = (n < NTOK) ? aqkv[((size_t)b * NTOK + n) * 3072 + 2048 + h * 64 + lx] : 0.f;
    }
    __syncthreads();
    #pragma unroll
    for (int p = 0; p < 16; ++p) {
        int d = rg * 16 + p;
        int n = j0 + lx;
        if (n < NTOK)
            Vt[((size_t)(b * 16 + h) * 64 + d) * NTOK + n] = f2bf(t[lx][d]);
    }
}

// ---------------- MFMA flash attention (KV double-buffered) ----------------
__global__ __launch_bounds__(256)
void flash_mfma_k(const u16* __restrict__ Qsh, const u16* __restrict__ Qsl,
                  const u16* __restrict__ Ksh, const u16* __restrict__ Ksl,
                  const u16* __restrict__ Vts, u16* __restrict__ oh, u16* __restrict__ ol)
{
    __shared__ u16 lds[40960];             // QH QL | kv0{KH KL VT} | kv1{...} | PH PL
    u16* QH = lds;            u16* QL = lds + 4096;
    u16* KV0 = lds + 8192;    u16* KV1 = lds + 20480;
    u16* PH = lds + 32768;    u16* PL = lds + 36864;

    const int qt = blockIdx.x, h = blockIdx.y, b = blockIdx.z;
    const int tid = threadIdx.x;
    const int lane = tid & 63, wid = tid >> 6;
    const int fr = lane & 15, kq = lane >> 4;
    const int bh = b * 16 + h;
    const int q0c = qt * 64;
    const int q0a = NPERS + TSEQ + q0c;
    const int jtmax = (q0a + 63) >> 6;
    const int l8 = lane & 7, lr8 = lane >> 3;

    auto stageKV = [&](int jt, u16* kvb) {
        const int j0 = jt * 64;
        #pragma unroll
        for (int jj = 0; jj < 6; ++jj) {
            int j = wid * 6 + jj;
            int buf = j >> 3, i8 = j & 7;
            if (buf < 2) {
                int row = i8 * 8 + lr8;
                int grow = j0 + row; if (grow > NTOK - 1) grow = NTOK - 1;
                int c = l8 ^ (row & 7);
                const u16* src = (buf == 0 ? Ksh : Ksl) +
                                 (((size_t)bh * NTOK + grow) << 6) + c * 8;
                gload_lds16(src, kvb + buf * 4096 + i8 * 512);
            } else {
                int d = i8 * 8 + lr8;
                int c = l8 ^ (d & 7);
                int col = j0 + c * 8; if (col > NTOK - 8) col = NTOK - 8;
                const u16* src = Vts + ((size_t)bh * 64 + d) * NTOK + col;
                gload_lds16(src, kvb + 8192 + i8 * 512);
            }
        }
    };

    {
        #pragma unroll
        for (int jj = 0; jj < 4; ++jj) {
            int j = wid * 4 + jj;
            int buf = j >> 3, i8 = j & 7;
            int row = i8 * 8 + lr8;
            int c = l8 ^ (row & 7);
            const u16* src = (buf == 0 ? Qsh : Qsl) +
                             (((size_t)bh * 1024 + q0c + row) << 6) + c * 8;
            gload_lds16(src, (buf == 0 ? QH : QL) + i8 * 512);
        }
    }
    stageKV(0, KV0);
    __syncthreads();

    s16x8 qh[2], ql[2];
    #pragma unroll
    for (int kb = 0; kb < 2; ++kb) {
        int r = wid * 16 + fr;
        int sl = (kb * 4 + kq) ^ (fr & 7);
        qh[kb] = *(const s16x8*)&QH[r * 64 + sl * 8];
        ql[kb] = *(const s16x8*)&QL[r * 64 + sl * 8];
    }

    f32x4 Oa[4] = {};
    float mrow[4], lrow[4];
    #pragma unroll
    for (int r = 0; r < 4; ++r) { mrow[r] = -INFINITY; lrow[r] = 0.f; }

    for (int jt = 0; jt <= jtmax; ++jt) {
        const int j0 = jt * 64;
        if (jt) __syncthreads();
        if (jt + 1 <= jtmax) stageKV(jt + 1, (jt & 1) ? KV0 : KV1);
        u16* kvb = (jt & 1) ? KV1 : KV0;
        u16* KH = kvb; u16* KL = kvb + 4096; u16* VT = kvb + 8192;

        f32x4 sacc[4] = {};
        #pragma unroll
        for (int nt = 0; nt < 4; ++nt) {
            #pragma unroll
            for (int kb = 0; kb < 2; ++kb) {
                int br = nt * 16 + fr;
                int sl = (kb * 4 + kq) ^ (fr & 7);
                s16x8 kh = *(const s16x8*)&KH[br * 64 + sl * 8];
                s16x8 kl = *(const s16x8*)&KL[br * 64 + sl * 8];
                sacc[nt] = __builtin_amdgcn_mfma_f32_16x16x32_bf16(qh[kb], kh, sacc[nt], 0, 0, 0);
                sacc[nt] = __builtin_amdgcn_mfma_f32_16x16x32_bf16(ql[kb], kh, sacc[nt], 0, 0, 0);
                sacc[nt] = __builtin_amdgcn_mfma_f32_16x16x32_bf16(qh[kb], kl, sacc[nt], 0, 0, 0);
            }
        }

        #pragma unroll
        for (int r = 0; r < 4; ++r) {
            const int qloc = kq * 4 + r;
            const int qi = q0a + wid * 16 + qloc;
            float sv[4], tmax = -INFINITY;
            #pragma unroll
            for (int nt = 0; nt < 4; ++nt) {
                int kj = j0 + nt * 16 + fr;
                sv[nt] = (kj <= qi) ? sacc[nt][r] : -INFINITY;
                tmax = fmaxf(tmax, sv[nt]);
            }
            #pragma unroll
            for (int off = 1; off < 16; off <<= 1)
                tmax = fmaxf(tmax, __shfl_xor(tmax, off));
            float mnew = fmaxf(mrow[r], tmax);
            float scale = __expf(mrow[r] - mnew);
            float psum = 0.f;
            float p4[4];
            #pragma unroll
            for (int nt = 0; nt < 4; ++nt) { p4[nt] = __expf(sv[nt] - mnew); psum += p4[nt]; }
            #pragma unroll
            for (int off = 1; off < 16; off <<= 1)
                psum += __shfl_xor(psum, off);
            lrow[r] = lrow[r] * scale + psum;
            mrow[r] = mnew;
            #pragma unroll
            for (int dt = 0; dt < 4; ++dt) Oa[dt][r] *= scale;
            const int prow = wid * 16 + qloc;
            #pragma unroll
            for (int nt = 0; nt < 4; ++nt) {
                u16 ph, pl; split2(p4[nt], ph, pl);
                int col = nt * 16 + fr;
                int sl = (col >> 3) ^ (qloc & 7);
                int off = prow * 64 + sl * 8 + (col & 7);
                PH[off] = ph; PL[off] = pl;
            }
        }

        #pragma unroll
        for (int kb = 0; kb < 2; ++kb) {
            int pr = wid * 16 + fr;
            int sl = (kb * 4 + kq) ^ (fr & 7);
            s16x8 pa = *(const s16x8*)&PH[pr * 64 + sl * 8];
            s16x8 pb = *(const s16x8*)&PL[pr * 64 + sl * 8];
            #pragma unroll
            for (int dt = 0; dt < 4; ++dt) {
                int vr = dt * 16 + fr;
                s16x8 vb = *(const s16x8*)&VT[vr * 64 + sl * 8];
                Oa[dt] = __builtin_amdgcn_mfma_f32_16x16x32_bf16(pa, vb, Oa[dt], 0, 0, 0);
                Oa[dt] = __builtin_amdgcn_mfma_f32_16x16x32_bf16(pb, vb, Oa[dt], 0, 0, 0);
            }
        }
    }

    #pragma unroll
    for (int r = 0; r < 4; ++r) {
        float inv = 1.f / lrow[r];
        int row = b * 1024 + q0c + wid * 16 + kq * 4 + r;
        #pragma unroll
        for (int dt = 0; dt < 4; ++dt) {
            float v = Oa[dt][r] * inv;
            size_t o = (size_t)row * 1024 + h * 64 + dt * 16 + fr;
            u16 hh, ll; split2(v, hh, ll);
            oh[o] = hh; ol[o] = ll;
        }
    }
}

// ---------------- launch ----------------
extern "C" void kernel_launch(void* const* d_in, const int* in_sizes, int n_in,
                              void* d_out, int out_size, void* d_ws, size_t ws_size,
                              hipStream_t stream)
{
    const float* x     = (const float*)d_in[0];
    const float* Wqkv  = (const float*)d_in[1];
    const float* mW1   = (const float*)d_in[2];
    const float* mb1   = (const float*)d_in[3];
    const float* mW2   = (const float*)d_in[4];
    const float* mb2   = (const float*)d_in[5];
    const float* Pp    = (const float*)d_in[6];
    const float* Wqa   = (const float*)d_in[7];
    const float* Wo    = (const float*)d_in[8];
    const float* ffW1  = (const float*)d_in[9];
    const float* ffb1  = (const float*)d_in[10];
    const float* ffW2  = (const float*)d_in[11];
    const float* ffb2  = (const float*)d_in[12];
    char* wsb = (char*)d_ws;
    float* outp = (float*)d_out;

    // region A (multiplexed)
    float* qkv   = (float*)(wsb + oRA);
    float* z1    = (float*)(wsb + oRA);
    float* grd   = (float*)(wsb + oRA + 3145728);
    float* cp2   = (float*)(wsb + oRA + 7346176);
    float* cp1   = (float*)(wsb + oRA + 7362560);
    u16* hh_     = (u16*)(wsb + oRA + 8388608);
    u16* hl_     = (u16*)(wsb + oRA + 8650752);
    u16* hTh     = (u16*)(wsb + oRA + 9437184);
    u16* hTl     = (u16*)(wsb + oRA + 9699328);
    u16* rh_     = (u16*)(wsb + oRA + 10485760);
    u16* rl_     = (u16*)(wsb + oRA + 11010048);
    u16* rTh     = (u16*)(wsb + oRA + 11534336);
    u16* rTl     = (u16*)(wsb + oRA + 12058624);
    u16* dhTh    = (u16*)(wsb + oRA + 12582912);
    u16* dhTl    = (u16*)(wsb + oRA + 12845056);
    u16* kcTh    = (u16*)(wsb + oRA + 16777216);
    u16* kcTl    = (u16*)(wsb + oRA + 20971520);
    float* aqkv  = (float*)(wsb + oRA);
    u16* Woh     = (u16*)(wsb + oRA);
    u16* Wol     = (u16*)(wsb + oRA + 2097152);
    u16* ffhh    = (u16*)(wsb + oRA);
    u16* ffhl    = (u16*)(wsb + oRA + 16777216);
    u16* outbh   = (u16*)(wsb + oRA + 33554432);
    u16* outbl   = (u16*)(wsb + oRA + 37748736);
    u16* newQh   = (u16*)(wsb + oRA);
    u16* newQl   = (u16*)(wsb + oRA + 4194304);
    u16* hzh     = (u16*)(wsb + oRA + 8388608);
    u16* hzl     = (u16*)(wsb + oRA + 10485760);
    float* memq  = (float*)(wsb + oRA + 12582912);
    // split-K partial buffers (time-multiplexed dead zones)
    float* partA0 = (float*)(wsb + oRA);                 // readout memtok (S=2, 16.8MB)
    float* partA1 = (float*)(wsb + oRA + 4194304);       // Wo (S=2, 16.8MB)
    float* partA2 = (float*)(wsb + oRA + 16777216);      // t1 (S=4, 16.8MB)
    // region B
    float* Kb    = (float*)(wsb + oRB);
    float* Vb    = (float*)(wsb + oRB + 8388608);
    u16* tokh    = (u16*)(wsb + oRB);
    u16* tokl    = (u16*)(wsb + oRB + 8454144);
    u16* oh      = (u16*)(wsb + oRB);
    u16* ol      = (u16*)(wsb + oRB + 4194304);
    u16* fVth    = (u16*)(wsb + oRB + 8388608);
    u16* y1h     = (u16*)(wsb + oRB + 8388608);
    u16* y1l     = (u16*)(wsb + oRB + 12582912);
    float* partB = (float*)(wsb + oRB);                  // FF2/newQ/hz/memq (16.8MB)
    // region C
    u16* xh      = (u16*)(wsb + oRC);
    u16* xl      = (u16*)(wsb + oRC + 4194304);
    float* mom   = (float*)(wsb + oRC);
    u16* pW2Th   = (u16*)(wsb + oRC + 5242880);
    u16* pW2Tl   = (u16*)(wsb + oRC + 6291456);
    u16* Wqah    = (u16*)(wsb + oRC);
    u16* Wqal    = (u16*)(wsb + oRC + 6291456);
    u16* fKl     = (u16*)(wsb + oRC);
    // region D
    u16* Qh      = (u16*)(wsb + oRD);
    u16* Ql      = (u16*)(wsb + oRD + 4194304);
    u16* kchh    = (u16*)(wsb + oRD + 8388608);
    u16* kchl    = (u16*)(wsb + oRD + 12582912);
    u16* t1h     = (u16*)(wsb + oRD + 8388608);
    u16* t1l     = (u16*)(wsb + oRD + 10485760);
    float* memtok= (float*)(wsb + oRD);
    u16* fKh     = (u16*)(wsb + oRD);
    u16* ffW1h   = (u16*)(wsb + oRD);
    u16* ffW1l   = (u16*)(wsb + oRD + 8388608);
    u16* ffW2h   = (u16*)(wsb + oRD);
    u16* ffW2l   = (u16*)(wsb + oRD + 8388608);
    // persistent
    u16* Wqkvh   = (u16*)(wsb + oRE);
    u16* Wqkvl   = (u16*)(wsb + oRE + 6291456);
    u16* pW1h    = (u16*)(wsb + oRF);
    u16* pW1l    = (u16*)(wsb + oRF + 1048576);
    u16* pW2h    = (u16*)(wsb + oRF + 2097152);
    u16* pW2l    = (u16*)(wsb + oRF + 3145728);
    float* par   = (float*)(wsb + oRG);
    float* outb  = (float*)(wsb + oRH);
    u16* fQh     = (u16*)(wsb + oRH);
    u16* fQl     = (u16*)(wsb + oRH + 4194304);

    // init memory-MLP params
    hipMemcpyAsync(par + PW1, mW1, 524288 * sizeof(float), hipMemcpyDeviceToDevice, stream);
    hipMemcpyAsync(par + PB1, mb1, 512 * sizeof(float), hipMemcpyDeviceToDevice, stream);
    hipMemcpyAsync(par + PW2, mW2, 524288 * sizeof(float), hipMemcpyDeviceToDevice, stream);
    hipMemcpyAsync(par + PB2, mb2, 1024 * sizeof(float), hipMemcpyDeviceToDevice, stream);

    // qkv = x @ Wqkv^T
    cvt_split_k<<<2048, 256, 0, stream>>>(x, xh, xl, 524288);
    cvt_split_k<<<3072, 256, 0, stream>>>(Wqkv, Wqkvh, Wqkvl, 786432);
    gemm_mfma(stream, 0, 1, 0, xh, xl, Wqkvh, Wqkvl, qkv, nullptr, nullptr, 2048, 3072, 1024, nullptr);
    extractqkv2_k<<<24576, 256, 0, stream>>>(qkv, Qh, Ql, Kb, Vb);

    // scan prep
    hipMemsetAsync(mom, 0, PSZ * sizeof(float), stream);
    cvt_split_k<<<2048, 256, 0, stream>>>(Kb, kchh, kchl, 524288);
    transpose_split_k<<<dim3(32, 8, 8), 256, 0, stream>>>(Kb, kcTh, kcTl, 256, 1024);
    cvt_split_k<<<512, 256, 0, stream>>>(par + PW1, pW1h, pW1l, 131072);
    cvt_split_k<<<512, 256, 0, stream>>>(par + PW2, pW2h, pW2l, 131072);
    transpose_split_k<<<dim3(16, 32, 1), 256, 0, stream>>>(par + PW2, pW2Th, pW2Tl, 1024, 512);

    // memory scan
    const float cs = 2.f / (float)(BATCH * 128 * DIMD);
    for (int c = 0; c < NCH; ++c) {
        const u16* kch = kchh + (size_t)c * 262144;
        const u16* kcl = kchl + (size_t)c * 262144;
        const u16* kth = kcTh + (size_t)c * 262144;
        const u16* ktl = kcTl + (size_t)c * 262144;
        const float* vc = Vb + (size_t)c * 262144;
        gemm_scan_k<1><<<dim3(4, 2), 256, 0, stream>>>(kch, kcl, pW1h, pW1l,
            z1, hh_, hl_, hTh, hTl, nullptr, nullptr, par + PB1, nullptr, 256, 512, 1024, 1.f);
        gemm_scan_k<2><<<dim3(8, 2), 256, 0, stream>>>(hh_, hl_, pW2h, pW2l,
            nullptr, rh_, rl_, rTh, rTl, nullptr, vc, par + PB2, cp2, 256, 1024, 512, cs);
        gemm_scan_k<3><<<dim3(4, 8), 256, 0, stream>>>(rTh, rTl, hTh, hTl,
            grd + PW2, nullptr, nullptr, nullptr, nullptr, nullptr, nullptr, nullptr, nullptr,
            1024, 512, 256, cs);
        gemm_scan_k<4><<<dim3(4, 2), 256, 0, stream>>>(rh_, rl_, pW2Th, pW2Tl,
            nullptr, nullptr, nullptr, dhTh, dhTl, z1, nullptr, nullptr, cp1, 256, 512, 1024, cs);
        gemm_scan_k<3><<<dim3(8, 4), 256, 0, stream>>>(dhTh, dhTl, kth, ktl,
            grd + PW1, nullptr, nullptr, nullptr, nullptr, nullptr, nullptr, nullptr, nullptr,
            512, 1024, 256, 1.f);
        update3_k<<<4102, 256, 0, stream>>>(par, mom, grd, cp1, cp2,
            pW1h, pW1l, pW2h, pW2l, pW2Th, pW2Tl, (int)PSZ);
    }

    // memory readout (split-K: t1 S=4 part@A2, memtok S=2 part@A0)
    gemm_mfma_sk(stream, 1, 0, 1, Qh, Ql, pW1h, pW1l, nullptr, t1h, t1l,
                 2048, 512, 1024, par + PB1, 4, partA2);
    gemm_mfma_sk(stream, 0, 1, 0, t1h, t1l, pW2h, pW2l, memtok, nullptr, nullptr,
                 2048, 1024, 512, par + PB2, 2, partA0);

    // tokens + attention qkv
    tokens_split_k<<<16512, 256, 0, stream>>>(Pp, memtok, x, tokh, tokl);
    cvt_split_k<<<3072, 256, 0, stream>>>(Wqa, Wqah, Wqal, 786432);
    gemm_mfma(stream, 0, 1, 0, tokh, tokl, Wqah, Wqal, aqkv, nullptr, nullptr, 4128, 3072, 1024, nullptr);

    // attention prep
    prep_q_k<<<8192, 256, 0, stream>>>(aqkv, fQh, fQl);
    prep_kk_k<<<16512, 256, 0, stream>>>(aqkv, fKh, fKl);
    prep_vt_k<<<dim3(33, 16, 2), 256, 0, stream>>>(aqkv, fVth);

    // MFMA flash attention
    flash_mfma_k<<<dim3(16, 16, 2), 256, 0, stream>>>(fQh, fQl, fKh, fKl, fVth, oh, ol);

    // Wo projection + FFN (split-K on grid-starved GEMMs)
    cvt_split_k<<<1024, 256, 0, stream>>>(Wo, Woh, Wol, 262144);
    gemm_mfma_sk(stream, 0, 0, 1, oh, ol, Woh, Wol, nullptr, y1h, y1l,
                 2048, 1024, 1024, nullptr, 2, partA1);
    cvt_split_k<<<4096, 256, 0, stream>>>(ffW1, ffW1h, ffW1l, 1048576);
    gemm_mfma(stream, 2, 0, 1, y1h, y1l, ffW1h, ffW1l, nullptr, ffhh, ffhl, 2048, 4096, 1024, ffb1);
    cvt_split_k<<<4096, 256, 0, stream>>>(ffW2, ffW2h, ffW2l, 1048576);
    gemm_mfma_sk(stream, 0, 1, 1, ffhh, ffhl, ffW2h, ffW2l, outb, outbh, outbl,
                 2048, 1024, 4096, ffb2, 2, partB);

    // gate
    gemm_mfma_sk(stream, 0, 0, 1, outbh, outbl, Wqkvh, Wqkvl, nullptr, newQh, newQl,
                 2048, 1024, 1024, nullptr, 2, partB);
    gemm_mfma_sk(stream, 1, 0, 1, newQh, newQl, pW1h, pW1l, nullptr, hzh, hzl,
                 2048, 512, 1024, par + PB1, 4, partB);
    gemm_mfma_sk(stream, 0, 1, 0, hzh, hzl, pW2h, pW2l, memq, nullptr, nullptr,
                 2048, 1024, 512, par + PB2, 2, partB);
    mul_k<<<8192, 256, 0, stream>>>(outb, memq, outp, 2097152);
}